// Round 8
// baseline (3039.909 us; speedup 1.0000x reference)
//
#include <hip/hip_runtime.h>
#include <cstdint>
#include <cstddef>

#define B_TOTAL 65536
#define SDIM 64
#define ADIM 32
#define LDIM 64
#define HDIM 1024
#define NEMB 1024
#define TAU 0.125f
#define FMAX 16384

typedef __attribute__((ext_vector_type(8))) short short8;
typedef __attribute__((ext_vector_type(4))) float f32x4;

__device__ inline unsigned short f2bf(float f) {
    unsigned int u = __float_as_uint(f);
    u += 0x7fffu + ((u >> 16) & 1u);
    return (unsigned short)(u >> 16);
}
__device__ inline float bf2f(unsigned short s) {
    return __uint_as_float(((unsigned int)s) << 16);
}

// async global->LDS, 16B per lane; LDS dest = wave-uniform base + lane*16.
__device__ inline void gload16(const unsigned short* g, unsigned short* l) {
    __builtin_amdgcn_global_load_lds(
        (__attribute__((address_space(1))) void*)(g),
        (__attribute__((address_space(3))) void*)(l), 16, 0, 0);
}

// ---------------------------------------------------------------------------
__global__ void cb_norms(const float* __restrict__ codebook, float* __restrict__ cbn)
{
    int i = blockIdx.x * 256 + threadIdx.x;
    if (i < NEMB) {
        float s = 0.f;
#pragma unroll
        for (int k = 0; k < LDIM; ++k) {
            float v = codebook[(size_t)i * LDIM + k];
            s = fmaf(v, v, s);
        }
        cbn[i] = s;
    }
}

__global__ void zero_ctr(int* ctr) { if (threadIdx.x == 0) *ctr = 0; }

// ---------------------------------------------------------------------------
// Weight pre-transform: W[K][N] fp32 -> bf16 plane(s), MFMA-B-ready layout.
// ---------------------------------------------------------------------------
template <int NT, int BN>
__global__ __launch_bounds__(256) void w_xform(
    const float* __restrict__ W, int K, int N,
    unsigned short* __restrict__ Ph, unsigned short* __restrict__ Pl)
{
    __shared__ float Ws[32][BN + 4];
    const int tid = threadIdx.x;
    const int ks = blockIdx.x, nb = blockIdx.y;
    const int k0 = ks * 32, n0 = nb * BN;
    constexpr int LT = 32 * (BN / 4);
#pragma unroll
    for (int it = 0; it < (LT + 255) / 256; ++it) {
        int idx = tid + it * 256;
        if (LT % 256 == 0 || idx < LT) {
            int k = idx / (BN / 4);
            int nf = idx % (BN / 4);
            *(f32x4*)&Ws[k][nf * 4] =
                *(const f32x4*)&W[(size_t)(k0 + k) * N + n0 + nf * 4];
        }
    }
    __syncthreads();
    const int KS = K >> 5;
    size_t bo = ((size_t)nb * KS + ks) * (BN * 32);
    constexpr int WT = BN * 4;
#pragma unroll
    for (int it = 0; it < (WT + 255) / 256; ++it) {
        int idx = tid + it * 256;
        if (WT % 256 == 0 || idx < WT) {
            int kb = idx / BN;
            int n = idx % BN;
            short8 h, l;
#pragma unroll
            for (int j = 0; j < 8; ++j) {
                float x = Ws[kb * 8 + j][n];
                unsigned short hb_ = f2bf(x);
                h[j] = (short)hb_;
                if (NT == 3) l[j] = (short)f2bf(x - bf2f(hb_));
            }
            *(short8*)&Ph[bo + (size_t)idx * 8] = h;
            if (NT == 3) *(short8*)&Pl[bo + (size_t)idx * 8] = l;
        }
    }
}

// ---------------------------------------------------------------------------
// BF16 MFMA GEMM, double-buffered prefetch + XCD swizzle (unchanged, proven).
// ---------------------------------------------------------------------------
template <int NT, int BN, int OUT, int ACT>
__global__ __launch_bounds__(256, 2) void mfma_gemm(
    const unsigned short* __restrict__ Ah_g, const unsigned short* __restrict__ Al_g,
    int K,
    const unsigned short* __restrict__ Wh, const unsigned short* __restrict__ Wl,
    const float* __restrict__ bias,
    void* __restrict__ out0, void* __restrict__ out1, int NTOT)
{
    constexpr int NWC = (BN == 128) ? 2 : 1;
    constexpr int WM = (BN == 128) ? 4 : 2;
    constexpr int WN = (BN == 32) ? 2 : 4;
    constexpr int ABUF = (NT == 3) ? 8192 : 4096;           // shorts per buffer (A)
    constexpr int BBUF = 4 * BN * 8 * ((NT == 3) ? 2 : 1);  // shorts per buffer (B)
    constexpr int BUFSH = ABUF + BBUF;

    __shared__ unsigned short smem[2 * BUFSH];

    const int tid = threadIdx.x;
    int row_t, nb;
    if constexpr (BN == 128) {
        int per = gridDim.x >> 3;        // == mt (mt % 8 == 0 guaranteed by host)
        int xcd = blockIdx.x & 7;
        int lid = blockIdx.x >> 3;
        int tile = xcd * per + lid;
        row_t = tile >> 3;
        nb = tile & 7;
    } else {
        row_t = blockIdx.x;
        nb = 0;
    }
    const int m0 = row_t * 128;
    const int n0 = nb * BN;
    const int w = tid >> 6, lane = tid & 63;
    const int g = lane >> 4, lr = lane & 15;
    const int wrow0 = (w / NWC) * (WM * 16);
    const int wcol0 = (w % NWC) * (WN * 16);
    const int KS = K >> 5;

    auto stage = [&](unsigned short* buf, int ks) {
        unsigned short* Ah = buf;
        unsigned short* Al = buf + 4096;
        unsigned short* Bh = buf + ABUF;
        unsigned short* Bl = Bh + 4 * BN * 8;
#pragma unroll
        for (int it = 0; it < 2; ++it) {
            int t0 = it * 256 + w * 64;
            int t = t0 + lane;
            int row = t & 127, kb = t >> 7;
            size_t go = (size_t)(m0 + row) * K + ks * 32 + kb * 8;
            gload16(Ah_g + go, Ah + (size_t)t0 * 8);
            if constexpr (NT == 3) gload16(Al_g + go, Al + (size_t)t0 * 8);
        }
        size_t bo = ((size_t)nb * KS + ks) * (BN * 32);
        constexpr int BT = 4 * BN;
        if constexpr (BT >= 256) {
#pragma unroll
            for (int it = 0; it < BT / 256; ++it) {
                int t0 = it * 256 + w * 64;
                size_t go = bo + (size_t)(t0 + lane) * 8;
                gload16(Wh + go, Bh + (size_t)t0 * 8);
                if constexpr (NT == 3) gload16(Wl + go, Bl + (size_t)t0 * 8);
            }
        } else {
            if (tid < BT) {
                int t0 = w * 64;
                size_t go = bo + (size_t)(t0 + lane) * 8;
                gload16(Wh + go, Bh + (size_t)t0 * 8);
                if constexpr (NT == 3) gload16(Wl + go, Bl + (size_t)t0 * 8);
            }
        }
    };

    f32x4 acc[WM][WN];
#pragma unroll
    for (int m = 0; m < WM; ++m)
#pragma unroll
        for (int n = 0; n < WN; ++n) {
            acc[m][n][0] = 0.f; acc[m][n][1] = 0.f;
            acc[m][n][2] = 0.f; acc[m][n][3] = 0.f;
        }

    stage(smem, 0);   // prologue into buffer 0

    for (int ks = 0; ks < KS; ++ks) {
        __syncthreads();   // drains vmcnt: buf[cur] staged (issued a full phase ago)
        unsigned short* buf = smem + (size_t)(ks & 1) * BUFSH;
        if (ks + 1 < KS)
            stage(smem + (size_t)((ks + 1) & 1) * BUFSH, ks + 1);   // flies during MFMA

        unsigned short* Ah = buf;
        unsigned short* Al = buf + 4096;
        unsigned short* Bh = buf + ABUF;
        unsigned short* Bl = Bh + 4 * BN * 8;

        short8 ah[WM], bh[WN];
        short8 al[WM], bl[WN];
#pragma unroll
        for (int m = 0; m < WM; ++m) {
            int ro = (g << 7) + wrow0 + m * 16 + lr;
            ah[m] = *(const short8*)&Ah[ro * 8];
            if constexpr (NT == 3) al[m] = *(const short8*)&Al[ro * 8];
        }
#pragma unroll
        for (int n = 0; n < WN; ++n) {
            int co = g * BN + wcol0 + n * 16 + lr;
            bh[n] = *(const short8*)&Bh[co * 8];
            if constexpr (NT == 3) bl[n] = *(const short8*)&Bl[co * 8];
        }
#pragma unroll
        for (int m = 0; m < WM; ++m)
#pragma unroll
            for (int n = 0; n < WN; ++n) {
                acc[m][n] = __builtin_amdgcn_mfma_f32_16x16x32_bf16(
                    ah[m], bh[n], acc[m][n], 0, 0, 0);
                if constexpr (NT == 3) {
                    acc[m][n] = __builtin_amdgcn_mfma_f32_16x16x32_bf16(
                        ah[m], bl[n], acc[m][n], 0, 0, 0);
                    acc[m][n] = __builtin_amdgcn_mfma_f32_16x16x32_bf16(
                        al[m], bh[n], acc[m][n], 0, 0, 0);
                }
            }
    }

    // ---- epilogue: bias + act, LDS transpose, coalesced stores ----
    float bv[WN];
#pragma unroll
    for (int n = 0; n < WN; ++n) bv[n] = bias[n0 + wcol0 + n * 16 + lr];

    unsigned short* Sb = smem;
    float* Sf = (float*)smem;
    constexpr int NPASS = (OUT == 0) ? 2 : 1;

#pragma unroll
    for (int p = 0; p < NPASS; ++p) {
        __syncthreads();
#pragma unroll
        for (int m = 0; m < WM; ++m)
#pragma unroll
            for (int n = 0; n < WN; ++n)
#pragma unroll
                for (int q = 0; q < 4; ++q) {
                    int rl = wrow0 + m * 16 + g * 4 + q;
                    int cl = wcol0 + n * 16 + lr;
                    float x = acc[m][n][q] + bv[n];
                    if (ACT == 0) x = fmaxf(x, 0.f);
                    else x = tanhf(x);
                    if constexpr (OUT == 2) {
                        Sf[rl * BN + cl] = x;
                    } else {
                        unsigned short hb_ = f2bf(x);
                        Sb[rl * BN + cl] = (p == 0) ? hb_ : f2bf(x - bf2f(hb_));
                    }
                }
        __syncthreads();
        if constexpr (OUT == 2) {
            constexpr int SL = BN / 4;
#pragma unroll
            for (int it = 0; it < (128 * SL) / 256; ++it) {
                int idx = tid + it * 256;
                int row = idx / SL, sl = idx % SL;
                *(f32x4*)((float*)out0 + (size_t)(m0 + row) * NTOT + n0 + sl * 4)
                    = *(const f32x4*)&Sf[row * BN + sl * 4];
            }
        } else {
            constexpr int SL = BN / 8;
            unsigned short* dst = (unsigned short*)((p == 0) ? out0 : out1);
#pragma unroll
            for (int it = 0; it < (128 * SL) / 256; ++it) {
                int idx = tid + it * 256;
                int row = idx / SL, sl = idx % SL;
                *(short8*)&dst[(size_t)(m0 + row) * NTOT + n0 + sl * 8]
                    = *(const short8*)&Sb[row * BN + sl * 8];
            }
        }
    }
}

// ---------------------------------------------------------------------------
// fp32 vector GEMM (round-3 proven structure) with early-exit on *mrows.
// Used only for the fixup path. ACT: 0 = relu.
// ---------------------------------------------------------------------------
template <int BN, int ACT>
__global__ __launch_bounds__(256) void gemm_f32(
    const int* __restrict__ mrows,
    const float* __restrict__ A, int K,
    const float* __restrict__ W, const float* __restrict__ bias,
    float* __restrict__ Co, int N)
{
    const int m0 = blockIdx.x * 128;
    if (m0 >= *mrows) return;

    constexpr int TN = BN / 16;
    __shared__ float At[16][132];
    __shared__ float Bt[16][BN + 4];

    const int tid = threadIdx.x;
    const int n0 = blockIdx.y * BN;
    const int r = tid >> 4;
    const int c = tid & 15;

    float acc[8][TN];
#pragma unroll
    for (int i = 0; i < 8; ++i)
#pragma unroll
        for (int j = 0; j < TN; ++j) acc[i][j] = 0.f;

    for (int k0 = 0; k0 < K; k0 += 16) {
#pragma unroll
        for (int it = 0; it < 2; ++it) {
            int idx = tid + it * 256;
            int row = idx >> 2;
            int lf = idx & 3;
            int col = k0 + lf * 4;
            float4 v = *(const float4*)(A + (size_t)(m0 + row) * K + col);
            At[lf * 4 + 0][row] = v.x;
            At[lf * 4 + 1][row] = v.y;
            At[lf * 4 + 2][row] = v.z;
            At[lf * 4 + 3][row] = v.w;
        }
        constexpr int NF4 = BN / 4;
        constexpr int NEL = 16 * NF4;
        if constexpr (NEL >= 256) {
#pragma unroll
            for (int it = 0; it < NEL / 256; ++it) {
                int idx = tid + it * 256;
                int kk = idx / NF4;
                int f = idx % NF4;
                float4 v = *(const float4*)(W + (size_t)(k0 + kk) * N + n0 + f * 4);
                *(float4*)&Bt[kk][f * 4] = v;
            }
        } else {
            if (tid < NEL) {
                int kk = tid / NF4;
                int f = tid % NF4;
                float4 v = *(const float4*)(W + (size_t)(k0 + kk) * N + n0 + f * 4);
                *(float4*)&Bt[kk][f * 4] = v;
            }
        }
        __syncthreads();

#pragma unroll
        for (int kk = 0; kk < 16; ++kk) {
            float a[8];
            float4 av0 = *(const float4*)&At[kk][r * 8];
            float4 av1 = *(const float4*)&At[kk][r * 8 + 4];
            a[0] = av0.x; a[1] = av0.y; a[2] = av0.z; a[3] = av0.w;
            a[4] = av1.x; a[5] = av1.y; a[6] = av1.z; a[7] = av1.w;
            float b[TN];
            if constexpr (BN == 128) {
                float4 b0 = *(const float4*)&Bt[kk][c * 4];
                float4 b1 = *(const float4*)&Bt[kk][64 + c * 4];
                b[0] = b0.x; b[1] = b0.y; b[2] = b0.z; b[3] = b0.w;
                b[4] = b1.x; b[5] = b1.y; b[6] = b1.z; b[7] = b1.w;
            } else {
                float4 b0 = *(const float4*)&Bt[kk][c * 4];
                b[0] = b0.x; b[1] = b0.y; b[2] = b0.z; b[3] = b0.w;
            }
#pragma unroll
            for (int i = 0; i < 8; ++i)
#pragma unroll
                for (int j = 0; j < TN; ++j)
                    acc[i][j] = fmaf(a[i], b[j], acc[i][j]);
        }
        __syncthreads();
    }

#pragma unroll
    for (int i = 0; i < 8; ++i) {
        size_t row = (size_t)(m0 + r * 8 + i);
        if constexpr (BN == 128) {
            float e[8];
#pragma unroll
            for (int j = 0; j < 8; ++j) {
                int col = (j < 4) ? (c * 4 + j) : (64 + c * 4 + (j - 4));
                float v = acc[i][j] + bias[n0 + col];
                if (ACT == 0) v = fmaxf(v, 0.f);
                e[j] = v;
            }
            float4 v0, v1;
            v0.x = e[0]; v0.y = e[1]; v0.z = e[2]; v0.w = e[3];
            v1.x = e[4]; v1.y = e[5]; v1.z = e[6]; v1.w = e[7];
            *(float4*)&Co[row * N + n0 + c * 4] = v0;
            *(float4*)&Co[row * N + n0 + 64 + c * 4] = v1;
        } else {
            float e[4];
#pragma unroll
            for (int j = 0; j < 4; ++j) {
                float v = acc[i][j] + bias[n0 + c * 4 + j];
                if (ACT == 0) v = fmaxf(v, 0.f);
                e[j] = v;
            }
            float4 v0;
            v0.x = e[0]; v0.y = e[1]; v0.z = e[2]; v0.w = e[3];
            *(float4*)&Co[row * N + n0 + c * 4] = v0;
        }
    }
}

// ---------------------------------------------------------------------------
__global__ void sa_pre(const float* __restrict__ state, const float* __restrict__ action,
                       unsigned short* __restrict__ saH, unsigned short* __restrict__ saL)
{
    int idx = blockIdx.x * 256 + threadIdx.x;
    int row = idx / 12, q = idx % 12;
    const float* src = (q < 8) ? (state + (size_t)row * 64 + q * 8)
                               : (action + (size_t)row * 32 + (q - 8) * 8);
    f32x4 v0 = *(const f32x4*)src;
    f32x4 v1 = *(const f32x4*)(src + 4);
    short8 h, l;
#pragma unroll
    for (int j = 0; j < 8; ++j) {
        float x = (j < 4) ? v0[j] : v1[j - 4];
        unsigned short hb_ = f2bf(x);
        h[j] = (short)hb_;
        l[j] = (short)f2bf(x - bf2f(hb_));
    }
    *(short8*)&saH[(size_t)row * 96 + q * 8] = h;
    *(short8*)&saL[(size_t)row * 96 + q * 8] = l;
}

__global__ void xz_pre(const float* __restrict__ state, unsigned short* __restrict__ xz)
{
    int idx = blockIdx.x * 256 + threadIdx.x;
    int row = idx >> 4, q = idx & 15;
    f32x4 v = *(const f32x4*)&state[(size_t)row * 64 + q * 4];
    unsigned short o[4];
    o[0] = f2bf(v[0]); o[1] = f2bf(v[1]); o[2] = f2bf(v[2]); o[3] = f2bf(v[3]);
    *(uint2*)&xz[(size_t)row * 128 + q * 4] = *(uint2*)o;
}

// ---------------------------------------------------------------------------
// Fused VQ + latent head.  Flag list stores GLOBAL row ids (rowbase + local).
// ---------------------------------------------------------------------------
__global__ __launch_bounds__(256) void vq_latent(
    const float* __restrict__ midz,
    const float* __restrict__ codebook,
    const float* __restrict__ cbn,
    const float* __restrict__ mean_w, const float* __restrict__ mean_b,
    const float* __restrict__ logstd_w, const float* __restrict__ logstd_b,
    const float* __restrict__ eps,
    float* __restrict__ mean_out,
    float* __restrict__ std_out,
    unsigned short* __restrict__ xz,
    int* __restrict__ ctr, int* __restrict__ list, int rowbase)
{
    __shared__ float smem[13120];
    float* Zt = smem;                    // [64][132]
    float* Ct = smem + 8448;             // [64][68]
    float* cn = smem + 12800;            // [64]
    float* zn = smem + 12864;            // [128]
    int* sidx = (int*)(smem + 12992);    // [128]

    const int tid = threadIdx.x;
    const int m0 = blockIdx.x * 128;
    const int r = tid >> 4;
    const int c = tid & 15;

#pragma unroll
    for (int it = 0; it < 8; ++it) {
        int idx = tid + it * 256;
        int row = idx >> 4;
        int f = idx & 15;
        float4 v = *(const float4*)(midz + (size_t)(m0 + row) * 64 + f * 4);
        Zt[(f * 4 + 0) * 132 + row] = v.x;
        Zt[(f * 4 + 1) * 132 + row] = v.y;
        Zt[(f * 4 + 2) * 132 + row] = v.z;
        Zt[(f * 4 + 3) * 132 + row] = v.w;
    }
    __syncthreads();
    if (tid < 128) {
        float s = 0.f;
#pragma unroll
        for (int k = 0; k < 64; ++k) {
            float v = Zt[k * 132 + tid];
            s = fmaf(v, v, s);
        }
        zn[tid] = s;
    }

    float best[8], sec[8];
    int bidx[8];
#pragma unroll
    for (int i = 0; i < 8; ++i) { best[i] = 3.4e38f; sec[i] = 3.4e38f; bidx[i] = 0x7fffffff; }

    for (int ch = 0; ch < 16; ++ch) {
        int e0 = ch * 64;
        __syncthreads();
#pragma unroll
        for (int it = 0; it < 4; ++it) {
            int idx = tid + it * 256;
            int e = idx >> 4;
            int f = idx & 15;
            float4 v = *(const float4*)(codebook + (size_t)(e0 + e) * 64 + f * 4);
            Ct[(f * 4 + 0) * 68 + e] = v.x;
            Ct[(f * 4 + 1) * 68 + e] = v.y;
            Ct[(f * 4 + 2) * 68 + e] = v.z;
            Ct[(f * 4 + 3) * 68 + e] = v.w;
        }
        if (tid < 64) cn[tid] = cbn[e0 + tid];
        __syncthreads();

        float acc[8][4];
#pragma unroll
        for (int i = 0; i < 8; ++i)
#pragma unroll
            for (int j = 0; j < 4; ++j) acc[i][j] = 0.f;

#pragma unroll 8
        for (int kk = 0; kk < 64; ++kk) {
            float a[8], b[4];
            float4 av0 = *(const float4*)&Zt[kk * 132 + r * 8];
            float4 av1 = *(const float4*)&Zt[kk * 132 + r * 8 + 4];
            a[0] = av0.x; a[1] = av0.y; a[2] = av0.z; a[3] = av0.w;
            a[4] = av1.x; a[5] = av1.y; a[6] = av1.z; a[7] = av1.w;
            float4 bv = *(const float4*)&Ct[kk * 68 + c * 4];
            b[0] = bv.x; b[1] = bv.y; b[2] = bv.z; b[3] = bv.w;
#pragma unroll
            for (int i = 0; i < 8; ++i)
#pragma unroll
                for (int j = 0; j < 4; ++j)
                    acc[i][j] = fmaf(a[i], b[j], acc[i][j]);
        }
#pragma unroll
        for (int i = 0; i < 8; ++i) {
            float zni = zn[r * 8 + i];
#pragma unroll
            for (int j = 0; j < 4; ++j) {
                int e = c * 4 + j;
                float s = (zni + cn[e]) - 2.0f * acc[i][j];
                int gi = e0 + e;
                if (s < best[i] || (s == best[i] && gi < bidx[i])) {
                    sec[i] = best[i];
                    best[i] = s;
                    bidx[i] = gi;
                } else {
                    sec[i] = fminf(sec[i], s);
                }
            }
        }
    }

#pragma unroll
    for (int i = 0; i < 8; ++i) {
#pragma unroll
        for (int m = 1; m < 16; m <<= 1) {
            float ob = __shfl_xor(best[i], m, 64);
            int oi = __shfl_xor(bidx[i], m, 64);
            float os = __shfl_xor(sec[i], m, 64);
            if (ob < best[i] || (ob == best[i] && oi < bidx[i])) {
                sec[i] = fminf(best[i], os);
                best[i] = ob;
                bidx[i] = oi;
            } else {
                sec[i] = fminf(sec[i], ob);
            }
        }
    }
    __syncthreads();
    if (c == 0) {
#pragma unroll
        for (int i = 0; i < 8; ++i) {
            sidx[r * 8 + i] = bidx[i];
            if (sec[i] - best[i] < TAU) {
                int p = atomicAdd(ctr, 1);
                list[p] = rowbase + m0 + r * 8 + i;
            }
        }
    }

    float* mw = smem;
    float* lw = smem + 4160;
#pragma unroll
    for (int it = 0; it < 4; ++it) {
        int idx = tid + it * 256;
        int k = idx >> 4;
        int f = idx & 15;
        float4 v = *(const float4*)(mean_w + (size_t)k * 64 + f * 4);
        mw[k * 65 + f * 4 + 0] = v.x;
        mw[k * 65 + f * 4 + 1] = v.y;
        mw[k * 65 + f * 4 + 2] = v.z;
        mw[k * 65 + f * 4 + 3] = v.w;
        float4 w2 = *(const float4*)(logstd_w + (size_t)k * 64 + f * 4);
        lw[k * 65 + f * 4 + 0] = w2.x;
        lw[k * 65 + f * 4 + 1] = w2.y;
        lw[k * 65 + f * 4 + 2] = w2.z;
        lw[k * 65 + f * 4 + 3] = w2.w;
    }
    __syncthreads();

    {
        int row = tid >> 1;
        int d0 = (tid & 1) * 32;
        int e = sidx[row];
        const float* cb = codebook + (size_t)e * 64;
        float mv[32], lv[32];
#pragma unroll
        for (int d = 0; d < 32; ++d) {
            mv[d] = mean_b[d0 + d];
            lv[d] = logstd_b[d0 + d];
        }
        for (int k = 0; k < 64; ++k) {
            float zk = cb[k];
#pragma unroll
            for (int d = 0; d < 32; ++d) {
                mv[d] = fmaf(zk, mw[k * 65 + d0 + d], mv[d]);
                lv[d] = fmaf(zk, lw[k * 65 + d0 + d], lv[d]);
            }
        }
        size_t ro = (size_t)(m0 + row) * 64 + d0;
        size_t xo = (size_t)(m0 + row) * 128 + 64 + d0;
#pragma unroll
        for (int d = 0; d < 32; ++d) {
            float mean = mv[d];
            float ls = fminf(fmaxf(lv[d], -4.f), 15.f);
            float sd = expf(ls);
            float z = fmaf(sd, eps[ro + d], mean);
            mean_out[ro + d] = mean;
            std_out[ro + d] = sd;
            xz[xo + d] = f2bf(z);
        }
    }
}

// ---------------------------------------------------------------------------
// Gather flagged rows into compact sa_fix [cnt,96]; write padded count meta.
// ---------------------------------------------------------------------------
__global__ void gather_fix(const int* __restrict__ ctr, int* __restrict__ meta,
                           const int* __restrict__ list,
                           const float* __restrict__ state,
                           const float* __restrict__ action,
                           float* __restrict__ sa_fix)
{
    int cnt = *ctr; if (cnt > FMAX) cnt = FMAX;
    if (blockIdx.x == 0 && threadIdx.x == 0)
        meta[0] = (cnt + 127) & ~127;
    int t = blockIdx.x * 256 + threadIdx.x;
    if (t >= cnt * 24) return;
    int f = t / 24, q = t % 24;
    size_t g = (size_t)list[f];
    f32x4 v = (q < 16) ? *(const f32x4*)&state[g * 64 + q * 4]
                       : *(const f32x4*)&action[g * 32 + (q - 16) * 4];
    *(f32x4*)&sa_fix[(size_t)f * 96 + q * 4] = v;
}

// ---------------------------------------------------------------------------
// VQ + latent head on the compact fixed rows; scatter via list.
// ---------------------------------------------------------------------------
__global__ __launch_bounds__(256) void vq_fix(
    const int* __restrict__ ctr, const int* __restrict__ list,
    const float* __restrict__ mz_fix,
    const float* __restrict__ codebook, const float* __restrict__ cbn,
    const float* __restrict__ mean_w, const float* __restrict__ mean_b,
    const float* __restrict__ logstd_w, const float* __restrict__ logstd_b,
    const float* __restrict__ eps,
    float* __restrict__ mean_out, float* __restrict__ std_out,
    unsigned short* __restrict__ xz)
{
    __shared__ float mzs[8][64];
    __shared__ float zns[8];
    __shared__ float sv[2048];
    __shared__ int si[2048];
    __shared__ int am_s[8];

    int cnt = *ctr; if (cnt > FMAX) cnt = FMAX;
    const int base = blockIdx.x * 8;
    if (base >= cnt) return;
    const int nr = min(8, cnt - base);
    const int tid = threadIdx.x;

    if (tid < 128) {
        int rr = tid >> 4, q = tid & 15;
        int src = base + ((rr < nr) ? rr : 0);
        *(f32x4*)&mzs[rr][q * 4] = *(const f32x4*)&mz_fix[(size_t)src * 64 + q * 4];
    }
    __syncthreads();
    if (tid < 8) {
        float s = 0.f;
#pragma unroll
        for (int k = 0; k < 64; ++k) s = fmaf(mzs[tid][k], mzs[tid][k], s);
        zns[tid] = s;
    }
    __syncthreads();

    float bb[8];
    int bi[8];
#pragma unroll
    for (int rr = 0; rr < 8; ++rr) { bb[rr] = 3.4e38f; bi[rr] = 0x7fffffff; }
    for (int j = 0; j < 4; ++j) {
        int code = tid + j * 256;
        const f32x4* cp = (const f32x4*)(codebook + (size_t)code * 64);
        float dot[8];
#pragma unroll
        for (int rr = 0; rr < 8; ++rr) dot[rr] = 0.f;
        for (int t = 0; t < 16; ++t) {
            f32x4 cv = cp[t];
#pragma unroll
            for (int e = 0; e < 4; ++e) {
                float cvv = cv[e];
#pragma unroll
                for (int rr = 0; rr < 8; ++rr)
                    dot[rr] = fmaf(mzs[rr][t * 4 + e], cvv, dot[rr]);
            }
        }
        float cnv = cbn[code];
#pragma unroll
        for (int rr = 0; rr < 8; ++rr) {
            float s = (zns[rr] + cnv) - 2.0f * dot[rr];
            if (s < bb[rr] || (s == bb[rr] && code < bi[rr])) {
                bb[rr] = s; bi[rr] = code;
            }
        }
    }
#pragma unroll
    for (int rr = 0; rr < 8; ++rr) {
        sv[rr * 256 + tid] = bb[rr];
        si[rr * 256 + tid] = bi[rr];
    }
    __syncthreads();
    if (tid < 8) {
        float b = 3.4e38f;
        int ix = 0x7fffffff;
        for (int t = 0; t < 256; ++t) {
            float v = sv[tid * 256 + t];
            int iv = si[tid * 256 + t];
            if (v < b || (v == b && iv < ix)) { b = v; ix = iv; }
        }
        am_s[tid] = ix;
    }
    __syncthreads();

    for (int jo = 0; jo < 2; ++jo) {
        int o = tid + jo * 256;
        int rr = o >> 6, d = o & 63;
        if (rr < nr) {
            int e = am_s[rr];
            size_t g = (size_t)list[base + rr];
            float mv = mean_b[d], lv = logstd_b[d];
            const float* cb = codebook + (size_t)e * 64;
            for (int k = 0; k < 64; ++k) {
                float zk = cb[k];
                mv = fmaf(zk, mean_w[(size_t)k * 64 + d], mv);
                lv = fmaf(zk, logstd_w[(size_t)k * 64 + d], lv);
            }
            float ls = fminf(fmaxf(lv, -4.f), 15.f);
            float sd = expf(ls);
            float z = fmaf(sd, eps[g * 64 + d], mv);
            mean_out[g * 64 + d] = mv;
            std_out[g * 64 + d] = sd;
            xz[g * 128 + 64 + d] = f2bf(z);
        }
    }
}

// ---------------------------------------------------------------------------
extern "C" void kernel_launch(void* const* d_in, const int* in_sizes, int n_in,
                              void* d_out, int out_size, void* d_ws, size_t ws_size,
                              hipStream_t stream)
{
    const float* state    = (const float*)d_in[0];
    const float* action   = (const float*)d_in[1];
    const float* eps      = (const float*)d_in[2];
    const float* enc_w1   = (const float*)d_in[3];
    const float* enc_b1   = (const float*)d_in[4];
    const float* enc_w2   = (const float*)d_in[5];
    const float* enc_b2   = (const float*)d_in[6];
    const float* enc_w3   = (const float*)d_in[7];
    const float* enc_b3   = (const float*)d_in[8];
    const float* mean_w   = (const float*)d_in[9];
    const float* mean_b   = (const float*)d_in[10];
    const float* logstd_w = (const float*)d_in[11];
    const float* logstd_b = (const float*)d_in[12];
    const float* codebook = (const float*)d_in[13];
    const float* dec_w1   = (const float*)d_in[14];
    const float* dec_b1   = (const float*)d_in[15];
    const float* dec_w2   = (const float*)d_in[16];
    const float* dec_b2   = (const float*)d_in[17];
    const float* dec_w3   = (const float*)d_in[18];
    const float* dec_b3   = (const float*)d_in[19];

    float* out = (float*)d_out;
    float* u_out = out;
    float* mean_out = out + (size_t)B_TOTAL * 32;
    float* std_out = mean_out + (size_t)B_TOTAL * 64;

    // ---- fixed ws region ----
    char* base = (char*)d_ws;
    float* cbn = (float*)base;                                   // 4096
    unsigned short* W1h = (unsigned short*)(base + 4096);        // 196608
    unsigned short* W1l = (unsigned short*)(base + 200704);      // 196608
    unsigned short* W2h = (unsigned short*)(base + 397312);      // 2097152
    unsigned short* W2l = (unsigned short*)(base + 2494464);     // 2097152
    unsigned short* W3h = (unsigned short*)(base + 4591616);     // 131072
    unsigned short* W3l = (unsigned short*)(base + 4722688);     // 131072
    unsigned short* W4h = (unsigned short*)(base + 4853760);     // 262144
    unsigned short* W5h = (unsigned short*)(base + 5115904);     // 2097152
    unsigned short* W6h = (unsigned short*)(base + 7213056);     // 65536
    int* ctr            = (int*)(base + 7278592);                // 256
    int* flag_list      = (int*)(base + 7278848);                // 262144
    int* meta           = (int*)(base + 7540992);                // 256
    float* sa_fix       = (float*)(base + 7541248);              // FMAX*96*4   = 6291456
    float* h1_fix       = (float*)(base + 13832704);             // FMAX*1024*4 = 67108864
    float* h2_fix       = (float*)(base + 80941568);             // 67108864
    float* mz_fix       = (float*)(base + 148050432);            // FMAX*64*4   = 4194304
    const size_t FIXED  = 152244736;

    // global xz plane [B_TOTAL, 128] bf16 (decoder input, fixup target)
    unsigned short* xz_g = (unsigned short*)(base + FIXED);      // 16 MB
    const size_t XZ_SZ = (size_t)B_TOTAL * 128 * 2;

    // per-chunk: saH 192 + saL 192 + h1H/h1L/h2H/h2L 2048ea + mz 256 = 8832 B
    const size_t per_row = 8832;
    size_t avail = (ws_size > FIXED + XZ_SZ) ? (ws_size - FIXED - XZ_SZ) : 0;
    long maxC = (long)(avail / per_row);
    int C = (int)(maxC / 1024) * 1024;
    if (C > B_TOTAL) C = B_TOTAL;
    if (C < 1024) C = 1024;

    char* dyn = base + FIXED + XZ_SZ;
    unsigned short* saH = (unsigned short*)dyn;                   // [C,96]
    unsigned short* saL = saH + (size_t)C * 96;
    unsigned short* h1H = saL + (size_t)C * 96;                   // [C,1024]
    unsigned short* h1L = h1H + (size_t)C * 1024;
    unsigned short* h2H = h1L + (size_t)C * 1024;
    unsigned short* h2L = h2H + (size_t)C * 1024;
    float* mz = (float*)(h2L + (size_t)C * 1024);                 // [C,64]
    unsigned short* hc = h1H;   // decoder reuse
    unsigned short* hd = h2H;

    // ---- once per call ----
    cb_norms<<<dim3(4), dim3(256), 0, stream>>>(codebook, cbn);
    zero_ctr<<<dim3(1), dim3(64), 0, stream>>>(ctr);
    w_xform<3, 128><<<dim3(3, 8), dim3(256), 0, stream>>>(enc_w1, 96, 1024, W1h, W1l);
    w_xform<3, 128><<<dim3(32, 8), dim3(256), 0, stream>>>(enc_w2, 1024, 1024, W2h, W2l);
    w_xform<3, 64><<<dim3(32, 1), dim3(256), 0, stream>>>(enc_w3, 1024, 64, W3h, W3l);
    w_xform<1, 128><<<dim3(4, 8), dim3(256), 0, stream>>>(dec_w1, 128, 1024, W4h, nullptr);
    w_xform<1, 128><<<dim3(32, 8), dim3(256), 0, stream>>>(dec_w2, 1024, 1024, W5h, nullptr);
    w_xform<1, 32><<<dim3(32, 1), dim3(256), 0, stream>>>(dec_w3, 1024, 32, W6h, nullptr);

    // ---- phase A: encoder + VQ for all chunks ----
    for (int r0 = 0; r0 < B_TOTAL; r0 += C) {
        int M = (r0 + C <= B_TOTAL) ? C : (B_TOTAL - r0);
        int mt = M / 128;          // multiple of 8 (M multiple of 1024)

        sa_pre<<<dim3(M * 12 / 256), dim3(256), 0, stream>>>(
            state + (size_t)r0 * SDIM, action + (size_t)r0 * ADIM, saH, saL);

        mfma_gemm<3, 128, 0, 0><<<dim3(mt * 8), dim3(256), 0, stream>>>(
            saH, saL, 96, W1h, W1l, enc_b1, h1H, h1L, 1024);
        mfma_gemm<3, 128, 0, 0><<<dim3(mt * 8), dim3(256), 0, stream>>>(
            h1H, h1L, 1024, W2h, W2l, enc_b2, h2H, h2L, 1024);
        mfma_gemm<3, 64, 2, 0><<<dim3(mt), dim3(256), 0, stream>>>(
            h2H, h2L, 1024, W3h, W3l, enc_b3, mz, nullptr, 64);

        xz_pre<<<dim3(M / 16), dim3(256), 0, stream>>>(
            state + (size_t)r0 * SDIM, xz_g + (size_t)r0 * 128);

        vq_latent<<<dim3(mt), dim3(256), 0, stream>>>(
            mz, codebook, cbn, mean_w, mean_b, logstd_w, logstd_b,
            eps + (size_t)r0 * LDIM,
            mean_out + (size_t)r0 * LDIM, std_out + (size_t)r0 * LDIM,
            xz_g + (size_t)r0 * 128, ctr, flag_list, r0);
    }

    // ---- phase B: exact-fp32 fixup as dense GEMMs on gathered rows ----
    gather_fix<<<dim3(FMAX * 24 / 256), dim3(256), 0, stream>>>(
        ctr, meta, flag_list, state, action, sa_fix);
    gemm_f32<128, 0><<<dim3(FMAX / 128, 8), dim3(256), 0, stream>>>(
        meta, sa_fix, 96, enc_w1, enc_b1, h1_fix, 1024);
    gemm_f32<128, 0><<<dim3(FMAX / 128, 8), dim3(256), 0, stream>>>(
        meta, h1_fix, 1024, enc_w2, enc_b2, h2_fix, 1024);
    gemm_f32<64, 0><<<dim3(FMAX / 128, 1), dim3(256), 0, stream>>>(
        meta, h2_fix, 1024, enc_w3, enc_b3, mz_fix, 64);
    vq_fix<<<dim3(FMAX / 8), dim3(256), 0, stream>>>(
        ctr, flag_list, mz_fix, codebook, cbn,
        mean_w, mean_b, logstd_w, logstd_b, eps,
        mean_out, std_out, xz_g);

    // ---- phase C: decoder for all chunks ----
    for (int r0 = 0; r0 < B_TOTAL; r0 += C) {
        int M = (r0 + C <= B_TOTAL) ? C : (B_TOTAL - r0);
        int mt = M / 128;

        mfma_gemm<1, 128, 1, 0><<<dim3(mt * 8), dim3(256), 0, stream>>>(
            xz_g + (size_t)r0 * 128, nullptr, 128, W4h, nullptr, dec_b1, hc, nullptr, 1024);
        mfma_gemm<1, 128, 1, 0><<<dim3(mt * 8), dim3(256), 0, stream>>>(
            hc, nullptr, 1024, W5h, nullptr, dec_b2, hd, nullptr, 1024);
        mfma_gemm<1, 32, 2, 1><<<dim3(mt), dim3(256), 0, stream>>>(
            hd, nullptr, 1024, W6h, nullptr, dec_b3,
            u_out + (size_t)r0 * ADIM, nullptr, 32);
    }
}

// Round 9
// 2097.247 us; speedup vs baseline: 1.4495x; 1.4495x over previous
//
#include <hip/hip_runtime.h>
#include <cstdint>
#include <cstddef>

#define B_TOTAL 65536
#define SDIM 64
#define ADIM 32
#define LDIM 64
#define HDIM 1024
#define NEMB 1024
#define TAU 0.125f
#define FMAX 6144

typedef __attribute__((ext_vector_type(8))) short short8;
typedef __attribute__((ext_vector_type(4))) float f32x4;

__device__ inline unsigned short f2bf(float f) {
    unsigned int u = __float_as_uint(f);
    u += 0x7fffu + ((u >> 16) & 1u);
    return (unsigned short)(u >> 16);
}
__device__ inline float bf2f(unsigned short s) {
    return __uint_as_float(((unsigned int)s) << 16);
}

// async global->LDS, 16B per lane; LDS dest = wave-uniform base + lane*16.
__device__ inline void gload16(const unsigned short* g, unsigned short* l) {
    __builtin_amdgcn_global_load_lds(
        (__attribute__((address_space(1))) void*)(g),
        (__attribute__((address_space(3))) void*)(l), 16, 0, 0);
}

// ---------------------------------------------------------------------------
__global__ void cb_norms(const float* __restrict__ codebook, float* __restrict__ cbn)
{
    int i = blockIdx.x * 256 + threadIdx.x;
    if (i < NEMB) {
        float s = 0.f;
#pragma unroll
        for (int k = 0; k < LDIM; ++k) {
            float v = codebook[(size_t)i * LDIM + k];
            s = fmaf(v, v, s);
        }
        cbn[i] = s;
    }
}

__global__ void zero_ctr(int* ctr) { if (threadIdx.x == 0) *ctr = 0; }

// ---------------------------------------------------------------------------
// Weight pre-transform: W[K][N] fp32 -> bf16 plane(s), MFMA-B-ready layout.
// ---------------------------------------------------------------------------
template <int NT, int BN>
__global__ __launch_bounds__(256) void w_xform(
    const float* __restrict__ W, int K, int N,
    unsigned short* __restrict__ Ph, unsigned short* __restrict__ Pl)
{
    __shared__ float Ws[32][BN + 4];
    const int tid = threadIdx.x;
    const int ks = blockIdx.x, nb = blockIdx.y;
    const int k0 = ks * 32, n0 = nb * BN;
    constexpr int LT = 32 * (BN / 4);
#pragma unroll
    for (int it = 0; it < (LT + 255) / 256; ++it) {
        int idx = tid + it * 256;
        if (LT % 256 == 0 || idx < LT) {
            int k = idx / (BN / 4);
            int nf = idx % (BN / 4);
            *(f32x4*)&Ws[k][nf * 4] =
                *(const f32x4*)&W[(size_t)(k0 + k) * N + n0 + nf * 4];
        }
    }
    __syncthreads();
    const int KS = K >> 5;
    size_t bo = ((size_t)nb * KS + ks) * (BN * 32);
    constexpr int WT = BN * 4;
#pragma unroll
    for (int it = 0; it < (WT + 255) / 256; ++it) {
        int idx = tid + it * 256;
        if (WT % 256 == 0 || idx < WT) {
            int kb = idx / BN;
            int n = idx % BN;
            short8 h, l;
#pragma unroll
            for (int j = 0; j < 8; ++j) {
                float x = Ws[kb * 8 + j][n];
                unsigned short hb_ = f2bf(x);
                h[j] = (short)hb_;
                if (NT == 3) l[j] = (short)f2bf(x - bf2f(hb_));
            }
            *(short8*)&Ph[bo + (size_t)idx * 8] = h;
            if (NT == 3) *(short8*)&Pl[bo + (size_t)idx * 8] = l;
        }
    }
}

// ---------------------------------------------------------------------------
// BF16 MFMA GEMM, double-buffered prefetch + XCD swizzle (unchanged, proven).
// ---------------------------------------------------------------------------
template <int NT, int BN, int OUT, int ACT>
__global__ __launch_bounds__(256, 2) void mfma_gemm(
    const unsigned short* __restrict__ Ah_g, const unsigned short* __restrict__ Al_g,
    int K,
    const unsigned short* __restrict__ Wh, const unsigned short* __restrict__ Wl,
    const float* __restrict__ bias,
    void* __restrict__ out0, void* __restrict__ out1, int NTOT)
{
    constexpr int NWC = (BN == 128) ? 2 : 1;
    constexpr int WM = (BN == 128) ? 4 : 2;
    constexpr int WN = (BN == 32) ? 2 : 4;
    constexpr int ABUF = (NT == 3) ? 8192 : 4096;           // shorts per buffer (A)
    constexpr int BBUF = 4 * BN * 8 * ((NT == 3) ? 2 : 1);  // shorts per buffer (B)
    constexpr int BUFSH = ABUF + BBUF;

    __shared__ unsigned short smem[2 * BUFSH];

    const int tid = threadIdx.x;
    int row_t, nb;
    if constexpr (BN == 128) {
        int per = gridDim.x >> 3;        // == mt (mt % 8 == 0 guaranteed by host)
        int xcd = blockIdx.x & 7;
        int lid = blockIdx.x >> 3;
        int tile = xcd * per + lid;
        row_t = tile >> 3;
        nb = tile & 7;
    } else {
        row_t = blockIdx.x;
        nb = 0;
    }
    const int m0 = row_t * 128;
    const int n0 = nb * BN;
    const int w = tid >> 6, lane = tid & 63;
    const int g = lane >> 4, lr = lane & 15;
    const int wrow0 = (w / NWC) * (WM * 16);
    const int wcol0 = (w % NWC) * (WN * 16);
    const int KS = K >> 5;

    auto stage = [&](unsigned short* buf, int ks) {
        unsigned short* Ah = buf;
        unsigned short* Al = buf + 4096;
        unsigned short* Bh = buf + ABUF;
        unsigned short* Bl = Bh + 4 * BN * 8;
#pragma unroll
        for (int it = 0; it < 2; ++it) {
            int t0 = it * 256 + w * 64;
            int t = t0 + lane;
            int row = t & 127, kb = t >> 7;
            size_t go = (size_t)(m0 + row) * K + ks * 32 + kb * 8;
            gload16(Ah_g + go, Ah + (size_t)t0 * 8);
            if constexpr (NT == 3) gload16(Al_g + go, Al + (size_t)t0 * 8);
        }
        size_t bo = ((size_t)nb * KS + ks) * (BN * 32);
        constexpr int BT = 4 * BN;
        if constexpr (BT >= 256) {
#pragma unroll
            for (int it = 0; it < BT / 256; ++it) {
                int t0 = it * 256 + w * 64;
                size_t go = bo + (size_t)(t0 + lane) * 8;
                gload16(Wh + go, Bh + (size_t)t0 * 8);
                if constexpr (NT == 3) gload16(Wl + go, Bl + (size_t)t0 * 8);
            }
        } else {
            if (tid < BT) {
                int t0 = w * 64;
                size_t go = bo + (size_t)(t0 + lane) * 8;
                gload16(Wh + go, Bh + (size_t)t0 * 8);
                if constexpr (NT == 3) gload16(Wl + go, Bl + (size_t)t0 * 8);
            }
        }
    };

    f32x4 acc[WM][WN];
#pragma unroll
    for (int m = 0; m < WM; ++m)
#pragma unroll
        for (int n = 0; n < WN; ++n) {
            acc[m][n][0] = 0.f; acc[m][n][1] = 0.f;
            acc[m][n][2] = 0.f; acc[m][n][3] = 0.f;
        }

    stage(smem, 0);   // prologue into buffer 0

    for (int ks = 0; ks < KS; ++ks) {
        __syncthreads();   // drains vmcnt: buf[cur] staged (issued a full phase ago)
        unsigned short* buf = smem + (size_t)(ks & 1) * BUFSH;
        if (ks + 1 < KS)
            stage(smem + (size_t)((ks + 1) & 1) * BUFSH, ks + 1);   // flies during MFMA

        unsigned short* Ah = buf;
        unsigned short* Al = buf + 4096;
        unsigned short* Bh = buf + ABUF;
        unsigned short* Bl = Bh + 4 * BN * 8;

        short8 ah[WM], bh[WN];
        short8 al[WM], bl[WN];
#pragma unroll
        for (int m = 0; m < WM; ++m) {
            int ro = (g << 7) + wrow0 + m * 16 + lr;
            ah[m] = *(const short8*)&Ah[ro * 8];
            if constexpr (NT == 3) al[m] = *(const short8*)&Al[ro * 8];
        }
#pragma unroll
        for (int n = 0; n < WN; ++n) {
            int co = g * BN + wcol0 + n * 16 + lr;
            bh[n] = *(const short8*)&Bh[co * 8];
            if constexpr (NT == 3) bl[n] = *(const short8*)&Bl[co * 8];
        }
#pragma unroll
        for (int m = 0; m < WM; ++m)
#pragma unroll
            for (int n = 0; n < WN; ++n) {
                acc[m][n] = __builtin_amdgcn_mfma_f32_16x16x32_bf16(
                    ah[m], bh[n], acc[m][n], 0, 0, 0);
                if constexpr (NT == 3) {
                    acc[m][n] = __builtin_amdgcn_mfma_f32_16x16x32_bf16(
                        ah[m], bl[n], acc[m][n], 0, 0, 0);
                    acc[m][n] = __builtin_amdgcn_mfma_f32_16x16x32_bf16(
                        al[m], bh[n], acc[m][n], 0, 0, 0);
                }
            }
    }

    // ---- epilogue: bias + act, LDS transpose, coalesced stores ----
    float bv[WN];
#pragma unroll
    for (int n = 0; n < WN; ++n) bv[n] = bias[n0 + wcol0 + n * 16 + lr];

    unsigned short* Sb = smem;
    float* Sf = (float*)smem;
    constexpr int NPASS = (OUT == 0) ? 2 : 1;

#pragma unroll
    for (int p = 0; p < NPASS; ++p) {
        __syncthreads();
#pragma unroll
        for (int m = 0; m < WM; ++m)
#pragma unroll
            for (int n = 0; n < WN; ++n)
#pragma unroll
                for (int q = 0; q < 4; ++q) {
                    int rl = wrow0 + m * 16 + g * 4 + q;
                    int cl = wcol0 + n * 16 + lr;
                    float x = acc[m][n][q] + bv[n];
                    if (ACT == 0) x = fmaxf(x, 0.f);
                    else x = tanhf(x);
                    if constexpr (OUT == 2) {
                        Sf[rl * BN + cl] = x;
                    } else {
                        unsigned short hb_ = f2bf(x);
                        Sb[rl * BN + cl] = (p == 0) ? hb_ : f2bf(x - bf2f(hb_));
                    }
                }
        __syncthreads();
        if constexpr (OUT == 2) {
            constexpr int SL = BN / 4;
#pragma unroll
            for (int it = 0; it < (128 * SL) / 256; ++it) {
                int idx = tid + it * 256;
                int row = idx / SL, sl = idx % SL;
                *(f32x4*)((float*)out0 + (size_t)(m0 + row) * NTOT + n0 + sl * 4)
                    = *(const f32x4*)&Sf[row * BN + sl * 4];
            }
        } else {
            constexpr int SL = BN / 8;
            unsigned short* dst = (unsigned short*)((p == 0) ? out0 : out1);
#pragma unroll
            for (int it = 0; it < (128 * SL) / 256; ++it) {
                int idx = tid + it * 256;
                int row = idx / SL, sl = idx % SL;
                *(short8*)&dst[(size_t)(m0 + row) * NTOT + n0 + sl * 8]
                    = *(const short8*)&Sb[row * BN + sl * 8];
            }
        }
    }
}

// ---------------------------------------------------------------------------
// fp32 fixup GEMM, 32-row tiles for tile-parallelism at small M.
// 256 threads = 16x16; each thread 2 rows x TN cols. ~40 VGPR, 9 KB LDS ->
// multiple blocks/CU so staging latency hides under other blocks' compute
// (round-8's 128-row version had 232 blocks -> 1 wave/SIMD -> 253 us).
// ---------------------------------------------------------------------------
template <int BN, int ACT>
__global__ __launch_bounds__(256) void gemm_fix(
    const int* __restrict__ mrows,
    const float* __restrict__ A, int K,
    const float* __restrict__ W, const float* __restrict__ bias,
    float* __restrict__ Co, int N)
{
    const int m0 = blockIdx.x * 32;
    if (m0 >= *mrows) return;

    constexpr int TN = BN / 16;
    __shared__ float At[16][36];
    __shared__ float Bt[16][BN + 4];

    const int tid = threadIdx.x;
    const int n0 = blockIdx.y * BN;
    const int r = tid >> 4;
    const int c = tid & 15;

    float acc[2][TN];
#pragma unroll
    for (int i = 0; i < 2; ++i)
#pragma unroll
        for (int j = 0; j < TN; ++j) acc[i][j] = 0.f;

    for (int k0 = 0; k0 < K; k0 += 16) {
        // stage A: 32 rows x 16 cols (transposed), 128 float4 tasks
        if (tid < 128) {
            int row = tid >> 2;
            int lf = tid & 3;
            float4 v = *(const float4*)(A + (size_t)(m0 + row) * K + k0 + lf * 4);
            At[lf * 4 + 0][row] = v.x;
            At[lf * 4 + 1][row] = v.y;
            At[lf * 4 + 2][row] = v.z;
            At[lf * 4 + 3][row] = v.w;
        }
        // stage B: 16 x BN
        constexpr int NF4 = BN / 4;
        constexpr int NEL = 16 * NF4;
#pragma unroll
        for (int it = 0; it < NEL / 256; ++it) {
            int idx = tid + it * 256;
            int kk = idx / NF4;
            int f = idx % NF4;
            float4 v = *(const float4*)(W + (size_t)(k0 + kk) * N + n0 + f * 4);
            *(float4*)&Bt[kk][f * 4] = v;
        }
        __syncthreads();

#pragma unroll
        for (int kk = 0; kk < 16; ++kk) {
            float a0 = At[kk][r * 2];
            float a1 = At[kk][r * 2 + 1];
            float b[TN];
            if constexpr (BN == 128) {
                float4 b0 = *(const float4*)&Bt[kk][c * 4];
                float4 b1 = *(const float4*)&Bt[kk][64 + c * 4];
                b[0] = b0.x; b[1] = b0.y; b[2] = b0.z; b[3] = b0.w;
                b[4] = b1.x; b[5] = b1.y; b[6] = b1.z; b[7] = b1.w;
            } else {
                float4 b0 = *(const float4*)&Bt[kk][c * 4];
                b[0] = b0.x; b[1] = b0.y; b[2] = b0.z; b[3] = b0.w;
            }
#pragma unroll
            for (int j = 0; j < TN; ++j) {
                acc[0][j] = fmaf(a0, b[j], acc[0][j]);
                acc[1][j] = fmaf(a1, b[j], acc[1][j]);
            }
        }
        __syncthreads();
    }

#pragma unroll
    for (int i = 0; i < 2; ++i) {
        size_t row = (size_t)(m0 + r * 2 + i);
        if constexpr (BN == 128) {
            float e[8];
#pragma unroll
            for (int j = 0; j < 8; ++j) {
                int col = (j < 4) ? (c * 4 + j) : (64 + c * 4 + (j - 4));
                float v = acc[i][j] + bias[n0 + col];
                if (ACT == 0) v = fmaxf(v, 0.f);
                e[j] = v;
            }
            float4 v0, v1;
            v0.x = e[0]; v0.y = e[1]; v0.z = e[2]; v0.w = e[3];
            v1.x = e[4]; v1.y = e[5]; v1.z = e[6]; v1.w = e[7];
            *(float4*)&Co[row * N + n0 + c * 4] = v0;
            *(float4*)&Co[row * N + n0 + 64 + c * 4] = v1;
        } else {
            float e[4];
#pragma unroll
            for (int j = 0; j < 4; ++j) {
                float v = acc[i][j] + bias[n0 + c * 4 + j];
                if (ACT == 0) v = fmaxf(v, 0.f);
                e[j] = v;
            }
            float4 v0;
            v0.x = e[0]; v0.y = e[1]; v0.z = e[2]; v0.w = e[3];
            *(float4*)&Co[row * N + n0 + c * 4] = v0;
        }
    }
}

// ---------------------------------------------------------------------------
__global__ void sa_pre(const float* __restrict__ state, const float* __restrict__ action,
                       unsigned short* __restrict__ saH, unsigned short* __restrict__ saL)
{
    int idx = blockIdx.x * 256 + threadIdx.x;
    int row = idx / 12, q = idx % 12;
    const float* src = (q < 8) ? (state + (size_t)row * 64 + q * 8)
                               : (action + (size_t)row * 32 + (q - 8) * 8);
    f32x4 v0 = *(const f32x4*)src;
    f32x4 v1 = *(const f32x4*)(src + 4);
    short8 h, l;
#pragma unroll
    for (int j = 0; j < 8; ++j) {
        float x = (j < 4) ? v0[j] : v1[j - 4];
        unsigned short hb_ = f2bf(x);
        h[j] = (short)hb_;
        l[j] = (short)f2bf(x - bf2f(hb_));
    }
    *(short8*)&saH[(size_t)row * 96 + q * 8] = h;
    *(short8*)&saL[(size_t)row * 96 + q * 8] = l;
}

__global__ void xz_pre(const float* __restrict__ state, unsigned short* __restrict__ xz)
{
    int idx = blockIdx.x * 256 + threadIdx.x;
    int row = idx >> 4, q = idx & 15;
    f32x4 v = *(const f32x4*)&state[(size_t)row * 64 + q * 4];
    unsigned short o[4];
    o[0] = f2bf(v[0]); o[1] = f2bf(v[1]); o[2] = f2bf(v[2]); o[3] = f2bf(v[3]);
    *(uint2*)&xz[(size_t)row * 128 + q * 4] = *(uint2*)o;
}

// ---------------------------------------------------------------------------
// Fused VQ + latent head.  Flag list stores GLOBAL row ids (rowbase + local).
// ---------------------------------------------------------------------------
__global__ __launch_bounds__(256) void vq_latent(
    const float* __restrict__ midz,
    const float* __restrict__ codebook,
    const float* __restrict__ cbn,
    const float* __restrict__ mean_w, const float* __restrict__ mean_b,
    const float* __restrict__ logstd_w, const float* __restrict__ logstd_b,
    const float* __restrict__ eps,
    float* __restrict__ mean_out,
    float* __restrict__ std_out,
    unsigned short* __restrict__ xz,
    int* __restrict__ ctr, int* __restrict__ list, int rowbase)
{
    __shared__ float smem[13120];
    float* Zt = smem;                    // [64][132]
    float* Ct = smem + 8448;             // [64][68]
    float* cn = smem + 12800;            // [64]
    float* zn = smem + 12864;            // [128]
    int* sidx = (int*)(smem + 12992);    // [128]

    const int tid = threadIdx.x;
    const int m0 = blockIdx.x * 128;
    const int r = tid >> 4;
    const int c = tid & 15;

#pragma unroll
    for (int it = 0; it < 8; ++it) {
        int idx = tid + it * 256;
        int row = idx >> 4;
        int f = idx & 15;
        float4 v = *(const float4*)(midz + (size_t)(m0 + row) * 64 + f * 4);
        Zt[(f * 4 + 0) * 132 + row] = v.x;
        Zt[(f * 4 + 1) * 132 + row] = v.y;
        Zt[(f * 4 + 2) * 132 + row] = v.z;
        Zt[(f * 4 + 3) * 132 + row] = v.w;
    }
    __syncthreads();
    if (tid < 128) {
        float s = 0.f;
#pragma unroll
        for (int k = 0; k < 64; ++k) {
            float v = Zt[k * 132 + tid];
            s = fmaf(v, v, s);
        }
        zn[tid] = s;
    }

    float best[8], sec[8];
    int bidx[8];
#pragma unroll
    for (int i = 0; i < 8; ++i) { best[i] = 3.4e38f; sec[i] = 3.4e38f; bidx[i] = 0x7fffffff; }

    for (int ch = 0; ch < 16; ++ch) {
        int e0 = ch * 64;
        __syncthreads();
#pragma unroll
        for (int it = 0; it < 4; ++it) {
            int idx = tid + it * 256;
            int e = idx >> 4;
            int f = idx & 15;
            float4 v = *(const float4*)(codebook + (size_t)(e0 + e) * 64 + f * 4);
            Ct[(f * 4 + 0) * 68 + e] = v.x;
            Ct[(f * 4 + 1) * 68 + e] = v.y;
            Ct[(f * 4 + 2) * 68 + e] = v.z;
            Ct[(f * 4 + 3) * 68 + e] = v.w;
        }
        if (tid < 64) cn[tid] = cbn[e0 + tid];
        __syncthreads();

        float acc[8][4];
#pragma unroll
        for (int i = 0; i < 8; ++i)
#pragma unroll
            for (int j = 0; j < 4; ++j) acc[i][j] = 0.f;

#pragma unroll 8
        for (int kk = 0; kk < 64; ++kk) {
            float a[8], b[4];
            float4 av0 = *(const float4*)&Zt[kk * 132 + r * 8];
            float4 av1 = *(const float4*)&Zt[kk * 132 + r * 8 + 4];
            a[0] = av0.x; a[1] = av0.y; a[2] = av0.z; a[3] = av0.w;
            a[4] = av1.x; a[5] = av1.y; a[6] = av1.z; a[7] = av1.w;
            float4 bv = *(const float4*)&Ct[kk * 68 + c * 4];
            b[0] = bv.x; b[1] = bv.y; b[2] = bv.z; b[3] = bv.w;
#pragma unroll
            for (int i = 0; i < 8; ++i)
#pragma unroll
                for (int j = 0; j < 4; ++j)
                    acc[i][j] = fmaf(a[i], b[j], acc[i][j]);
        }
#pragma unroll
        for (int i = 0; i < 8; ++i) {
            float zni = zn[r * 8 + i];
#pragma unroll
            for (int j = 0; j < 4; ++j) {
                int e = c * 4 + j;
                float s = (zni + cn[e]) - 2.0f * acc[i][j];
                int gi = e0 + e;
                if (s < best[i] || (s == best[i] && gi < bidx[i])) {
                    sec[i] = best[i];
                    best[i] = s;
                    bidx[i] = gi;
                } else {
                    sec[i] = fminf(sec[i], s);
                }
            }
        }
    }

#pragma unroll
    for (int i = 0; i < 8; ++i) {
#pragma unroll
        for (int m = 1; m < 16; m <<= 1) {
            float ob = __shfl_xor(best[i], m, 64);
            int oi = __shfl_xor(bidx[i], m, 64);
            float os = __shfl_xor(sec[i], m, 64);
            if (ob < best[i] || (ob == best[i] && oi < bidx[i])) {
                sec[i] = fminf(best[i], os);
                best[i] = ob;
                bidx[i] = oi;
            } else {
                sec[i] = fminf(sec[i], ob);
            }
        }
    }
    __syncthreads();
    if (c == 0) {
#pragma unroll
        for (int i = 0; i < 8; ++i) {
            sidx[r * 8 + i] = bidx[i];
            if (sec[i] - best[i] < TAU) {
                int p = atomicAdd(ctr, 1);
                list[p] = rowbase + m0 + r * 8 + i;
            }
        }
    }

    float* mw = smem;
    float* lw = smem + 4160;
#pragma unroll
    for (int it = 0; it < 4; ++it) {
        int idx = tid + it * 256;
        int k = idx >> 4;
        int f = idx & 15;
        float4 v = *(const float4*)(mean_w + (size_t)k * 64 + f * 4);
        mw[k * 65 + f * 4 + 0] = v.x;
        mw[k * 65 + f * 4 + 1] = v.y;
        mw[k * 65 + f * 4 + 2] = v.z;
        mw[k * 65 + f * 4 + 3] = v.w;
        float4 w2 = *(const float4*)(logstd_w + (size_t)k * 64 + f * 4);
        lw[k * 65 + f * 4 + 0] = w2.x;
        lw[k * 65 + f * 4 + 1] = w2.y;
        lw[k * 65 + f * 4 + 2] = w2.z;
        lw[k * 65 + f * 4 + 3] = w2.w;
    }
    __syncthreads();

    {
        int row = tid >> 1;
        int d0 = (tid & 1) * 32;
        int e = sidx[row];
        const float* cb = codebook + (size_t)e * 64;
        float mv[32], lv[32];
#pragma unroll
        for (int d = 0; d < 32; ++d) {
            mv[d] = mean_b[d0 + d];
            lv[d] = logstd_b[d0 + d];
        }
        for (int k = 0; k < 64; ++k) {
            float zk = cb[k];
#pragma unroll
            for (int d = 0; d < 32; ++d) {
                mv[d] = fmaf(zk, mw[k * 65 + d0 + d], mv[d]);
                lv[d] = fmaf(zk, lw[k * 65 + d0 + d], lv[d]);
            }
        }
        size_t ro = (size_t)(m0 + row) * 64 + d0;
        size_t xo = (size_t)(m0 + row) * 128 + 64 + d0;
#pragma unroll
        for (int d = 0; d < 32; ++d) {
            float mean = mv[d];
            float ls = fminf(fmaxf(lv[d], -4.f), 15.f);
            float sd = expf(ls);
            float z = fmaf(sd, eps[ro + d], mean);
            mean_out[ro + d] = mean;
            std_out[ro + d] = sd;
            xz[xo + d] = f2bf(z);
        }
    }
}

// ---------------------------------------------------------------------------
// Gather flagged rows into compact sa_fix [cnt,96]; write padded count meta.
// ---------------------------------------------------------------------------
__global__ void gather_fix(const int* __restrict__ ctr, int* __restrict__ meta,
                           const int* __restrict__ list,
                           const float* __restrict__ state,
                           const float* __restrict__ action,
                           float* __restrict__ sa_fix)
{
    int cnt = *ctr; if (cnt > FMAX) cnt = FMAX;
    if (blockIdx.x == 0 && threadIdx.x == 0)
        meta[0] = (cnt + 31) & ~31;
    int t = blockIdx.x * 256 + threadIdx.x;
    if (t >= cnt * 24) return;
    int f = t / 24, q = t % 24;
    size_t g = (size_t)list[f];
    f32x4 v = (q < 16) ? *(const f32x4*)&state[g * 64 + q * 4]
                       : *(const f32x4*)&action[g * 32 + (q - 16) * 4];
    *(f32x4*)&sa_fix[(size_t)f * 96 + q * 4] = v;
}

// ---------------------------------------------------------------------------
// VQ + latent head on the compact fixed rows; scatter via list.
// ---------------------------------------------------------------------------
__global__ __launch_bounds__(256) void vq_fix(
    const int* __restrict__ ctr, const int* __restrict__ list,
    const float* __restrict__ mz_fix,
    const float* __restrict__ codebook, const float* __restrict__ cbn,
    const float* __restrict__ mean_w, const float* __restrict__ mean_b,
    const float* __restrict__ logstd_w, const float* __restrict__ logstd_b,
    const float* __restrict__ eps,
    float* __restrict__ mean_out, float* __restrict__ std_out,
    unsigned short* __restrict__ xz)
{
    __shared__ float mzs[8][64];
    __shared__ float zns[8];
    __shared__ float sv[2048];
    __shared__ int si[2048];
    __shared__ int am_s[8];

    int cnt = *ctr; if (cnt > FMAX) cnt = FMAX;
    const int base = blockIdx.x * 8;
    if (base >= cnt) return;
    const int nr = min(8, cnt - base);
    const int tid = threadIdx.x;

    if (tid < 128) {
        int rr = tid >> 4, q = tid & 15;
        int src = base + ((rr < nr) ? rr : 0);
        *(f32x4*)&mzs[rr][q * 4] = *(const f32x4*)&mz_fix[(size_t)src * 64 + q * 4];
    }
    __syncthreads();
    if (tid < 8) {
        float s = 0.f;
#pragma unroll
        for (int k = 0; k < 64; ++k) s = fmaf(mzs[tid][k], mzs[tid][k], s);
        zns[tid] = s;
    }
    __syncthreads();

    float bb[8];
    int bi[8];
#pragma unroll
    for (int rr = 0; rr < 8; ++rr) { bb[rr] = 3.4e38f; bi[rr] = 0x7fffffff; }
    for (int j = 0; j < 4; ++j) {
        int code = tid + j * 256;
        const f32x4* cp = (const f32x4*)(codebook + (size_t)code * 64);
        float dot[8];
#pragma unroll
        for (int rr = 0; rr < 8; ++rr) dot[rr] = 0.f;
        for (int t = 0; t < 16; ++t) {
            f32x4 cv = cp[t];
#pragma unroll
            for (int e = 0; e < 4; ++e) {
                float cvv = cv[e];
#pragma unroll
                for (int rr = 0; rr < 8; ++rr)
                    dot[rr] = fmaf(mzs[rr][t * 4 + e], cvv, dot[rr]);
            }
        }
        float cnv = cbn[code];
#pragma unroll
        for (int rr = 0; rr < 8; ++rr) {
            float s = (zns[rr] + cnv) - 2.0f * dot[rr];
            if (s < bb[rr] || (s == bb[rr] && code < bi[rr])) {
                bb[rr] = s; bi[rr] = code;
            }
        }
    }
#pragma unroll
    for (int rr = 0; rr < 8; ++rr) {
        sv[rr * 256 + tid] = bb[rr];
        si[rr * 256 + tid] = bi[rr];
    }
    __syncthreads();
    if (tid < 8) {
        float b = 3.4e38f;
        int ix = 0x7fffffff;
        for (int t = 0; t < 256; ++t) {
            float v = sv[tid * 256 + t];
            int iv = si[tid * 256 + t];
            if (v < b || (v == b && iv < ix)) { b = v; ix = iv; }
        }
        am_s[tid] = ix;
    }
    __syncthreads();

    for (int jo = 0; jo < 2; ++jo) {
        int o = tid + jo * 256;
        int rr = o >> 6, d = o & 63;
        if (rr < nr) {
            int e = am_s[rr];
            size_t g = (size_t)list[base + rr];
            float mv = mean_b[d], lv = logstd_b[d];
            const float* cb = codebook + (size_t)e * 64;
            for (int k = 0; k < 64; ++k) {
                float zk = cb[k];
                mv = fmaf(zk, mean_w[(size_t)k * 64 + d], mv);
                lv = fmaf(zk, logstd_w[(size_t)k * 64 + d], lv);
            }
            float ls = fminf(fmaxf(lv, -4.f), 15.f);
            float sd = expf(ls);
            float z = fmaf(sd, eps[g * 64 + d], mv);
            mean_out[g * 64 + d] = mv;
            std_out[g * 64 + d] = sd;
            xz[g * 128 + 64 + d] = f2bf(z);
        }
    }
}

// ---------------------------------------------------------------------------
extern "C" void kernel_launch(void* const* d_in, const int* in_sizes, int n_in,
                              void* d_out, int out_size, void* d_ws, size_t ws_size,
                              hipStream_t stream)
{
    const float* state    = (const float*)d_in[0];
    const float* action   = (const float*)d_in[1];
    const float* eps      = (const float*)d_in[2];
    const float* enc_w1   = (const float*)d_in[3];
    const float* enc_b1   = (const float*)d_in[4];
    const float* enc_w2   = (const float*)d_in[5];
    const float* enc_b2   = (const float*)d_in[6];
    const float* enc_w3   = (const float*)d_in[7];
    const float* enc_b3   = (const float*)d_in[8];
    const float* mean_w   = (const float*)d_in[9];
    const float* mean_b   = (const float*)d_in[10];
    const float* logstd_w = (const float*)d_in[11];
    const float* logstd_b = (const float*)d_in[12];
    const float* codebook = (const float*)d_in[13];
    const float* dec_w1   = (const float*)d_in[14];
    const float* dec_b1   = (const float*)d_in[15];
    const float* dec_w2   = (const float*)d_in[16];
    const float* dec_b2   = (const float*)d_in[17];
    const float* dec_w3   = (const float*)d_in[18];
    const float* dec_b3   = (const float*)d_in[19];

    float* out = (float*)d_out;
    float* u_out = out;
    float* mean_out = out + (size_t)B_TOTAL * 32;
    float* std_out = mean_out + (size_t)B_TOTAL * 64;

    // ---- fixed ws region ----
    char* base = (char*)d_ws;
    float* cbn = (float*)base;                                   // 4096
    unsigned short* W1h = (unsigned short*)(base + 4096);        // 196608
    unsigned short* W1l = (unsigned short*)(base + 200704);      // 196608
    unsigned short* W2h = (unsigned short*)(base + 397312);      // 2097152
    unsigned short* W2l = (unsigned short*)(base + 2494464);     // 2097152
    unsigned short* W3h = (unsigned short*)(base + 4591616);     // 131072
    unsigned short* W3l = (unsigned short*)(base + 4722688);     // 131072
    unsigned short* W4h = (unsigned short*)(base + 4853760);     // 262144
    unsigned short* W5h = (unsigned short*)(base + 5115904);     // 2097152
    unsigned short* W6h = (unsigned short*)(base + 7213056);     // 65536
    int* ctr            = (int*)(base + 7278592);                // 256
    int* flag_list      = (int*)(base + 7278848);                // 262144
    int* meta           = (int*)(base + 7540992);                // 256
    float* sa_fix       = (float*)(base + 7541248);              // FMAX*96*4   = 2359296
    float* h1_fix       = (float*)(base + 9900544);              // FMAX*1024*4 = 25165824
    float* h2_fix       = (float*)(base + 35066368);             // 25165824
    float* mz_fix       = (float*)(base + 60232192);             // FMAX*64*4   = 1572864
    const size_t FIXED  = 61805056;                              // ~62 MB

    // global xz plane [B_TOTAL, 128] bf16 (decoder input, fixup target)
    unsigned short* xz_g = (unsigned short*)(base + FIXED);      // 16 MB
    const size_t XZ_SZ = (size_t)B_TOTAL * 128 * 2;

    // per-chunk: saH 192 + saL 192 + h1H/h1L/h2H/h2L 2048ea + mz 256 = 8832 B
    const size_t per_row = 8832;
    size_t avail = (ws_size > FIXED + XZ_SZ) ? (ws_size - FIXED - XZ_SZ) : 0;
    long maxC = (long)(avail / per_row);
    int C = (int)(maxC / 1024) * 1024;
    if (C > B_TOTAL) C = B_TOTAL;
    if (C < 1024) C = 1024;

    char* dyn = base + FIXED + XZ_SZ;
    unsigned short* saH = (unsigned short*)dyn;                   // [C,96]
    unsigned short* saL = saH + (size_t)C * 96;
    unsigned short* h1H = saL + (size_t)C * 96;                   // [C,1024]
    unsigned short* h1L = h1H + (size_t)C * 1024;
    unsigned short* h2H = h1L + (size_t)C * 1024;
    unsigned short* h2L = h2H + (size_t)C * 1024;
    float* mz = (float*)(h2L + (size_t)C * 1024);                 // [C,64]
    unsigned short* hc = h1H;   // decoder reuse
    unsigned short* hd = h2H;

    // ---- once per call ----
    cb_norms<<<dim3(4), dim3(256), 0, stream>>>(codebook, cbn);
    zero_ctr<<<dim3(1), dim3(64), 0, stream>>>(ctr);
    w_xform<3, 128><<<dim3(3, 8), dim3(256), 0, stream>>>(enc_w1, 96, 1024, W1h, W1l);
    w_xform<3, 128><<<dim3(32, 8), dim3(256), 0, stream>>>(enc_w2, 1024, 1024, W2h, W2l);
    w_xform<3, 64><<<dim3(32, 1), dim3(256), 0, stream>>>(enc_w3, 1024, 64, W3h, W3l);
    w_xform<1, 128><<<dim3(4, 8), dim3(256), 0, stream>>>(dec_w1, 128, 1024, W4h, nullptr);
    w_xform<1, 128><<<dim3(32, 8), dim3(256), 0, stream>>>(dec_w2, 1024, 1024, W5h, nullptr);
    w_xform<1, 32><<<dim3(32, 1), dim3(256), 0, stream>>>(dec_w3, 1024, 32, W6h, nullptr);

    // ---- phase A: encoder + VQ for all chunks ----
    for (int r0 = 0; r0 < B_TOTAL; r0 += C) {
        int M = (r0 + C <= B_TOTAL) ? C : (B_TOTAL - r0);
        int mt = M / 128;          // multiple of 8 (M multiple of 1024)

        sa_pre<<<dim3(M * 12 / 256), dim3(256), 0, stream>>>(
            state + (size_t)r0 * SDIM, action + (size_t)r0 * ADIM, saH, saL);

        mfma_gemm<3, 128, 0, 0><<<dim3(mt * 8), dim3(256), 0, stream>>>(
            saH, saL, 96, W1h, W1l, enc_b1, h1H, h1L, 1024);
        mfma_gemm<3, 128, 0, 0><<<dim3(mt * 8), dim3(256), 0, stream>>>(
            h1H, h1L, 1024, W2h, W2l, enc_b2, h2H, h2L, 1024);
        mfma_gemm<3, 64, 2, 0><<<dim3(mt), dim3(256), 0, stream>>>(
            h2H, h2L, 1024, W3h, W3l, enc_b3, mz, nullptr, 64);

        xz_pre<<<dim3(M / 16), dim3(256), 0, stream>>>(
            state + (size_t)r0 * SDIM, xz_g + (size_t)r0 * 128);

        vq_latent<<<dim3(mt), dim3(256), 0, stream>>>(
            mz, codebook, cbn, mean_w, mean_b, logstd_w, logstd_b,
            eps + (size_t)r0 * LDIM,
            mean_out + (size_t)r0 * LDIM, std_out + (size_t)r0 * LDIM,
            xz_g + (size_t)r0 * 128, ctr, flag_list, r0);
    }

    // ---- phase B: exact-fp32 fixup as 32-row-tile GEMMs on gathered rows ----
    gather_fix<<<dim3(FMAX * 24 / 256), dim3(256), 0, stream>>>(
        ctr, meta, flag_list, state, action, sa_fix);
    gemm_fix<128, 0><<<dim3(FMAX / 32, 8), dim3(256), 0, stream>>>(
        meta, sa_fix, 96, enc_w1, enc_b1, h1_fix, 1024);
    gemm_fix<128, 0><<<dim3(FMAX / 32, 8), dim3(256), 0, stream>>>(
        meta, h1_fix, 1024, enc_w2, enc_b2, h2_fix, 1024);
    gemm_fix<64, 0><<<dim3(FMAX / 32, 1), dim3(256), 0, stream>>>(
        meta, h2_fix, 1024, enc_w3, enc_b3, mz_fix, 64);
    vq_fix<<<dim3(FMAX / 8), dim3(256), 0, stream>>>(
        ctr, flag_list, mz_fix, codebook, cbn,
        mean_w, mean_b, logstd_w, logstd_b, eps,
        mean_out, std_out, xz_g);

    // ---- phase C: decoder for all chunks ----
    for (int r0 = 0; r0 < B_TOTAL; r0 += C) {
        int M = (r0 + C <= B_TOTAL) ? C : (B_TOTAL - r0);
        int mt = M / 128;

        mfma_gemm<1, 128, 1, 0><<<dim3(mt * 8), dim3(256), 0, stream>>>(
            xz_g + (size_t)r0 * 128, nullptr, 128, W4h, nullptr, dec_b1, hc, nullptr, 1024);
        mfma_gemm<1, 128, 1, 0><<<dim3(mt * 8), dim3(256), 0, stream>>>(
            hc, nullptr, 1024, W5h, nullptr, dec_b2, hd, nullptr, 1024);
        mfma_gemm<1, 32, 2, 1><<<dim3(mt), dim3(256), 0, stream>>>(
            hd, nullptr, 1024, W6h, nullptr, dec_b3,
            u_out + (size_t)r0 * ADIM, nullptr, 32);
    }
}

// Round 10
// 1776.707 us; speedup vs baseline: 1.7110x; 1.1804x over previous
//
#include <hip/hip_runtime.h>
#include <cstdint>
#include <cstddef>

#define B_TOTAL 65536
#define SDIM 64
#define ADIM 32
#define LDIM 64
#define HDIM 1024
#define NEMB 1024
#define TAU 0.125f
#define FMAX 6144

typedef __attribute__((ext_vector_type(8))) short short8;
typedef __attribute__((ext_vector_type(4))) float f32x4;

__device__ inline unsigned short f2bf(float f) {
    unsigned int u = __float_as_uint(f);
    u += 0x7fffu + ((u >> 16) & 1u);
    return (unsigned short)(u >> 16);
}
__device__ inline float bf2f(unsigned short s) {
    return __uint_as_float(((unsigned int)s) << 16);
}

// async global->LDS, 16B per lane; LDS dest = wave-uniform base + lane*16.
__device__ inline void gload16(const unsigned short* g, unsigned short* l) {
    __builtin_amdgcn_global_load_lds(
        (__attribute__((address_space(1))) void*)(g),
        (__attribute__((address_space(3))) void*)(l), 16, 0, 0);
}

// ---------------------------------------------------------------------------
__global__ void cb_norms(const float* __restrict__ codebook, float* __restrict__ cbn)
{
    int i = blockIdx.x * 256 + threadIdx.x;
    if (i < NEMB) {
        float s = 0.f;
#pragma unroll
        for (int k = 0; k < LDIM; ++k) {
            float v = codebook[(size_t)i * LDIM + k];
            s = fmaf(v, v, s);
        }
        cbn[i] = s;
    }
}

__global__ void zero_ctr(int* ctr) { if (threadIdx.x == 0) *ctr = 0; }

// ---------------------------------------------------------------------------
// Weight pre-transform: W[K][N] fp32 -> bf16 plane(s), MFMA-B-ready layout.
// ---------------------------------------------------------------------------
template <int NT, int BN>
__global__ __launch_bounds__(256) void w_xform(
    const float* __restrict__ W, int K, int N,
    unsigned short* __restrict__ Ph, unsigned short* __restrict__ Pl)
{
    __shared__ float Ws[32][BN + 4];
    const int tid = threadIdx.x;
    const int ks = blockIdx.x, nb = blockIdx.y;
    const int k0 = ks * 32, n0 = nb * BN;
    constexpr int LT = 32 * (BN / 4);
#pragma unroll
    for (int it = 0; it < (LT + 255) / 256; ++it) {
        int idx = tid + it * 256;
        if (LT % 256 == 0 || idx < LT) {
            int k = idx / (BN / 4);
            int nf = idx % (BN / 4);
            *(f32x4*)&Ws[k][nf * 4] =
                *(const f32x4*)&W[(size_t)(k0 + k) * N + n0 + nf * 4];
        }
    }
    __syncthreads();
    const int KS = K >> 5;
    size_t bo = ((size_t)nb * KS + ks) * (BN * 32);
    constexpr int WT = BN * 4;
#pragma unroll
    for (int it = 0; it < (WT + 255) / 256; ++it) {
        int idx = tid + it * 256;
        if (WT % 256 == 0 || idx < WT) {
            int kb = idx / BN;
            int n = idx % BN;
            short8 h, l;
#pragma unroll
            for (int j = 0; j < 8; ++j) {
                float x = Ws[kb * 8 + j][n];
                unsigned short hb_ = f2bf(x);
                h[j] = (short)hb_;
                if (NT == 3) l[j] = (short)f2bf(x - bf2f(hb_));
            }
            *(short8*)&Ph[bo + (size_t)idx * 8] = h;
            if (NT == 3) *(short8*)&Pl[bo + (size_t)idx * 8] = l;
        }
    }
}

// ---------------------------------------------------------------------------
// BF16 MFMA GEMM, double-buffered prefetch + XCD swizzle (unchanged, proven).
// ---------------------------------------------------------------------------
template <int NT, int BN, int OUT, int ACT>
__global__ __launch_bounds__(256, 2) void mfma_gemm(
    const unsigned short* __restrict__ Ah_g, const unsigned short* __restrict__ Al_g,
    int K,
    const unsigned short* __restrict__ Wh, const unsigned short* __restrict__ Wl,
    const float* __restrict__ bias,
    void* __restrict__ out0, void* __restrict__ out1, int NTOT)
{
    constexpr int NWC = (BN == 128) ? 2 : 1;
    constexpr int WM = (BN == 128) ? 4 : 2;
    constexpr int WN = (BN == 32) ? 2 : 4;
    constexpr int ABUF = (NT == 3) ? 8192 : 4096;           // shorts per buffer (A)
    constexpr int BBUF = 4 * BN * 8 * ((NT == 3) ? 2 : 1);  // shorts per buffer (B)
    constexpr int BUFSH = ABUF + BBUF;

    __shared__ unsigned short smem[2 * BUFSH];

    const int tid = threadIdx.x;
    int row_t, nb;
    if constexpr (BN == 128) {
        int per = gridDim.x >> 3;        // == mt (grid = mt*8)
        int xcd = blockIdx.x & 7;
        int lid = blockIdx.x >> 3;
        int tile = xcd * per + lid;
        row_t = tile >> 3;
        nb = tile & 7;
    } else {
        row_t = blockIdx.x;
        nb = 0;
    }
    const int m0 = row_t * 128;
    const int n0 = nb * BN;
    const int w = tid >> 6, lane = tid & 63;
    const int g = lane >> 4, lr = lane & 15;
    const int wrow0 = (w / NWC) * (WM * 16);
    const int wcol0 = (w % NWC) * (WN * 16);
    const int KS = K >> 5;

    auto stage = [&](unsigned short* buf, int ks) {
        unsigned short* Ah = buf;
        unsigned short* Al = buf + 4096;
        unsigned short* Bh = buf + ABUF;
        unsigned short* Bl = Bh + 4 * BN * 8;
#pragma unroll
        for (int it = 0; it < 2; ++it) {
            int t0 = it * 256 + w * 64;
            int t = t0 + lane;
            int row = t & 127, kb = t >> 7;
            size_t go = (size_t)(m0 + row) * K + ks * 32 + kb * 8;
            gload16(Ah_g + go, Ah + (size_t)t0 * 8);
            if constexpr (NT == 3) gload16(Al_g + go, Al + (size_t)t0 * 8);
        }
        size_t bo = ((size_t)nb * KS + ks) * (BN * 32);
        constexpr int BT = 4 * BN;
        if constexpr (BT >= 256) {
#pragma unroll
            for (int it = 0; it < BT / 256; ++it) {
                int t0 = it * 256 + w * 64;
                size_t go = bo + (size_t)(t0 + lane) * 8;
                gload16(Wh + go, Bh + (size_t)t0 * 8);
                if constexpr (NT == 3) gload16(Wl + go, Bl + (size_t)t0 * 8);
            }
        } else {
            if (tid < BT) {
                int t0 = w * 64;
                size_t go = bo + (size_t)(t0 + lane) * 8;
                gload16(Wh + go, Bh + (size_t)t0 * 8);
                if constexpr (NT == 3) gload16(Wl + go, Bl + (size_t)t0 * 8);
            }
        }
    };

    f32x4 acc[WM][WN];
#pragma unroll
    for (int m = 0; m < WM; ++m)
#pragma unroll
        for (int n = 0; n < WN; ++n) {
            acc[m][n][0] = 0.f; acc[m][n][1] = 0.f;
            acc[m][n][2] = 0.f; acc[m][n][3] = 0.f;
        }

    stage(smem, 0);   // prologue into buffer 0

    for (int ks = 0; ks < KS; ++ks) {
        __syncthreads();   // drains vmcnt: buf[cur] staged (issued a full phase ago)
        unsigned short* buf = smem + (size_t)(ks & 1) * BUFSH;
        if (ks + 1 < KS)
            stage(smem + (size_t)((ks + 1) & 1) * BUFSH, ks + 1);   // flies during MFMA

        unsigned short* Ah = buf;
        unsigned short* Al = buf + 4096;
        unsigned short* Bh = buf + ABUF;
        unsigned short* Bl = Bh + 4 * BN * 8;

        short8 ah[WM], bh[WN];
        short8 al[WM], bl[WN];
#pragma unroll
        for (int m = 0; m < WM; ++m) {
            int ro = (g << 7) + wrow0 + m * 16 + lr;
            ah[m] = *(const short8*)&Ah[ro * 8];
            if constexpr (NT == 3) al[m] = *(const short8*)&Al[ro * 8];
        }
#pragma unroll
        for (int n = 0; n < WN; ++n) {
            int co = g * BN + wcol0 + n * 16 + lr;
            bh[n] = *(const short8*)&Bh[co * 8];
            if constexpr (NT == 3) bl[n] = *(const short8*)&Bl[co * 8];
        }
#pragma unroll
        for (int m = 0; m < WM; ++m)
#pragma unroll
            for (int n = 0; n < WN; ++n) {
                acc[m][n] = __builtin_amdgcn_mfma_f32_16x16x32_bf16(
                    ah[m], bh[n], acc[m][n], 0, 0, 0);
                if constexpr (NT == 3) {
                    acc[m][n] = __builtin_amdgcn_mfma_f32_16x16x32_bf16(
                        ah[m], bl[n], acc[m][n], 0, 0, 0);
                    acc[m][n] = __builtin_amdgcn_mfma_f32_16x16x32_bf16(
                        al[m], bh[n], acc[m][n], 0, 0, 0);
                }
            }
    }

    // ---- epilogue: bias + act, LDS transpose, coalesced stores ----
    float bv[WN];
#pragma unroll
    for (int n = 0; n < WN; ++n) bv[n] = bias[n0 + wcol0 + n * 16 + lr];

    unsigned short* Sb = smem;
    float* Sf = (float*)smem;
    constexpr int NPASS = (OUT == 0) ? 2 : 1;

#pragma unroll
    for (int p = 0; p < NPASS; ++p) {
        __syncthreads();
#pragma unroll
        for (int m = 0; m < WM; ++m)
#pragma unroll
            for (int n = 0; n < WN; ++n)
#pragma unroll
                for (int q = 0; q < 4; ++q) {
                    int rl = wrow0 + m * 16 + g * 4 + q;
                    int cl = wcol0 + n * 16 + lr;
                    float x = acc[m][n][q] + bv[n];
                    if (ACT == 0) x = fmaxf(x, 0.f);
                    else x = tanhf(x);
                    if constexpr (OUT == 2) {
                        Sf[rl * BN + cl] = x;
                    } else {
                        unsigned short hb_ = f2bf(x);
                        Sb[rl * BN + cl] = (p == 0) ? hb_ : f2bf(x - bf2f(hb_));
                    }
                }
        __syncthreads();
        if constexpr (OUT == 2) {
            constexpr int SL = BN / 4;
#pragma unroll
            for (int it = 0; it < (128 * SL) / 256; ++it) {
                int idx = tid + it * 256;
                int row = idx / SL, sl = idx % SL;
                *(f32x4*)((float*)out0 + (size_t)(m0 + row) * NTOT + n0 + sl * 4)
                    = *(const f32x4*)&Sf[row * BN + sl * 4];
            }
        } else {
            constexpr int SL = BN / 8;
            unsigned short* dst = (unsigned short*)((p == 0) ? out0 : out1);
#pragma unroll
            for (int it = 0; it < (128 * SL) / 256; ++it) {
                int idx = tid + it * 256;
                int row = idx / SL, sl = idx % SL;
                *(short8*)&dst[(size_t)(m0 + row) * NTOT + n0 + sl * 8]
                    = *(const short8*)&Sb[row * BN + sl * 8];
            }
        }
    }
}

// ---------------------------------------------------------------------------
// fp32 fixup GEMM, 32-row tiles (proven round 9).
// ---------------------------------------------------------------------------
template <int BN, int ACT>
__global__ __launch_bounds__(256) void gemm_fix(
    const int* __restrict__ mrows,
    const float* __restrict__ A, int K,
    const float* __restrict__ W, const float* __restrict__ bias,
    float* __restrict__ Co, int N)
{
    const int m0 = blockIdx.x * 32;
    if (m0 >= *mrows) return;

    constexpr int TN = BN / 16;
    __shared__ float At[16][36];
    __shared__ float Bt[16][BN + 4];

    const int tid = threadIdx.x;
    const int n0 = blockIdx.y * BN;
    const int r = tid >> 4;
    const int c = tid & 15;

    float acc[2][TN];
#pragma unroll
    for (int i = 0; i < 2; ++i)
#pragma unroll
        for (int j = 0; j < TN; ++j) acc[i][j] = 0.f;

    for (int k0 = 0; k0 < K; k0 += 16) {
        if (tid < 128) {
            int row = tid >> 2;
            int lf = tid & 3;
            float4 v = *(const float4*)(A + (size_t)(m0 + row) * K + k0 + lf * 4);
            At[lf * 4 + 0][row] = v.x;
            At[lf * 4 + 1][row] = v.y;
            At[lf * 4 + 2][row] = v.z;
            At[lf * 4 + 3][row] = v.w;
        }
        constexpr int NF4 = BN / 4;
        constexpr int NEL = 16 * NF4;
#pragma unroll
        for (int it = 0; it < NEL / 256; ++it) {
            int idx = tid + it * 256;
            int kk = idx / NF4;
            int f = idx % NF4;
            float4 v = *(const float4*)(W + (size_t)(k0 + kk) * N + n0 + f * 4);
            *(float4*)&Bt[kk][f * 4] = v;
        }
        __syncthreads();

#pragma unroll
        for (int kk = 0; kk < 16; ++kk) {
            float a0 = At[kk][r * 2];
            float a1 = At[kk][r * 2 + 1];
            float b[TN];
            if constexpr (BN == 128) {
                float4 b0 = *(const float4*)&Bt[kk][c * 4];
                float4 b1 = *(const float4*)&Bt[kk][64 + c * 4];
                b[0] = b0.x; b[1] = b0.y; b[2] = b0.z; b[3] = b0.w;
                b[4] = b1.x; b[5] = b1.y; b[6] = b1.z; b[7] = b1.w;
            } else {
                float4 b0 = *(const float4*)&Bt[kk][c * 4];
                b[0] = b0.x; b[1] = b0.y; b[2] = b0.z; b[3] = b0.w;
            }
#pragma unroll
            for (int j = 0; j < TN; ++j) {
                acc[0][j] = fmaf(a0, b[j], acc[0][j]);
                acc[1][j] = fmaf(a1, b[j], acc[1][j]);
            }
        }
        __syncthreads();
    }

#pragma unroll
    for (int i = 0; i < 2; ++i) {
        size_t row = (size_t)(m0 + r * 2 + i);
        if constexpr (BN == 128) {
            float e[8];
#pragma unroll
            for (int j = 0; j < 8; ++j) {
                int col = (j < 4) ? (c * 4 + j) : (64 + c * 4 + (j - 4));
                float v = acc[i][j] + bias[n0 + col];
                if (ACT == 0) v = fmaxf(v, 0.f);
                e[j] = v;
            }
            float4 v0, v1;
            v0.x = e[0]; v0.y = e[1]; v0.z = e[2]; v0.w = e[3];
            v1.x = e[4]; v1.y = e[5]; v1.z = e[6]; v1.w = e[7];
            *(float4*)&Co[row * N + n0 + c * 4] = v0;
            *(float4*)&Co[row * N + n0 + 64 + c * 4] = v1;
        } else {
            float e[4];
#pragma unroll
            for (int j = 0; j < 4; ++j) {
                float v = acc[i][j] + bias[n0 + c * 4 + j];
                if (ACT == 0) v = fmaxf(v, 0.f);
                e[j] = v;
            }
            float4 v0;
            v0.x = e[0]; v0.y = e[1]; v0.z = e[2]; v0.w = e[3];
            *(float4*)&Co[row * N + n0 + c * 4] = v0;
        }
    }
}

// ---------------------------------------------------------------------------
__global__ void sa_pre(const float* __restrict__ state, const float* __restrict__ action,
                       unsigned short* __restrict__ saH, unsigned short* __restrict__ saL)
{
    int idx = blockIdx.x * 256 + threadIdx.x;
    int row = idx / 12, q = idx % 12;
    const float* src = (q < 8) ? (state + (size_t)row * 64 + q * 8)
                               : (action + (size_t)row * 32 + (q - 8) * 8);
    f32x4 v0 = *(const f32x4*)src;
    f32x4 v1 = *(const f32x4*)(src + 4);
    short8 h, l;
#pragma unroll
    for (int j = 0; j < 8; ++j) {
        float x = (j < 4) ? v0[j] : v1[j - 4];
        unsigned short hb_ = f2bf(x);
        h[j] = (short)hb_;
        l[j] = (short)f2bf(x - bf2f(hb_));
    }
    *(short8*)&saH[(size_t)row * 96 + q * 8] = h;
    *(short8*)&saL[(size_t)row * 96 + q * 8] = l;
}

__global__ void xz_pre(const float* __restrict__ state, unsigned short* __restrict__ xz)
{
    int idx = blockIdx.x * 256 + threadIdx.x;
    int row = idx >> 4, q = idx & 15;
    f32x4 v = *(const f32x4*)&state[(size_t)row * 64 + q * 4];
    unsigned short o[4];
    o[0] = f2bf(v[0]); o[1] = f2bf(v[1]); o[2] = f2bf(v[2]); o[3] = f2bf(v[3]);
    *(uint2*)&xz[(size_t)row * 128 + q * 4] = *(uint2*)o;
}

// ---------------------------------------------------------------------------
// VQ score kernel: 64 rows x 512 codes per block, grid (M/64, 2).
// Score s = ||c||^2 - 2 z.c   (||z||^2 dropped: row-constant, cancels in
// both argmin and the top-2 gap; the fixup path keeps the full formula).
// Writes per-row partial {best, sec, idx} for its code-half.
// ---------------------------------------------------------------------------
__global__ __launch_bounds__(256) void vq_score(
    const float* __restrict__ midz,
    const float* __restrict__ codebook,
    const float* __restrict__ cbn,
    float4* __restrict__ part)
{
    __shared__ float Zt[64 * 68];        // [k][row]
    __shared__ float Ct[64 * 68];        // [k][code]
    __shared__ float cn[64];

    const int tid = threadIdx.x;
    const int m0 = blockIdx.x * 64;
    const int eh = blockIdx.y;           // code half (512 codes each)
    const int r = tid >> 4;
    const int c = tid & 15;

    // stage Zt: 64 rows x 16 f4, transposed
#pragma unroll
    for (int it = 0; it < 4; ++it) {
        int idx = tid + it * 256;
        int row = idx >> 4, f = idx & 15;
        float4 v = *(const float4*)(midz + (size_t)(m0 + row) * 64 + f * 4);
        Zt[(f * 4 + 0) * 68 + row] = v.x;
        Zt[(f * 4 + 1) * 68 + row] = v.y;
        Zt[(f * 4 + 2) * 68 + row] = v.z;
        Zt[(f * 4 + 3) * 68 + row] = v.w;
    }

    float best[4], sec[4];
    int bidx[4];
#pragma unroll
    for (int i = 0; i < 4; ++i) { best[i] = 3.4e38f; sec[i] = 3.4e38f; bidx[i] = 0x7fffffff; }

    for (int ch = 0; ch < 8; ++ch) {
        int e0 = eh * 512 + ch * 64;
        __syncthreads();   // Zt staged / prev chunk's Ct readers done
#pragma unroll
        for (int it = 0; it < 4; ++it) {
            int idx = tid + it * 256;
            int e = idx >> 4, f = idx & 15;
            float4 v = *(const float4*)(codebook + (size_t)(e0 + e) * 64 + f * 4);
            Ct[(f * 4 + 0) * 68 + e] = v.x;
            Ct[(f * 4 + 1) * 68 + e] = v.y;
            Ct[(f * 4 + 2) * 68 + e] = v.z;
            Ct[(f * 4 + 3) * 68 + e] = v.w;
        }
        if (tid < 64) cn[tid] = cbn[e0 + tid];
        __syncthreads();

        float acc[4][4];
#pragma unroll
        for (int i = 0; i < 4; ++i)
#pragma unroll
            for (int j = 0; j < 4; ++j) acc[i][j] = 0.f;

#pragma unroll 8
        for (int kk = 0; kk < 64; ++kk) {
            float4 a = *(const float4*)&Zt[kk * 68 + r * 4];
            float4 b = *(const float4*)&Ct[kk * 68 + c * 4];
            acc[0][0] = fmaf(a.x, b.x, acc[0][0]);
            acc[0][1] = fmaf(a.x, b.y, acc[0][1]);
            acc[0][2] = fmaf(a.x, b.z, acc[0][2]);
            acc[0][3] = fmaf(a.x, b.w, acc[0][3]);
            acc[1][0] = fmaf(a.y, b.x, acc[1][0]);
            acc[1][1] = fmaf(a.y, b.y, acc[1][1]);
            acc[1][2] = fmaf(a.y, b.z, acc[1][2]);
            acc[1][3] = fmaf(a.y, b.w, acc[1][3]);
            acc[2][0] = fmaf(a.z, b.x, acc[2][0]);
            acc[2][1] = fmaf(a.z, b.y, acc[2][1]);
            acc[2][2] = fmaf(a.z, b.z, acc[2][2]);
            acc[2][3] = fmaf(a.z, b.w, acc[2][3]);
            acc[3][0] = fmaf(a.w, b.x, acc[3][0]);
            acc[3][1] = fmaf(a.w, b.y, acc[3][1]);
            acc[3][2] = fmaf(a.w, b.z, acc[3][2]);
            acc[3][3] = fmaf(a.w, b.w, acc[3][3]);
        }
#pragma unroll
        for (int i = 0; i < 4; ++i)
#pragma unroll
            for (int j = 0; j < 4; ++j) {
                int e = c * 4 + j;
                float s = cn[e] - 2.0f * acc[i][j];
                int gi = e0 + e;
                if (s < best[i] || (s == best[i] && gi < bidx[i])) {
                    sec[i] = best[i];
                    best[i] = s;
                    bidx[i] = gi;
                } else {
                    sec[i] = fminf(sec[i], s);
                }
            }
    }

    // top-2 merge across the 16 c-lanes (xor of low 4 lane bits keeps r)
#pragma unroll
    for (int i = 0; i < 4; ++i) {
#pragma unroll
        for (int m = 1; m < 16; m <<= 1) {
            float ob = __shfl_xor(best[i], m, 64);
            int oi = __shfl_xor(bidx[i], m, 64);
            float os = __shfl_xor(sec[i], m, 64);
            if (ob < best[i] || (ob == best[i] && oi < bidx[i])) {
                sec[i] = fminf(best[i], os);
                best[i] = ob;
                bidx[i] = oi;
            } else {
                sec[i] = fminf(sec[i], ob);
            }
        }
    }
    if (c == 0) {
#pragma unroll
        for (int i = 0; i < 4; ++i) {
            float4 p;
            p.x = best[i];
            p.y = sec[i];
            p.z = __int_as_float(bidx[i]);
            p.w = 0.f;
            part[(size_t)(m0 + r * 4 + i) * 2 + eh] = p;
        }
    }
}

// ---------------------------------------------------------------------------
// VQ merge + flag + latent head.  128 rows per block, grid mt.
// ---------------------------------------------------------------------------
__global__ __launch_bounds__(256) void vq_merge(
    const float4* __restrict__ part,
    const float* __restrict__ codebook,
    const float* __restrict__ mean_w, const float* __restrict__ mean_b,
    const float* __restrict__ logstd_w, const float* __restrict__ logstd_b,
    const float* __restrict__ eps,
    float* __restrict__ mean_out, float* __restrict__ std_out,
    unsigned short* __restrict__ xz,
    int* __restrict__ ctr, int* __restrict__ list, int rowbase)
{
    __shared__ float mw[4160];
    __shared__ float lw[4160];
    __shared__ int sidx[128];

    const int tid = threadIdx.x;
    const int m0 = blockIdx.x * 128;

    if (tid < 128) {
        size_t row = (size_t)(m0 + tid);
        float4 p0 = part[row * 2 + 0];
        float4 p1 = part[row * 2 + 1];
        int i0 = __float_as_int(p0.z), i1 = __float_as_int(p1.z);
        float b, s;
        int ix;
        if (p0.x < p1.x || (p0.x == p1.x && i0 < i1)) {
            b = p0.x; ix = i0; s = fminf(p0.y, p1.x);
        } else {
            b = p1.x; ix = i1; s = fminf(p1.y, p0.x);
        }
        sidx[tid] = ix;
        if (s - b < TAU) {
            int p = atomicAdd(ctr, 1);
            list[p] = rowbase + m0 + tid;
        }
    }
    // stage mean_w / logstd_w
#pragma unroll
    for (int it = 0; it < 4; ++it) {
        int idx = tid + it * 256;
        int k = idx >> 4, f = idx & 15;
        float4 v = *(const float4*)(mean_w + (size_t)k * 64 + f * 4);
        mw[k * 65 + f * 4 + 0] = v.x;
        mw[k * 65 + f * 4 + 1] = v.y;
        mw[k * 65 + f * 4 + 2] = v.z;
        mw[k * 65 + f * 4 + 3] = v.w;
        float4 w2 = *(const float4*)(logstd_w + (size_t)k * 64 + f * 4);
        lw[k * 65 + f * 4 + 0] = w2.x;
        lw[k * 65 + f * 4 + 1] = w2.y;
        lw[k * 65 + f * 4 + 2] = w2.z;
        lw[k * 65 + f * 4 + 3] = w2.w;
    }
    __syncthreads();

    {
        int row = tid >> 1;
        int d0 = (tid & 1) * 32;
        int e = sidx[row];
        const float* cb = codebook + (size_t)e * 64;
        float mv[32], lv[32];
#pragma unroll
        for (int d = 0; d < 32; ++d) {
            mv[d] = mean_b[d0 + d];
            lv[d] = logstd_b[d0 + d];
        }
        for (int k = 0; k < 64; ++k) {
            float zk = cb[k];
#pragma unroll
            for (int d = 0; d < 32; ++d) {
                mv[d] = fmaf(zk, mw[k * 65 + d0 + d], mv[d]);
                lv[d] = fmaf(zk, lw[k * 65 + d0 + d], lv[d]);
            }
        }
        size_t ro = (size_t)(m0 + row) * 64 + d0;
        size_t xo = (size_t)(m0 + row) * 128 + 64 + d0;
#pragma unroll
        for (int d = 0; d < 32; ++d) {
            float mean = mv[d];
            float ls = fminf(fmaxf(lv[d], -4.f), 15.f);
            float sd = expf(ls);
            float z = fmaf(sd, eps[ro + d], mean);
            mean_out[ro + d] = mean;
            std_out[ro + d] = sd;
            xz[xo + d] = f2bf(z);
        }
    }
}

// ---------------------------------------------------------------------------
// Gather flagged rows into compact sa_fix [cnt,96]; write padded count meta.
// ---------------------------------------------------------------------------
__global__ void gather_fix(const int* __restrict__ ctr, int* __restrict__ meta,
                           const int* __restrict__ list,
                           const float* __restrict__ state,
                           const float* __restrict__ action,
                           float* __restrict__ sa_fix)
{
    int cnt = *ctr; if (cnt > FMAX) cnt = FMAX;
    if (blockIdx.x == 0 && threadIdx.x == 0)
        meta[0] = (cnt + 31) & ~31;
    int t = blockIdx.x * 256 + threadIdx.x;
    if (t >= cnt * 24) return;
    int f = t / 24, q = t % 24;
    size_t g = (size_t)list[f];
    f32x4 v = (q < 16) ? *(const f32x4*)&state[g * 64 + q * 4]
                       : *(const f32x4*)&action[g * 32 + (q - 16) * 4];
    *(f32x4*)&sa_fix[(size_t)f * 96 + q * 4] = v;
}

// ---------------------------------------------------------------------------
// VQ + latent head on the compact fixed rows; scatter via list.
// ---------------------------------------------------------------------------
__global__ __launch_bounds__(256) void vq_fix(
    const int* __restrict__ ctr, const int* __restrict__ list,
    const float* __restrict__ mz_fix,
    const float* __restrict__ codebook, const float* __restrict__ cbn,
    const float* __restrict__ mean_w, const float* __restrict__ mean_b,
    const float* __restrict__ logstd_w, const float* __restrict__ logstd_b,
    const float* __restrict__ eps,
    float* __restrict__ mean_out, float* __restrict__ std_out,
    unsigned short* __restrict__ xz)
{
    __shared__ float mzs[8][64];
    __shared__ float zns[8];
    __shared__ float sv[2048];
    __shared__ int si[2048];
    __shared__ int am_s[8];

    int cnt = *ctr; if (cnt > FMAX) cnt = FMAX;
    const int base = blockIdx.x * 8;
    if (base >= cnt) return;
    const int nr = min(8, cnt - base);
    const int tid = threadIdx.x;

    if (tid < 128) {
        int rr = tid >> 4, q = tid & 15;
        int src = base + ((rr < nr) ? rr : 0);
        *(f32x4*)&mzs[rr][q * 4] = *(const f32x4*)&mz_fix[(size_t)src * 64 + q * 4];
    }
    __syncthreads();
    if (tid < 8) {
        float s = 0.f;
#pragma unroll
        for (int k = 0; k < 64; ++k) s = fmaf(mzs[tid][k], mzs[tid][k], s);
        zns[tid] = s;
    }
    __syncthreads();

    float bb[8];
    int bi[8];
#pragma unroll
    for (int rr = 0; rr < 8; ++rr) { bb[rr] = 3.4e38f; bi[rr] = 0x7fffffff; }
    for (int j = 0; j < 4; ++j) {
        int code = tid + j * 256;
        const f32x4* cp = (const f32x4*)(codebook + (size_t)code * 64);
        float dot[8];
#pragma unroll
        for (int rr = 0; rr < 8; ++rr) dot[rr] = 0.f;
        for (int t = 0; t < 16; ++t) {
            f32x4 cv = cp[t];
#pragma unroll
            for (int e = 0; e < 4; ++e) {
                float cvv = cv[e];
#pragma unroll
                for (int rr = 0; rr < 8; ++rr)
                    dot[rr] = fmaf(mzs[rr][t * 4 + e], cvv, dot[rr]);
            }
        }
        float cnv = cbn[code];
#pragma unroll
        for (int rr = 0; rr < 8; ++rr) {
            float s = (zns[rr] + cnv) - 2.0f * dot[rr];
            if (s < bb[rr] || (s == bb[rr] && code < bi[rr])) {
                bb[rr] = s; bi[rr] = code;
            }
        }
    }
#pragma unroll
    for (int rr = 0; rr < 8; ++rr) {
        sv[rr * 256 + tid] = bb[rr];
        si[rr * 256 + tid] = bi[rr];
    }
    __syncthreads();
    if (tid < 8) {
        float b = 3.4e38f;
        int ix = 0x7fffffff;
        for (int t = 0; t < 256; ++t) {
            float v = sv[tid * 256 + t];
            int iv = si[tid * 256 + t];
            if (v < b || (v == b && iv < ix)) { b = v; ix = iv; }
        }
        am_s[tid] = ix;
    }
    __syncthreads();

    for (int jo = 0; jo < 2; ++jo) {
        int o = tid + jo * 256;
        int rr = o >> 6, d = o & 63;
        if (rr < nr) {
            int e = am_s[rr];
            size_t g = (size_t)list[base + rr];
            float mv = mean_b[d], lv = logstd_b[d];
            const float* cb = codebook + (size_t)e * 64;
            for (int k = 0; k < 64; ++k) {
                float zk = cb[k];
                mv = fmaf(zk, mean_w[(size_t)k * 64 + d], mv);
                lv = fmaf(zk, logstd_w[(size_t)k * 64 + d], lv);
            }
            float ls = fminf(fmaxf(lv, -4.f), 15.f);
            float sd = expf(ls);
            float z = fmaf(sd, eps[g * 64 + d], mv);
            mean_out[g * 64 + d] = mv;
            std_out[g * 64 + d] = sd;
            xz[g * 128 + 64 + d] = f2bf(z);
        }
    }
}

// ---------------------------------------------------------------------------
extern "C" void kernel_launch(void* const* d_in, const int* in_sizes, int n_in,
                              void* d_out, int out_size, void* d_ws, size_t ws_size,
                              hipStream_t stream)
{
    const float* state    = (const float*)d_in[0];
    const float* action   = (const float*)d_in[1];
    const float* eps      = (const float*)d_in[2];
    const float* enc_w1   = (const float*)d_in[3];
    const float* enc_b1   = (const float*)d_in[4];
    const float* enc_w2   = (const float*)d_in[5];
    const float* enc_b2   = (const float*)d_in[6];
    const float* enc_w3   = (const float*)d_in[7];
    const float* enc_b3   = (const float*)d_in[8];
    const float* mean_w   = (const float*)d_in[9];
    const float* mean_b   = (const float*)d_in[10];
    const float* logstd_w = (const float*)d_in[11];
    const float* logstd_b = (const float*)d_in[12];
    const float* codebook = (const float*)d_in[13];
    const float* dec_w1   = (const float*)d_in[14];
    const float* dec_b1   = (const float*)d_in[15];
    const float* dec_w2   = (const float*)d_in[16];
    const float* dec_b2   = (const float*)d_in[17];
    const float* dec_w3   = (const float*)d_in[18];
    const float* dec_b3   = (const float*)d_in[19];

    float* out = (float*)d_out;
    float* u_out = out;
    float* mean_out = out + (size_t)B_TOTAL * 32;
    float* std_out = mean_out + (size_t)B_TOTAL * 64;

    // ---- fixed ws region ----
    char* base = (char*)d_ws;
    float* cbn = (float*)base;                                   // 4096
    unsigned short* W1h = (unsigned short*)(base + 4096);        // 196608
    unsigned short* W1l = (unsigned short*)(base + 200704);      // 196608
    unsigned short* W2h = (unsigned short*)(base + 397312);      // 2097152
    unsigned short* W2l = (unsigned short*)(base + 2494464);     // 2097152
    unsigned short* W3h = (unsigned short*)(base + 4591616);     // 131072
    unsigned short* W3l = (unsigned short*)(base + 4722688);     // 131072
    unsigned short* W4h = (unsigned short*)(base + 4853760);     // 262144
    unsigned short* W5h = (unsigned short*)(base + 5115904);     // 2097152
    unsigned short* W6h = (unsigned short*)(base + 7213056);     // 65536
    int* ctr            = (int*)(base + 7278592);                // 256
    int* flag_list      = (int*)(base + 7278848);                // 262144
    int* meta           = (int*)(base + 7540992);                // 256
    float4* part        = (float4*)(base + 7541248);             // B*2*16 = 2097152
    float* sa_fix       = (float*)(base + 9638400);              // FMAX*96*4   = 2359296
    float* h1_fix       = (float*)(base + 11997696);             // FMAX*1024*4 = 25165824
    float* h2_fix       = (float*)(base + 37163520);             // 25165824
    float* mz_fix       = (float*)(base + 62329344);             // FMAX*64*4   = 1572864
    const size_t FIXED  = 63902208;                              // ~64 MB

    // global xz plane [B_TOTAL, 128] bf16 (decoder input, fixup target)
    unsigned short* xz_g = (unsigned short*)(base + FIXED);      // 16 MB
    const size_t XZ_SZ = (size_t)B_TOTAL * 128 * 2;

    // per-chunk: saH 192 + saL 192 + h1H/h1L/h2H/h2L 2048ea + mz 256 = 8832 B
    const size_t per_row = 8832;
    size_t avail = (ws_size > FIXED + XZ_SZ) ? (ws_size - FIXED - XZ_SZ) : 0;
    long maxC = (long)(avail / per_row);
    int C = (int)(maxC / 1024) * 1024;
    if (C > B_TOTAL) C = B_TOTAL;
    if (C < 1024) C = 1024;

    char* dyn = base + FIXED + XZ_SZ;
    unsigned short* saH = (unsigned short*)dyn;                   // [C,96]
    unsigned short* saL = saH + (size_t)C * 96;
    unsigned short* h1H = saL + (size_t)C * 96;                   // [C,1024]
    unsigned short* h1L = h1H + (size_t)C * 1024;
    unsigned short* h2H = h1L + (size_t)C * 1024;
    unsigned short* h2L = h2H + (size_t)C * 1024;
    float* mz = (float*)(h2L + (size_t)C * 1024);                 // [C,64]
    unsigned short* hc = h1H;   // decoder reuse
    unsigned short* hd = h2H;

    // ---- once per call ----
    cb_norms<<<dim3(4), dim3(256), 0, stream>>>(codebook, cbn);
    zero_ctr<<<dim3(1), dim3(64), 0, stream>>>(ctr);
    w_xform<3, 128><<<dim3(3, 8), dim3(256), 0, stream>>>(enc_w1, 96, 1024, W1h, W1l);
    w_xform<3, 128><<<dim3(32, 8), dim3(256), 0, stream>>>(enc_w2, 1024, 1024, W2h, W2l);
    w_xform<3, 64><<<dim3(32, 1), dim3(256), 0, stream>>>(enc_w3, 1024, 64, W3h, W3l);
    w_xform<1, 128><<<dim3(4, 8), dim3(256), 0, stream>>>(dec_w1, 128, 1024, W4h, nullptr);
    w_xform<1, 128><<<dim3(32, 8), dim3(256), 0, stream>>>(dec_w2, 1024, 1024, W5h, nullptr);
    w_xform<1, 32><<<dim3(32, 1), dim3(256), 0, stream>>>(dec_w3, 1024, 32, W6h, nullptr);

    // ---- phase A: encoder + VQ for all chunks ----
    for (int r0 = 0; r0 < B_TOTAL; r0 += C) {
        int M = (r0 + C <= B_TOTAL) ? C : (B_TOTAL - r0);
        int mt = M / 128;          // multiple of 8 (M multiple of 1024)

        sa_pre<<<dim3(M * 12 / 256), dim3(256), 0, stream>>>(
            state + (size_t)r0 * SDIM, action + (size_t)r0 * ADIM, saH, saL);

        mfma_gemm<3, 128, 0, 0><<<dim3(mt * 8), dim3(256), 0, stream>>>(
            saH, saL, 96, W1h, W1l, enc_b1, h1H, h1L, 1024);
        mfma_gemm<3, 128, 0, 0><<<dim3(mt * 8), dim3(256), 0, stream>>>(
            h1H, h1L, 1024, W2h, W2l, enc_b2, h2H, h2L, 1024);
        mfma_gemm<3, 64, 2, 0><<<dim3(mt), dim3(256), 0, stream>>>(
            h2H, h2L, 1024, W3h, W3l, enc_b3, mz, nullptr, 64);

        xz_pre<<<dim3(M / 16), dim3(256), 0, stream>>>(
            state + (size_t)r0 * SDIM, xz_g + (size_t)r0 * 128);

        vq_score<<<dim3(M / 64, 2), dim3(256), 0, stream>>>(
            mz, codebook, cbn, part + (size_t)r0 * 2);
        vq_merge<<<dim3(mt), dim3(256), 0, stream>>>(
            part + (size_t)r0 * 2, codebook,
            mean_w, mean_b, logstd_w, logstd_b,
            eps + (size_t)r0 * LDIM,
            mean_out + (size_t)r0 * LDIM, std_out + (size_t)r0 * LDIM,
            xz_g + (size_t)r0 * 128, ctr, flag_list, r0);
    }

    // ---- phase B: exact-fp32 fixup as 32-row-tile GEMMs on gathered rows ----
    gather_fix<<<dim3(FMAX * 24 / 256), dim3(256), 0, stream>>>(
        ctr, meta, flag_list, state, action, sa_fix);
    gemm_fix<128, 0><<<dim3(FMAX / 32, 8), dim3(256), 0, stream>>>(
        meta, sa_fix, 96, enc_w1, enc_b1, h1_fix, 1024);
    gemm_fix<128, 0><<<dim3(FMAX / 32, 8), dim3(256), 0, stream>>>(
        meta, h1_fix, 1024, enc_w2, enc_b2, h2_fix, 1024);
    gemm_fix<64, 0><<<dim3(FMAX / 32, 1), dim3(256), 0, stream>>>(
        meta, h2_fix, 1024, enc_w3, enc_b3, mz_fix, 64);
    vq_fix<<<dim3(FMAX / 8), dim3(256), 0, stream>>>(
        ctr, flag_list, mz_fix, codebook, cbn,
        mean_w, mean_b, logstd_w, logstd_b, eps,
        mean_out, std_out, xz_g);

    // ---- phase C: decoder for all chunks ----
    for (int r0 = 0; r0 < B_TOTAL; r0 += C) {
        int M = (r0 + C <= B_TOTAL) ? C : (B_TOTAL - r0);
        int mt = M / 128;

        mfma_gemm<1, 128, 1, 0><<<dim3(mt * 8), dim3(256), 0, stream>>>(
            xz_g + (size_t)r0 * 128, nullptr, 128, W4h, nullptr, dec_b1, hc, nullptr, 1024);
        mfma_gemm<1, 128, 1, 0><<<dim3(mt * 8), dim3(256), 0, stream>>>(
            hc, nullptr, 1024, W5h, nullptr, dec_b2, hd, nullptr, 1024);
        mfma_gemm<1, 32, 2, 1><<<dim3(mt), dim3(256), 0, stream>>>(
            hd, nullptr, 1024, W6h, nullptr, dec_b3,
            u_out + (size_t)r0 * ADIM, nullptr, 32);
    }
}

// Round 11
// 1765.532 us; speedup vs baseline: 1.7218x; 1.0063x over previous
//
#include <hip/hip_runtime.h>
#include <cstdint>
#include <cstddef>

#define B_TOTAL 65536
#define SDIM 64
#define ADIM 32
#define LDIM 64
#define HDIM 1024
#define NEMB 1024
#define TAU 0.125f
#define FMAX 6144

typedef __attribute__((ext_vector_type(8))) short short8;
typedef __attribute__((ext_vector_type(4))) float f32x4;

__device__ inline unsigned short f2bf(float f) {
    unsigned int u = __float_as_uint(f);
    u += 0x7fffu + ((u >> 16) & 1u);
    return (unsigned short)(u >> 16);
}
__device__ inline float bf2f(unsigned short s) {
    return __uint_as_float(((unsigned int)s) << 16);
}

// async global->LDS, 16B per lane; LDS dest = wave-uniform base + lane*16.
__device__ inline void gload16(const unsigned short* g, unsigned short* l) {
    __builtin_amdgcn_global_load_lds(
        (__attribute__((address_space(1))) void*)(g),
        (__attribute__((address_space(3))) void*)(l), 16, 0, 0);
}

// ---------------------------------------------------------------------------
__global__ void cb_norms(const float* __restrict__ codebook, float* __restrict__ cbn)
{
    int i = blockIdx.x * 256 + threadIdx.x;
    if (i < NEMB) {
        float s = 0.f;
#pragma unroll
        for (int k = 0; k < LDIM; ++k) {
            float v = codebook[(size_t)i * LDIM + k];
            s = fmaf(v, v, s);
        }
        cbn[i] = s;
    }
}

__global__ void zero_ctr(int* ctr) { if (threadIdx.x == 0) *ctr = 0; }

// ---------------------------------------------------------------------------
// Weight pre-transform: W[K][N] fp32 -> bf16 plane(s), MFMA-B-ready layout.
// ---------------------------------------------------------------------------
template <int NT, int BN>
__global__ __launch_bounds__(256) void w_xform(
    const float* __restrict__ W, int K, int N,
    unsigned short* __restrict__ Ph, unsigned short* __restrict__ Pl)
{
    __shared__ float Ws[32][BN + 4];
    const int tid = threadIdx.x;
    const int ks = blockIdx.x, nb = blockIdx.y;
    const int k0 = ks * 32, n0 = nb * BN;
    constexpr int LT = 32 * (BN / 4);
#pragma unroll
    for (int it = 0; it < (LT + 255) / 256; ++it) {
        int idx = tid + it * 256;
        if (LT % 256 == 0 || idx < LT) {
            int k = idx / (BN / 4);
            int nf = idx % (BN / 4);
            *(f32x4*)&Ws[k][nf * 4] =
                *(const f32x4*)&W[(size_t)(k0 + k) * N + n0 + nf * 4];
        }
    }
    __syncthreads();
    const int KS = K >> 5;
    size_t bo = ((size_t)nb * KS + ks) * (BN * 32);
    constexpr int WT = BN * 4;
#pragma unroll
    for (int it = 0; it < (WT + 255) / 256; ++it) {
        int idx = tid + it * 256;
        if (WT % 256 == 0 || idx < WT) {
            int kb = idx / BN;
            int n = idx % BN;
            short8 h, l;
#pragma unroll
            for (int j = 0; j < 8; ++j) {
                float x = Ws[kb * 8 + j][n];
                unsigned short hb_ = f2bf(x);
                h[j] = (short)hb_;
                if (NT == 3) l[j] = (short)f2bf(x - bf2f(hb_));
            }
            *(short8*)&Ph[bo + (size_t)idx * 8] = h;
            if (NT == 3) *(short8*)&Pl[bo + (size_t)idx * 8] = l;
        }
    }
}

// ---------------------------------------------------------------------------
// OLD proven BF16 MFMA GEMM, 2-buf full-drain (fallback + BN 64/32 + NT1).
// ---------------------------------------------------------------------------
template <int NT, int BN, int OUT, int ACT>
__global__ __launch_bounds__(256, 2) void mfma_gemm(
    const unsigned short* __restrict__ Ah_g, const unsigned short* __restrict__ Al_g,
    int K,
    const unsigned short* __restrict__ Wh, const unsigned short* __restrict__ Wl,
    const float* __restrict__ bias,
    void* __restrict__ out0, void* __restrict__ out1, int NTOT)
{
    constexpr int NWC = (BN == 128) ? 2 : 1;
    constexpr int WM = (BN == 128) ? 4 : 2;
    constexpr int WN = (BN == 32) ? 2 : 4;
    constexpr int ABUF = (NT == 3) ? 8192 : 4096;
    constexpr int BBUF = 4 * BN * 8 * ((NT == 3) ? 2 : 1);
    constexpr int BUFSH = ABUF + BBUF;

    __shared__ unsigned short smem[2 * BUFSH];

    const int tid = threadIdx.x;
    int row_t, nb;
    if constexpr (BN == 128) {
        int per = gridDim.x >> 3;
        int xcd = blockIdx.x & 7;
        int lid = blockIdx.x >> 3;
        int tile = xcd * per + lid;
        row_t = tile >> 3;
        nb = tile & 7;
    } else {
        row_t = blockIdx.x;
        nb = 0;
    }
    const int m0 = row_t * 128;
    const int n0 = nb * BN;
    const int w = tid >> 6, lane = tid & 63;
    const int g = lane >> 4, lr = lane & 15;
    const int wrow0 = (w / NWC) * (WM * 16);
    const int wcol0 = (w % NWC) * (WN * 16);
    const int KS = K >> 5;

    auto stage = [&](unsigned short* buf, int ks) {
        unsigned short* Ah = buf;
        unsigned short* Al = buf + 4096;
        unsigned short* Bh = buf + ABUF;
        unsigned short* Bl = Bh + 4 * BN * 8;
#pragma unroll
        for (int it = 0; it < 2; ++it) {
            int t0 = it * 256 + w * 64;
            int t = t0 + lane;
            int row = t & 127, kb = t >> 7;
            size_t go = (size_t)(m0 + row) * K + ks * 32 + kb * 8;
            gload16(Ah_g + go, Ah + (size_t)t0 * 8);
            if constexpr (NT == 3) gload16(Al_g + go, Al + (size_t)t0 * 8);
        }
        size_t bo = ((size_t)nb * KS + ks) * (BN * 32);
        constexpr int BT = 4 * BN;
        if constexpr (BT >= 256) {
#pragma unroll
            for (int it = 0; it < BT / 256; ++it) {
                int t0 = it * 256 + w * 64;
                size_t go = bo + (size_t)(t0 + lane) * 8;
                gload16(Wh + go, Bh + (size_t)t0 * 8);
                if constexpr (NT == 3) gload16(Wl + go, Bl + (size_t)t0 * 8);
            }
        } else {
            if (tid < BT) {
                int t0 = w * 64;
                size_t go = bo + (size_t)(t0 + lane) * 8;
                gload16(Wh + go, Bh + (size_t)t0 * 8);
                if constexpr (NT == 3) gload16(Wl + go, Bl + (size_t)t0 * 8);
            }
        }
    };

    f32x4 acc[WM][WN];
#pragma unroll
    for (int m = 0; m < WM; ++m)
#pragma unroll
        for (int n = 0; n < WN; ++n) {
            acc[m][n][0] = 0.f; acc[m][n][1] = 0.f;
            acc[m][n][2] = 0.f; acc[m][n][3] = 0.f;
        }

    stage(smem, 0);

    for (int ks = 0; ks < KS; ++ks) {
        __syncthreads();
        unsigned short* buf = smem + (size_t)(ks & 1) * BUFSH;
        if (ks + 1 < KS)
            stage(smem + (size_t)((ks + 1) & 1) * BUFSH, ks + 1);

        unsigned short* Ah = buf;
        unsigned short* Al = buf + 4096;
        unsigned short* Bh = buf + ABUF;
        unsigned short* Bl = Bh + 4 * BN * 8;

        short8 ah[WM], bh[WN];
        short8 al[WM], bl[WN];
#pragma unroll
        for (int m = 0; m < WM; ++m) {
            int ro = (g << 7) + wrow0 + m * 16 + lr;
            ah[m] = *(const short8*)&Ah[ro * 8];
            if constexpr (NT == 3) al[m] = *(const short8*)&Al[ro * 8];
        }
#pragma unroll
        for (int n = 0; n < WN; ++n) {
            int co = g * BN + wcol0 + n * 16 + lr;
            bh[n] = *(const short8*)&Bh[co * 8];
            if constexpr (NT == 3) bl[n] = *(const short8*)&Bl[co * 8];
        }
#pragma unroll
        for (int m = 0; m < WM; ++m)
#pragma unroll
            for (int n = 0; n < WN; ++n) {
                acc[m][n] = __builtin_amdgcn_mfma_f32_16x16x32_bf16(
                    ah[m], bh[n], acc[m][n], 0, 0, 0);
                if constexpr (NT == 3) {
                    acc[m][n] = __builtin_amdgcn_mfma_f32_16x16x32_bf16(
                        ah[m], bl[n], acc[m][n], 0, 0, 0);
                    acc[m][n] = __builtin_amdgcn_mfma_f32_16x16x32_bf16(
                        al[m], bh[n], acc[m][n], 0, 0, 0);
                }
            }
    }

    float bv[WN];
#pragma unroll
    for (int n = 0; n < WN; ++n) bv[n] = bias[n0 + wcol0 + n * 16 + lr];

    unsigned short* Sb = smem;
    float* Sf = (float*)smem;
    constexpr int NPASS = (OUT == 0) ? 2 : 1;

#pragma unroll
    for (int p = 0; p < NPASS; ++p) {
        __syncthreads();
#pragma unroll
        for (int m = 0; m < WM; ++m)
#pragma unroll
            for (int n = 0; n < WN; ++n)
#pragma unroll
                for (int q = 0; q < 4; ++q) {
                    int rl = wrow0 + m * 16 + g * 4 + q;
                    int cl = wcol0 + n * 16 + lr;
                    float x = acc[m][n][q] + bv[n];
                    if (ACT == 0) x = fmaxf(x, 0.f);
                    else x = tanhf(x);
                    if constexpr (OUT == 2) {
                        Sf[rl * BN + cl] = x;
                    } else {
                        unsigned short hb_ = f2bf(x);
                        Sb[rl * BN + cl] = (p == 0) ? hb_ : f2bf(x - bf2f(hb_));
                    }
                }
        __syncthreads();
        if constexpr (OUT == 2) {
            constexpr int SL = BN / 4;
#pragma unroll
            for (int it = 0; it < (128 * SL) / 256; ++it) {
                int idx = tid + it * 256;
                int row = idx / SL, sl = idx % SL;
                *(f32x4*)((float*)out0 + (size_t)(m0 + row) * NTOT + n0 + sl * 4)
                    = *(const f32x4*)&Sf[row * BN + sl * 4];
            }
        } else {
            constexpr int SL = BN / 8;
            unsigned short* dst = (unsigned short*)((p == 0) ? out0 : out1);
#pragma unroll
            for (int it = 0; it < (128 * SL) / 256; ++it) {
                int idx = tid + it * 256;
                int row = idx / SL, sl = idx % SL;
                *(short8*)&dst[(size_t)(m0 + row) * NTOT + n0 + sl * 8]
                    = *(const short8*)&Sb[row * BN + sl * 8];
            }
        }
    }
}

// ---------------------------------------------------------------------------
// NEW: BN=128 MFMA GEMM with counted-vmcnt pipeline (T3/T4): A 3-deep,
// B 2-deep, dynamic LDS. Per iter: bar; issue B(k+1); issue A(k+2);
// vmcnt(X); bar; compute(k). X leaves {A(k+1),B(k+1),A(k+2)} in flight ->
// A gets TWO compute phases (~960cy) to cover HBM (~900cy); old full-drain
// gave one (~480cy). vmcnt retires oldest-first (m135); bias loads are
// issued FIRST so they sit oldest in the queue and never perturb X.
// ---------------------------------------------------------------------------
template <int NT, int OUT, int ACT>
__global__ __launch_bounds__(256, 2) void mfma_gemm128(
    const unsigned short* __restrict__ Ah_g, const unsigned short* __restrict__ Al_g,
    int K,
    const unsigned short* __restrict__ Wh, const unsigned short* __restrict__ Wl,
    const float* __restrict__ bias,
    void* __restrict__ out0, void* __restrict__ out1, int NTOT)
{
    constexpr int BN = 128;
    constexpr int WM = 4, WN = 4, NWC = 2;
    constexpr int ASTR = (NT == 3) ? 8192 : 4096;   // shorts per A buffer
    constexpr int BSTR = (NT == 3) ? 8192 : 4096;   // shorts per B buffer
    constexpr int BOFF = 3 * ASTR;
    extern __shared__ unsigned short smem[];

    const int tid = threadIdx.x;
    int per = gridDim.x >> 3;
    int xcd = blockIdx.x & 7;
    int lid = blockIdx.x >> 3;
    int tile = xcd * per + lid;
    const int m0 = (tile >> 3) * 128;
    const int nb = tile & 7;
    const int n0 = nb * BN;
    const int w = tid >> 6, lane = tid & 63;
    const int g = lane >> 4, lr = lane & 15;
    const int wrow0 = (w / NWC) * (WM * 16);
    const int wcol0 = (w % NWC) * (WN * 16);
    const int KS = K >> 5;

    auto stageA = [&](int i, int ks) {
        unsigned short* Ah = smem + i * ASTR;
        unsigned short* Al = Ah + 4096;
#pragma unroll
        for (int it = 0; it < 2; ++it) {
            int t0 = it * 256 + w * 64;
            int t = t0 + lane;
            int row = t & 127, kb = t >> 7;
            size_t go = (size_t)(m0 + row) * K + ks * 32 + kb * 8;
            gload16(Ah_g + go, Ah + (size_t)t0 * 8);
            if constexpr (NT == 3) gload16(Al_g + go, Al + (size_t)t0 * 8);
        }
    };
    auto stageB = [&](int j, int ks) {
        unsigned short* Bh = smem + BOFF + j * BSTR;
        unsigned short* Bl = Bh + 4096;
        size_t bo = ((size_t)nb * KS + ks) * (BN * 32);
#pragma unroll
        for (int it = 0; it < 2; ++it) {
            int t0 = it * 256 + w * 64;
            size_t go = bo + (size_t)(t0 + lane) * 8;
            gload16(Wh + go, Bh + (size_t)t0 * 8);
            if constexpr (NT == 3) gload16(Wl + go, Bl + (size_t)t0 * 8);
        }
    };

    // bias first: oldest in vmcnt queue, retired by the first counted wait.
    float bv[WN];
#pragma unroll
    for (int n = 0; n < WN; ++n) bv[n] = bias[n0 + wcol0 + n * 16 + lr];
    __builtin_amdgcn_sched_barrier(0);

    f32x4 acc[WM][WN];
#pragma unroll
    for (int m = 0; m < WM; ++m)
#pragma unroll
        for (int n = 0; n < WN; ++n) {
            acc[m][n][0] = 0.f; acc[m][n][1] = 0.f;
            acc[m][n][2] = 0.f; acc[m][n][3] = 0.f;
        }

    // prologue: B(0), A(0), A(1)
    stageB(0, 0);
    stageA(0, 0);
    if (KS > 1) stageA(1, 1);

    for (int ks = 0; ks < KS; ++ks) {
        __builtin_amdgcn_s_barrier();          // all waves done reading iter ks-1
        if (ks + 1 < KS) stageB((ks + 1) & 1, ks + 1);
        if (ks + 2 < KS) stageA((ks + 2) % 3, ks + 2);
        // retire through {A(ks), B(ks)}; leave {A(ks+1), B(ks+1), A(ks+2)}
        if (ks + 2 < KS) {
            if constexpr (NT == 3) asm volatile("s_waitcnt vmcnt(12)" ::: "memory");
            else                   asm volatile("s_waitcnt vmcnt(6)" ::: "memory");
        } else if (ks + 1 < KS) {
            if constexpr (NT == 3) asm volatile("s_waitcnt vmcnt(8)" ::: "memory");
            else                   asm volatile("s_waitcnt vmcnt(4)" ::: "memory");
        } else {
            asm volatile("s_waitcnt vmcnt(0)" ::: "memory");
        }
        __builtin_amdgcn_s_barrier();          // all waves' stage(ks) landed
        __builtin_amdgcn_sched_barrier(0);

        unsigned short* Ah = smem + (ks % 3) * ASTR;
        unsigned short* Al = Ah + 4096;
        unsigned short* Bh = smem + BOFF + (ks & 1) * BSTR;
        unsigned short* Bl = Bh + 4096;

        short8 ah[WM], bh[WN];
        short8 al[WM], bl[WN];
#pragma unroll
        for (int m = 0; m < WM; ++m) {
            int ro = (g << 7) + wrow0 + m * 16 + lr;
            ah[m] = *(const short8*)&Ah[ro * 8];
            if constexpr (NT == 3) al[m] = *(const short8*)&Al[ro * 8];
        }
#pragma unroll
        for (int n = 0; n < WN; ++n) {
            int co = g * BN + wcol0 + n * 16 + lr;
            bh[n] = *(const short8*)&Bh[co * 8];
            if constexpr (NT == 3) bl[n] = *(const short8*)&Bl[co * 8];
        }
#pragma unroll
        for (int m = 0; m < WM; ++m)
#pragma unroll
            for (int n = 0; n < WN; ++n) {
                acc[m][n] = __builtin_amdgcn_mfma_f32_16x16x32_bf16(
                    ah[m], bh[n], acc[m][n], 0, 0, 0);
                if constexpr (NT == 3) {
                    acc[m][n] = __builtin_amdgcn_mfma_f32_16x16x32_bf16(
                        ah[m], bl[n], acc[m][n], 0, 0, 0);
                    acc[m][n] = __builtin_amdgcn_mfma_f32_16x16x32_bf16(
                        al[m], bh[n], acc[m][n], 0, 0, 0);
                }
            }
    }

    // ---- epilogue (same as proven kernel) ----
    unsigned short* Sb = smem;
    float* Sf = (float*)smem;
    constexpr int NPASS = (OUT == 0) ? 2 : 1;

#pragma unroll
    for (int p = 0; p < NPASS; ++p) {
        __syncthreads();
#pragma unroll
        for (int m = 0; m < WM; ++m)
#pragma unroll
            for (int n = 0; n < WN; ++n)
#pragma unroll
                for (int q = 0; q < 4; ++q) {
                    int rl = wrow0 + m * 16 + g * 4 + q;
                    int cl = wcol0 + n * 16 + lr;
                    float x = acc[m][n][q] + bv[n];
                    if (ACT == 0) x = fmaxf(x, 0.f);
                    else x = tanhf(x);
                    if constexpr (OUT == 2) {
                        Sf[rl * BN + cl] = x;
                    } else {
                        unsigned short hb_ = f2bf(x);
                        Sb[rl * BN + cl] = (p == 0) ? hb_ : f2bf(x - bf2f(hb_));
                    }
                }
        __syncthreads();
        if constexpr (OUT == 2) {
            constexpr int SL = BN / 4;
#pragma unroll
            for (int it = 0; it < (128 * SL) / 256; ++it) {
                int idx = tid + it * 256;
                int row = idx / SL, sl = idx % SL;
                *(f32x4*)((float*)out0 + (size_t)(m0 + row) * NTOT + n0 + sl * 4)
                    = *(const f32x4*)&Sf[row * BN + sl * 4];
            }
        } else {
            constexpr int SL = BN / 8;
            unsigned short* dst = (unsigned short*)((p == 0) ? out0 : out1);
#pragma unroll
            for (int it = 0; it < (128 * SL) / 256; ++it) {
                int idx = tid + it * 256;
                int row = idx / SL, sl = idx % SL;
                *(short8*)&dst[(size_t)(m0 + row) * NTOT + n0 + sl * 8]
                    = *(const short8*)&Sb[row * BN + sl * 8];
            }
        }
    }
}

// ---------------------------------------------------------------------------
// fp32 fixup GEMM, 32-row tiles (proven round 9).
// ---------------------------------------------------------------------------
template <int BN, int ACT>
__global__ __launch_bounds__(256) void gemm_fix(
    const int* __restrict__ mrows,
    const float* __restrict__ A, int K,
    const float* __restrict__ W, const float* __restrict__ bias,
    float* __restrict__ Co, int N)
{
    const int m0 = blockIdx.x * 32;
    if (m0 >= *mrows) return;

    constexpr int TN = BN / 16;
    __shared__ float At[16][36];
    __shared__ float Bt[16][BN + 4];

    const int tid = threadIdx.x;
    const int n0 = blockIdx.y * BN;
    const int r = tid >> 4;
    const int c = tid & 15;

    float acc[2][TN];
#pragma unroll
    for (int i = 0; i < 2; ++i)
#pragma unroll
        for (int j = 0; j < TN; ++j) acc[i][j] = 0.f;

    for (int k0 = 0; k0 < K; k0 += 16) {
        if (tid < 128) {
            int row = tid >> 2;
            int lf = tid & 3;
            float4 v = *(const float4*)(A + (size_t)(m0 + row) * K + k0 + lf * 4);
            At[lf * 4 + 0][row] = v.x;
            At[lf * 4 + 1][row] = v.y;
            At[lf * 4 + 2][row] = v.z;
            At[lf * 4 + 3][row] = v.w;
        }
        constexpr int NF4 = BN / 4;
        constexpr int NEL = 16 * NF4;
#pragma unroll
        for (int it = 0; it < NEL / 256; ++it) {
            int idx = tid + it * 256;
            int kk = idx / NF4;
            int f = idx % NF4;
            float4 v = *(const float4*)(W + (size_t)(k0 + kk) * N + n0 + f * 4);
            *(float4*)&Bt[kk][f * 4] = v;
        }
        __syncthreads();

#pragma unroll
        for (int kk = 0; kk < 16; ++kk) {
            float a0 = At[kk][r * 2];
            float a1 = At[kk][r * 2 + 1];
            float b[TN];
            if constexpr (BN == 128) {
                float4 b0 = *(const float4*)&Bt[kk][c * 4];
                float4 b1 = *(const float4*)&Bt[kk][64 + c * 4];
                b[0] = b0.x; b[1] = b0.y; b[2] = b0.z; b[3] = b0.w;
                b[4] = b1.x; b[5] = b1.y; b[6] = b1.z; b[7] = b1.w;
            } else {
                float4 b0 = *(const float4*)&Bt[kk][c * 4];
                b[0] = b0.x; b[1] = b0.y; b[2] = b0.z; b[3] = b0.w;
            }
#pragma unroll
            for (int j = 0; j < TN; ++j) {
                acc[0][j] = fmaf(a0, b[j], acc[0][j]);
                acc[1][j] = fmaf(a1, b[j], acc[1][j]);
            }
        }
        __syncthreads();
    }

#pragma unroll
    for (int i = 0; i < 2; ++i) {
        size_t row = (size_t)(m0 + r * 2 + i);
        if constexpr (BN == 128) {
            float e[8];
#pragma unroll
            for (int j = 0; j < 8; ++j) {
                int col = (j < 4) ? (c * 4 + j) : (64 + c * 4 + (j - 4));
                float v = acc[i][j] + bias[n0 + col];
                if (ACT == 0) v = fmaxf(v, 0.f);
                e[j] = v;
            }
            float4 v0, v1;
            v0.x = e[0]; v0.y = e[1]; v0.z = e[2]; v0.w = e[3];
            v1.x = e[4]; v1.y = e[5]; v1.z = e[6]; v1.w = e[7];
            *(float4*)&Co[row * N + n0 + c * 4] = v0;
            *(float4*)&Co[row * N + n0 + 64 + c * 4] = v1;
        } else {
            float e[4];
#pragma unroll
            for (int j = 0; j < 4; ++j) {
                float v = acc[i][j] + bias[n0 + c * 4 + j];
                if (ACT == 0) v = fmaxf(v, 0.f);
                e[j] = v;
            }
            float4 v0;
            v0.x = e[0]; v0.y = e[1]; v0.z = e[2]; v0.w = e[3];
            *(float4*)&Co[row * N + n0 + c * 4] = v0;
        }
    }
}

// ---------------------------------------------------------------------------
__global__ void sa_pre(const float* __restrict__ state, const float* __restrict__ action,
                       unsigned short* __restrict__ saH, unsigned short* __restrict__ saL)
{
    int idx = blockIdx.x * 256 + threadIdx.x;
    int row = idx / 12, q = idx % 12;
    const float* src = (q < 8) ? (state + (size_t)row * 64 + q * 8)
                               : (action + (size_t)row * 32 + (q - 8) * 8);
    f32x4 v0 = *(const f32x4*)src;
    f32x4 v1 = *(const f32x4*)(src + 4);
    short8 h, l;
#pragma unroll
    for (int j = 0; j < 8; ++j) {
        float x = (j < 4) ? v0[j] : v1[j - 4];
        unsigned short hb_ = f2bf(x);
        h[j] = (short)hb_;
        l[j] = (short)f2bf(x - bf2f(hb_));
    }
    *(short8*)&saH[(size_t)row * 96 + q * 8] = h;
    *(short8*)&saL[(size_t)row * 96 + q * 8] = l;
}

__global__ void xz_pre(const float* __restrict__ state, unsigned short* __restrict__ xz)
{
    int idx = blockIdx.x * 256 + threadIdx.x;
    int row = idx >> 4, q = idx & 15;
    f32x4 v = *(const f32x4*)&state[(size_t)row * 64 + q * 4];
    unsigned short o[4];
    o[0] = f2bf(v[0]); o[1] = f2bf(v[1]); o[2] = f2bf(v[2]); o[3] = f2bf(v[3]);
    *(uint2*)&xz[(size_t)row * 128 + q * 4] = *(uint2*)o;
}

// ---------------------------------------------------------------------------
// VQ score kernel: 64 rows x 512 codes per block, grid (M/64, 2).
// ---------------------------------------------------------------------------
__global__ __launch_bounds__(256) void vq_score(
    const float* __restrict__ midz,
    const float* __restrict__ codebook,
    const float* __restrict__ cbn,
    float4* __restrict__ part)
{
    __shared__ float Zt[64 * 68];
    __shared__ float Ct[64 * 68];
    __shared__ float cn[64];

    const int tid = threadIdx.x;
    const int m0 = blockIdx.x * 64;
    const int eh = blockIdx.y;
    const int r = tid >> 4;
    const int c = tid & 15;

#pragma unroll
    for (int it = 0; it < 4; ++it) {
        int idx = tid + it * 256;
        int row = idx >> 4, f = idx & 15;
        float4 v = *(const float4*)(midz + (size_t)(m0 + row) * 64 + f * 4);
        Zt[(f * 4 + 0) * 68 + row] = v.x;
        Zt[(f * 4 + 1) * 68 + row] = v.y;
        Zt[(f * 4 + 2) * 68 + row] = v.z;
        Zt[(f * 4 + 3) * 68 + row] = v.w;
    }

    float best[4], sec[4];
    int bidx[4];
#pragma unroll
    for (int i = 0; i < 4; ++i) { best[i] = 3.4e38f; sec[i] = 3.4e38f; bidx[i] = 0x7fffffff; }

    for (int ch = 0; ch < 8; ++ch) {
        int e0 = eh * 512 + ch * 64;
        __syncthreads();
#pragma unroll
        for (int it = 0; it < 4; ++it) {
            int idx = tid + it * 256;
            int e = idx >> 4, f = idx & 15;
            float4 v = *(const float4*)(codebook + (size_t)(e0 + e) * 64 + f * 4);
            Ct[(f * 4 + 0) * 68 + e] = v.x;
            Ct[(f * 4 + 1) * 68 + e] = v.y;
            Ct[(f * 4 + 2) * 68 + e] = v.z;
            Ct[(f * 4 + 3) * 68 + e] = v.w;
        }
        if (tid < 64) cn[tid] = cbn[e0 + tid];
        __syncthreads();

        float acc[4][4];
#pragma unroll
        for (int i = 0; i < 4; ++i)
#pragma unroll
            for (int j = 0; j < 4; ++j) acc[i][j] = 0.f;

#pragma unroll 8
        for (int kk = 0; kk < 64; ++kk) {
            float4 a = *(const float4*)&Zt[kk * 68 + r * 4];
            float4 b = *(const float4*)&Ct[kk * 68 + c * 4];
            acc[0][0] = fmaf(a.x, b.x, acc[0][0]);
            acc[0][1] = fmaf(a.x, b.y, acc[0][1]);
            acc[0][2] = fmaf(a.x, b.z, acc[0][2]);
            acc[0][3] = fmaf(a.x, b.w, acc[0][3]);
            acc[1][0] = fmaf(a.y, b.x, acc[1][0]);
            acc[1][1] = fmaf(a.y, b.y, acc[1][1]);
            acc[1][2] = fmaf(a.y, b.z, acc[1][2]);
            acc[1][3] = fmaf(a.y, b.w, acc[1][3]);
            acc[2][0] = fmaf(a.z, b.x, acc[2][0]);
            acc[2][1] = fmaf(a.z, b.y, acc[2][1]);
            acc[2][2] = fmaf(a.z, b.z, acc[2][2]);
            acc[2][3] = fmaf(a.z, b.w, acc[2][3]);
            acc[3][0] = fmaf(a.w, b.x, acc[3][0]);
            acc[3][1] = fmaf(a.w, b.y, acc[3][1]);
            acc[3][2] = fmaf(a.w, b.z, acc[3][2]);
            acc[3][3] = fmaf(a.w, b.w, acc[3][3]);
        }
#pragma unroll
        for (int i = 0; i < 4; ++i)
#pragma unroll
            for (int j = 0; j < 4; ++j) {
                int e = c * 4 + j;
                float s = cn[e] - 2.0f * acc[i][j];
                int gi = e0 + e;
                if (s < best[i] || (s == best[i] && gi < bidx[i])) {
                    sec[i] = best[i];
                    best[i] = s;
                    bidx[i] = gi;
                } else {
                    sec[i] = fminf(sec[i], s);
                }
            }
    }

#pragma unroll
    for (int i = 0; i < 4; ++i) {
#pragma unroll
        for (int m = 1; m < 16; m <<= 1) {
            float ob = __shfl_xor(best[i], m, 64);
            int oi = __shfl_xor(bidx[i], m, 64);
            float os = __shfl_xor(sec[i], m, 64);
            if (ob < best[i] || (ob == best[i] && oi < bidx[i])) {
                sec[i] = fminf(best[i], os);
                best[i] = ob;
                bidx[i] = oi;
            } else {
                sec[i] = fminf(sec[i], ob);
            }
        }
    }
    if (c == 0) {
#pragma unroll
        for (int i = 0; i < 4; ++i) {
            float4 p;
            p.x = best[i];
            p.y = sec[i];
            p.z = __int_as_float(bidx[i]);
            p.w = 0.f;
            part[(size_t)(m0 + r * 4 + i) * 2 + eh] = p;
        }
    }
}

// ---------------------------------------------------------------------------
// VQ merge + flag + latent head.  128 rows per block, grid mt.
// ---------------------------------------------------------------------------
__global__ __launch_bounds__(256) void vq_merge(
    const float4* __restrict__ part,
    const float* __restrict__ codebook,
    const float* __restrict__ mean_w, const float* __restrict__ mean_b,
    const float* __restrict__ logstd_w, const float* __restrict__ logstd_b,
    const float* __restrict__ eps,
    float* __restrict__ mean_out, float* __restrict__ std_out,
    unsigned short* __restrict__ xz,
    int* __restrict__ ctr, int* __restrict__ list, int rowbase)
{
    __shared__ float mw[4160];
    __shared__ float lw[4160];
    __shared__ int sidx[128];

    const int tid = threadIdx.x;
    const int m0 = blockIdx.x * 128;

    if (tid < 128) {
        size_t row = (size_t)(m0 + tid);
        float4 p0 = part[row * 2 + 0];
        float4 p1 = part[row * 2 + 1];
        int i0 = __float_as_int(p0.z), i1 = __float_as_int(p1.z);
        float b, s;
        int ix;
        if (p0.x < p1.x || (p0.x == p1.x && i0 < i1)) {
            b = p0.x; ix = i0; s = fminf(p0.y, p1.x);
        } else {
            b = p1.x; ix = i1; s = fminf(p1.y, p0.x);
        }
        sidx[tid] = ix;
        if (s - b < TAU) {
            int p = atomicAdd(ctr, 1);
            list[p] = rowbase + m0 + tid;
        }
    }
#pragma unroll
    for (int it = 0; it < 4; ++it) {
        int idx = tid + it * 256;
        int k = idx >> 4, f = idx & 15;
        float4 v = *(const float4*)(mean_w + (size_t)k * 64 + f * 4);
        mw[k * 65 + f * 4 + 0] = v.x;
        mw[k * 65 + f * 4 + 1] = v.y;
        mw[k * 65 + f * 4 + 2] = v.z;
        mw[k * 65 + f * 4 + 3] = v.w;
        float4 w2 = *(const float4*)(logstd_w + (size_t)k * 64 + f * 4);
        lw[k * 65 + f * 4 + 0] = w2.x;
        lw[k * 65 + f * 4 + 1] = w2.y;
        lw[k * 65 + f * 4 + 2] = w2.z;
        lw[k * 65 + f * 4 + 3] = w2.w;
    }
    __syncthreads();

    {
        int row = tid >> 1;
        int d0 = (tid & 1) * 32;
        int e = sidx[row];
        const float* cb = codebook + (size_t)e * 64;
        float mv[32], lv[32];
#pragma unroll
        for (int d = 0; d < 32; ++d) {
            mv[d] = mean_b[d0 + d];
            lv[d] = logstd_b[d0 + d];
        }
        for (int k = 0; k < 64; ++k) {
            float zk = cb[k];
#pragma unroll
            for (int d = 0; d < 32; ++d) {
                mv[d] = fmaf(zk, mw[k * 65 + d0 + d], mv[d]);
                lv[d] = fmaf(zk, lw[k * 65 + d0 + d], lv[d]);
            }
        }
        size_t ro = (size_t)(m0 + row) * 64 + d0;
        size_t xo = (size_t)(m0 + row) * 128 + 64 + d0;
#pragma unroll
        for (int d = 0; d < 32; ++d) {
            float mean = mv[d];
            float ls = fminf(fmaxf(lv[d], -4.f), 15.f);
            float sd = expf(ls);
            float z = fmaf(sd, eps[ro + d], mean);
            mean_out[ro + d] = mean;
            std_out[ro + d] = sd;
            xz[xo + d] = f2bf(z);
        }
    }
}

// ---------------------------------------------------------------------------
__global__ void gather_fix(const int* __restrict__ ctr, int* __restrict__ meta,
                           const int* __restrict__ list,
                           const float* __restrict__ state,
                           const float* __restrict__ action,
                           float* __restrict__ sa_fix)
{
    int cnt = *ctr; if (cnt > FMAX) cnt = FMAX;
    if (blockIdx.x == 0 && threadIdx.x == 0)
        meta[0] = (cnt + 31) & ~31;
    int t = blockIdx.x * 256 + threadIdx.x;
    if (t >= cnt * 24) return;
    int f = t / 24, q = t % 24;
    size_t g = (size_t)list[f];
    f32x4 v = (q < 16) ? *(const f32x4*)&state[g * 64 + q * 4]
                       : *(const f32x4*)&action[g * 32 + (q - 16) * 4];
    *(f32x4*)&sa_fix[(size_t)f * 96 + q * 4] = v;
}

// ---------------------------------------------------------------------------
__global__ __launch_bounds__(256) void vq_fix(
    const int* __restrict__ ctr, const int* __restrict__ list,
    const float* __restrict__ mz_fix,
    const float* __restrict__ codebook, const float* __restrict__ cbn,
    const float* __restrict__ mean_w, const float* __restrict__ mean_b,
    const float* __restrict__ logstd_w, const float* __restrict__ logstd_b,
    const float* __restrict__ eps,
    float* __restrict__ mean_out, float* __restrict__ std_out,
    unsigned short* __restrict__ xz)
{
    __shared__ float mzs[8][64];
    __shared__ float zns[8];
    __shared__ float sv[2048];
    __shared__ int si[2048];
    __shared__ int am_s[8];

    int cnt = *ctr; if (cnt > FMAX) cnt = FMAX;
    const int base = blockIdx.x * 8;
    if (base >= cnt) return;
    const int nr = min(8, cnt - base);
    const int tid = threadIdx.x;

    if (tid < 128) {
        int rr = tid >> 4, q = tid & 15;
        int src = base + ((rr < nr) ? rr : 0);
        *(f32x4*)&mzs[rr][q * 4] = *(const f32x4*)&mz_fix[(size_t)src * 64 + q * 4];
    }
    __syncthreads();
    if (tid < 8) {
        float s = 0.f;
#pragma unroll
        for (int k = 0; k < 64; ++k) s = fmaf(mzs[tid][k], mzs[tid][k], s);
        zns[tid] = s;
    }
    __syncthreads();

    float bb[8];
    int bi[8];
#pragma unroll
    for (int rr = 0; rr < 8; ++rr) { bb[rr] = 3.4e38f; bi[rr] = 0x7fffffff; }
    for (int j = 0; j < 4; ++j) {
        int code = tid + j * 256;
        const f32x4* cp = (const f32x4*)(codebook + (size_t)code * 64);
        float dot[8];
#pragma unroll
        for (int rr = 0; rr < 8; ++rr) dot[rr] = 0.f;
        for (int t = 0; t < 16; ++t) {
            f32x4 cv = cp[t];
#pragma unroll
            for (int e = 0; e < 4; ++e) {
                float cvv = cv[e];
#pragma unroll
                for (int rr = 0; rr < 8; ++rr)
                    dot[rr] = fmaf(mzs[rr][t * 4 + e], cvv, dot[rr]);
            }
        }
        float cnv = cbn[code];
#pragma unroll
        for (int rr = 0; rr < 8; ++rr) {
            float s = (zns[rr] + cnv) - 2.0f * dot[rr];
            if (s < bb[rr] || (s == bb[rr] && code < bi[rr])) {
                bb[rr] = s; bi[rr] = code;
            }
        }
    }
#pragma unroll
    for (int rr = 0; rr < 8; ++rr) {
        sv[rr * 256 + tid] = bb[rr];
        si[rr * 256 + tid] = bi[rr];
    }
    __syncthreads();
    if (tid < 8) {
        float b = 3.4e38f;
        int ix = 0x7fffffff;
        for (int t = 0; t < 256; ++t) {
            float v = sv[tid * 256 + t];
            int iv = si[tid * 256 + t];
            if (v < b || (v == b && iv < ix)) { b = v; ix = iv; }
        }
        am_s[tid] = ix;
    }
    __syncthreads();

    for (int jo = 0; jo < 2; ++jo) {
        int o = tid + jo * 256;
        int rr = o >> 6, d = o & 63;
        if (rr < nr) {
            int e = am_s[rr];
            size_t g = (size_t)list[base + rr];
            float mv = mean_b[d], lv = logstd_b[d];
            const float* cb = codebook + (size_t)e * 64;
            for (int k = 0; k < 64; ++k) {
                float zk = cb[k];
                mv = fmaf(zk, mean_w[(size_t)k * 64 + d], mv);
                lv = fmaf(zk, logstd_w[(size_t)k * 64 + d], lv);
            }
            float ls = fminf(fmaxf(lv, -4.f), 15.f);
            float sd = expf(ls);
            float z = fmaf(sd, eps[g * 64 + d], mv);
            mean_out[g * 64 + d] = mv;
            std_out[g * 64 + d] = sd;
            xz[g * 128 + 64 + d] = f2bf(z);
        }
    }
}

// ---------------------------------------------------------------------------
extern "C" void kernel_launch(void* const* d_in, const int* in_sizes, int n_in,
                              void* d_out, int out_size, void* d_ws, size_t ws_size,
                              hipStream_t stream)
{
    const float* state    = (const float*)d_in[0];
    const float* action   = (const float*)d_in[1];
    const float* eps      = (const float*)d_in[2];
    const float* enc_w1   = (const float*)d_in[3];
    const float* enc_b1   = (const float*)d_in[4];
    const float* enc_w2   = (const float*)d_in[5];
    const float* enc_b2   = (const float*)d_in[6];
    const float* enc_w3   = (const float*)d_in[7];
    const float* enc_b3   = (const float*)d_in[8];
    const float* mean_w   = (const float*)d_in[9];
    const float* mean_b   = (const float*)d_in[10];
    const float* logstd_w = (const float*)d_in[11];
    const float* logstd_b = (const float*)d_in[12];
    const float* codebook = (const float*)d_in[13];
    const float* dec_w1   = (const float*)d_in[14];
    const float* dec_b1   = (const float*)d_in[15];
    const float* dec_w2   = (const float*)d_in[16];
    const float* dec_b2   = (const float*)d_in[17];
    const float* dec_w3   = (const float*)d_in[18];
    const float* dec_b3   = (const float*)d_in[19];

    float* out = (float*)d_out;
    float* u_out = out;
    float* mean_out = out + (size_t)B_TOTAL * 32;
    float* std_out = mean_out + (size_t)B_TOTAL * 64;

    // ---- fixed ws region ----
    char* base = (char*)d_ws;
    float* cbn = (float*)base;                                   // 4096
    unsigned short* W1h = (unsigned short*)(base + 4096);        // 196608
    unsigned short* W1l = (unsigned short*)(base + 200704);      // 196608
    unsigned short* W2h = (unsigned short*)(base + 397312);      // 2097152
    unsigned short* W2l = (unsigned short*)(base + 2494464);     // 2097152
    unsigned short* W3h = (unsigned short*)(base + 4591616);     // 131072
    unsigned short* W3l = (unsigned short*)(base + 4722688);     // 131072
    unsigned short* W4h = (unsigned short*)(base + 4853760);     // 262144
    unsigned short* W5h = (unsigned short*)(base + 5115904);     // 2097152
    unsigned short* W6h = (unsigned short*)(base + 7213056);     // 65536
    int* ctr            = (int*)(base + 7278592);                // 256
    int* flag_list      = (int*)(base + 7278848);                // 262144
    int* meta           = (int*)(base + 7540992);                // 256
    float4* part        = (float4*)(base + 7541248);             // B*2*16 = 2097152
    float* sa_fix       = (float*)(base + 9638400);              // FMAX*96*4   = 2359296
    float* h1_fix       = (float*)(base + 11997696);             // FMAX*1024*4 = 25165824
    float* h2_fix       = (float*)(base + 37163520);             // 25165824
    float* mz_fix       = (float*)(base + 62329344);             // FMAX*64*4   = 1572864
    const size_t FIXED  = 63902208;                              // ~64 MB

    unsigned short* xz_g = (unsigned short*)(base + FIXED);      // 16 MB
    const size_t XZ_SZ = (size_t)B_TOTAL * 128 * 2;

    const size_t per_row = 8832;
    size_t avail = (ws_size > FIXED + XZ_SZ) ? (ws_size - FIXED - XZ_SZ) : 0;
    long maxC = (long)(avail / per_row);
    int C = (int)(maxC / 1024) * 1024;
    if (C > B_TOTAL) C = B_TOTAL;
    if (C < 1024) C = 1024;

    char* dyn = base + FIXED + XZ_SZ;
    unsigned short* saH = (unsigned short*)dyn;                   // [C,96]
    unsigned short* saL = saH + (size_t)C * 96;
    unsigned short* h1H = saL + (size_t)C * 96;                   // [C,1024]
    unsigned short* h1L = h1H + (size_t)C * 1024;
    unsigned short* h2H = h1L + (size_t)C * 1024;
    unsigned short* h2L = h2H + (size_t)C * 1024;
    float* mz = (float*)(h2L + (size_t)C * 1024);                 // [C,64]
    unsigned short* hc = h1H;   // decoder reuse
    unsigned short* hd = h2H;

    // enable 80 KB dynamic LDS for the pipelined NT3 kernel; fall back if denied
    bool deep = hipFuncSetAttribute(
        reinterpret_cast<const void*>(&mfma_gemm128<3, 0, 0>),
        hipFuncAttributeMaxDynamicSharedMemorySize, 81920) == hipSuccess;

    // ---- once per call ----
    cb_norms<<<dim3(4), dim3(256), 0, stream>>>(codebook, cbn);
    zero_ctr<<<dim3(1), dim3(64), 0, stream>>>(ctr);
    w_xform<3, 128><<<dim3(3, 8), dim3(256), 0, stream>>>(enc_w1, 96, 1024, W1h, W1l);
    w_xform<3, 128><<<dim3(32, 8), dim3(256), 0, stream>>>(enc_w2, 1024, 1024, W2h, W2l);
    w_xform<3, 64><<<dim3(32, 1), dim3(256), 0, stream>>>(enc_w3, 1024, 64, W3h, W3l);
    w_xform<1, 128><<<dim3(4, 8), dim3(256), 0, stream>>>(dec_w1, 128, 1024, W4h, nullptr);
    w_xform<1, 128><<<dim3(32, 8), dim3(256), 0, stream>>>(dec_w2, 1024, 1024, W5h, nullptr);
    w_xform<1, 32><<<dim3(32, 1), dim3(256), 0, stream>>>(dec_w3, 1024, 32, W6h, nullptr);

    // ---- phase A: encoder + VQ for all chunks ----
    for (int r0 = 0; r0 < B_TOTAL; r0 += C) {
        int M = (r0 + C <= B_TOTAL) ? C : (B_TOTAL - r0);
        int mt = M / 128;

        sa_pre<<<dim3(M * 12 / 256), dim3(256), 0, stream>>>(
            state + (size_t)r0 * SDIM, action + (size_t)r0 * ADIM, saH, saL);

        if (deep) {
            mfma_gemm128<3, 0, 0><<<dim3(mt * 8), dim3(256), 81920, stream>>>(
                saH, saL, 96, W1h, W1l, enc_b1, h1H, h1L, 1024);
            mfma_gemm128<3, 0, 0><<<dim3(mt * 8), dim3(256), 81920, stream>>>(
                h1H, h1L, 1024, W2h, W2l, enc_b2, h2H, h2L, 1024);
        } else {
            mfma_gemm<3, 128, 0, 0><<<dim3(mt * 8), dim3(256), 0, stream>>>(
                saH, saL, 96, W1h, W1l, enc_b1, h1H, h1L, 1024);
            mfma_gemm<3, 128, 0, 0><<<dim3(mt * 8), dim3(256), 0, stream>>>(
                h1H, h1L, 1024, W2h, W2l, enc_b2, h2H, h2L, 1024);
        }
        mfma_gemm<3, 64, 2, 0><<<dim3(mt), dim3(256), 0, stream>>>(
            h2H, h2L, 1024, W3h, W3l, enc_b3, mz, nullptr, 64);

        xz_pre<<<dim3(M / 16), dim3(256), 0, stream>>>(
            state + (size_t)r0 * SDIM, xz_g + (size_t)r0 * 128);

        vq_score<<<dim3(M / 64, 2), dim3(256), 0, stream>>>(
            mz, codebook, cbn, part + (size_t)r0 * 2);
        vq_merge<<<dim3(mt), dim3(256), 0, stream>>>(
            part + (size_t)r0 * 2, codebook,
            mean_w, mean_b, logstd_w, logstd_b,
            eps + (size_t)r0 * LDIM,
            mean_out + (size_t)r0 * LDIM, std_out + (size_t)r0 * LDIM,
            xz_g + (size_t)r0 * 128, ctr, flag_list, r0);
    }

    // ---- phase B: exact-fp32 fixup as 32-row-tile GEMMs on gathered rows ----
    gather_fix<<<dim3(FMAX * 24 / 256), dim3(256), 0, stream>>>(
        ctr, meta, flag_list, state, action, sa_fix);
    gemm_fix<128, 0><<<dim3(FMAX / 32, 8), dim3(256), 0, stream>>>(
        meta, sa_fix, 96, enc_w1, enc_b1, h1_fix, 1024);
    gemm_fix<128, 0><<<dim3(FMAX / 32, 8), dim3(256), 0, stream>>>(
        meta, h1_fix, 1024, enc_w2, enc_b2, h2_fix, 1024);
    gemm_fix<64, 0><<<dim3(FMAX / 32, 1), dim3(256), 0, stream>>>(
        meta, h2_fix, 1024, enc_w3, enc_b3, mz_fix, 64);
    vq_fix<<<dim3(FMAX / 8), dim3(256), 0, stream>>>(
        ctr, flag_list, mz_fix, codebook, cbn,
        mean_w, mean_b, logstd_w, logstd_b, eps,
        mean_out, std_out, xz_g);

    // ---- phase C: decoder for all chunks ----
    for (int r0 = 0; r0 < B_TOTAL; r0 += C) {
        int M = (r0 + C <= B_TOTAL) ? C : (B_TOTAL - r0);
        int mt = M / 128;

        mfma_gemm<1, 128, 1, 0><<<dim3(mt * 8), dim3(256), 0, stream>>>(
            xz_g + (size_t)r0 * 128, nullptr, 128, W4h, nullptr, dec_b1, hc, nullptr, 1024);
        mfma_gemm<1, 128, 1, 0><<<dim3(mt * 8), dim3(256), 0, stream>>>(
            hc, nullptr, 1024, W5h, nullptr, dec_b2, hd, nullptr, 1024);
        mfma_gemm<1, 32, 2, 1><<<dim3(mt), dim3(256), 0, stream>>>(
            hd, nullptr, 1024, W6h, nullptr, dec_b3,
            u_out + (size_t)r0 * ADIM, nullptr, 32);
    }
}

// Round 12
// 1596.271 us; speedup vs baseline: 1.9044x; 1.1060x over previous
//
#include <hip/hip_runtime.h>
#include <cstdint>
#include <cstddef>

#define B_TOTAL 65536
#define SDIM 64
#define ADIM 32
#define LDIM 64
#define HDIM 1024
#define NEMB 1024
#define TAU 0.125f
#define FMAX 6144

typedef __attribute__((ext_vector_type(8))) short short8;
typedef __attribute__((ext_vector_type(4))) float f32x4;

__device__ inline unsigned short f2bf(float f) {
    unsigned int u = __float_as_uint(f);
    u += 0x7fffu + ((u >> 16) & 1u);
    return (unsigned short)(u >> 16);
}
__device__ inline float bf2f(unsigned short s) {
    return __uint_as_float(((unsigned int)s) << 16);
}

// async global->LDS, 16B per lane; LDS dest = wave-uniform base + lane*16.
__device__ inline void gload16(const unsigned short* g, unsigned short* l) {
    __builtin_amdgcn_global_load_lds(
        (__attribute__((address_space(1))) void*)(g),
        (__attribute__((address_space(3))) void*)(l), 16, 0, 0);
}

// ---------------------------------------------------------------------------
__global__ void cb_norms(const float* __restrict__ codebook, float* __restrict__ cbn)
{
    int i = blockIdx.x * 256 + threadIdx.x;
    if (i < NEMB) {
        float s = 0.f;
#pragma unroll
        for (int k = 0; k < LDIM; ++k) {
            float v = codebook[(size_t)i * LDIM + k];
            s = fmaf(v, v, s);
        }
        cbn[i] = s;
    }
}

__global__ void zero_ctr(int* ctr) { if (threadIdx.x == 0) *ctr = 0; }

// ---------------------------------------------------------------------------
// Weight pre-transform: W[K][N] fp32 -> bf16 plane(s), MFMA-B-ready layout.
// ---------------------------------------------------------------------------
template <int NT, int BN>
__global__ __launch_bounds__(256) void w_xform(
    const float* __restrict__ W, int K, int N,
    unsigned short* __restrict__ Ph, unsigned short* __restrict__ Pl)
{
    __shared__ float Ws[32][BN + 4];
    const int tid = threadIdx.x;
    const int ks = blockIdx.x, nb = blockIdx.y;
    const int k0 = ks * 32, n0 = nb * BN;
    constexpr int LT = 32 * (BN / 4);
#pragma unroll
    for (int it = 0; it < (LT + 255) / 256; ++it) {
        int idx = tid + it * 256;
        if (LT % 256 == 0 || idx < LT) {
            int k = idx / (BN / 4);
            int nf = idx % (BN / 4);
            *(f32x4*)&Ws[k][nf * 4] =
                *(const f32x4*)&W[(size_t)(k0 + k) * N + n0 + nf * 4];
        }
    }
    __syncthreads();
    const int KS = K >> 5;
    size_t bo = ((size_t)nb * KS + ks) * (BN * 32);
    constexpr int WT = BN * 4;
#pragma unroll
    for (int it = 0; it < (WT + 255) / 256; ++it) {
        int idx = tid + it * 256;
        if (WT % 256 == 0 || idx < WT) {
            int kb = idx / BN;
            int n = idx % BN;
            short8 h, l;
#pragma unroll
            for (int j = 0; j < 8; ++j) {
                float x = Ws[kb * 8 + j][n];
                unsigned short hb_ = f2bf(x);
                h[j] = (short)hb_;
                if (NT == 3) l[j] = (short)f2bf(x - bf2f(hb_));
            }
            *(short8*)&Ph[bo + (size_t)idx * 8] = h;
            if (NT == 3) *(short8*)&Pl[bo + (size_t)idx * 8] = l;
        }
    }
}

// ---------------------------------------------------------------------------
// OLD proven BF16 MFMA GEMM, 2-buf full-drain (fallback only).
// ---------------------------------------------------------------------------
template <int NT, int BN, int OUT, int ACT>
__global__ __launch_bounds__(256, 2) void mfma_gemm(
    const unsigned short* __restrict__ Ah_g, const unsigned short* __restrict__ Al_g,
    int K,
    const unsigned short* __restrict__ Wh, const unsigned short* __restrict__ Wl,
    const float* __restrict__ bias,
    void* __restrict__ out0, void* __restrict__ out1, int NTOT)
{
    constexpr int NWC = (BN == 128) ? 2 : 1;
    constexpr int WM = (BN == 128) ? 4 : 2;
    constexpr int WN = (BN == 32) ? 2 : 4;
    constexpr int ABUF = (NT == 3) ? 8192 : 4096;
    constexpr int BBUF = 4 * BN * 8 * ((NT == 3) ? 2 : 1);
    constexpr int BUFSH = ABUF + BBUF;

    __shared__ unsigned short smem[2 * BUFSH];

    const int tid = threadIdx.x;
    int row_t, nb;
    if constexpr (BN == 128) {
        int per = gridDim.x >> 3;
        int xcd = blockIdx.x & 7;
        int lid = blockIdx.x >> 3;
        int tile = xcd * per + lid;
        row_t = tile >> 3;
        nb = tile & 7;
    } else {
        row_t = blockIdx.x;
        nb = 0;
    }
    const int m0 = row_t * 128;
    const int n0 = nb * BN;
    const int w = tid >> 6, lane = tid & 63;
    const int g = lane >> 4, lr = lane & 15;
    const int wrow0 = (w / NWC) * (WM * 16);
    const int wcol0 = (w % NWC) * (WN * 16);
    const int KS = K >> 5;

    auto stage = [&](unsigned short* buf, int ks) {
        unsigned short* Ah = buf;
        unsigned short* Al = buf + 4096;
        unsigned short* Bh = buf + ABUF;
        unsigned short* Bl = Bh + 4 * BN * 8;
#pragma unroll
        for (int it = 0; it < 2; ++it) {
            int t0 = it * 256 + w * 64;
            int t = t0 + lane;
            int row = t & 127, kb = t >> 7;
            size_t go = (size_t)(m0 + row) * K + ks * 32 + kb * 8;
            gload16(Ah_g + go, Ah + (size_t)t0 * 8);
            if constexpr (NT == 3) gload16(Al_g + go, Al + (size_t)t0 * 8);
        }
        size_t bo = ((size_t)nb * KS + ks) * (BN * 32);
        constexpr int BT = 4 * BN;
        if constexpr (BT >= 256) {
#pragma unroll
            for (int it = 0; it < BT / 256; ++it) {
                int t0 = it * 256 + w * 64;
                size_t go = bo + (size_t)(t0 + lane) * 8;
                gload16(Wh + go, Bh + (size_t)t0 * 8);
                if constexpr (NT == 3) gload16(Wl + go, Bl + (size_t)t0 * 8);
            }
        } else {
            if (tid < BT) {
                int t0 = w * 64;
                size_t go = bo + (size_t)(t0 + lane) * 8;
                gload16(Wh + go, Bh + (size_t)t0 * 8);
                if constexpr (NT == 3) gload16(Wl + go, Bl + (size_t)t0 * 8);
            }
        }
    };

    f32x4 acc[WM][WN];
#pragma unroll
    for (int m = 0; m < WM; ++m)
#pragma unroll
        for (int n = 0; n < WN; ++n) {
            acc[m][n][0] = 0.f; acc[m][n][1] = 0.f;
            acc[m][n][2] = 0.f; acc[m][n][3] = 0.f;
        }

    stage(smem, 0);

    for (int ks = 0; ks < KS; ++ks) {
        __syncthreads();
        unsigned short* buf = smem + (size_t)(ks & 1) * BUFSH;
        if (ks + 1 < KS)
            stage(smem + (size_t)((ks + 1) & 1) * BUFSH, ks + 1);

        unsigned short* Ah = buf;
        unsigned short* Al = buf + 4096;
        unsigned short* Bh = buf + ABUF;
        unsigned short* Bl = Bh + 4 * BN * 8;

        short8 ah[WM], bh[WN];
        short8 al[WM], bl[WN];
#pragma unroll
        for (int m = 0; m < WM; ++m) {
            int ro = (g << 7) + wrow0 + m * 16 + lr;
            ah[m] = *(const short8*)&Ah[ro * 8];
            if constexpr (NT == 3) al[m] = *(const short8*)&Al[ro * 8];
        }
#pragma unroll
        for (int n = 0; n < WN; ++n) {
            int co = g * BN + wcol0 + n * 16 + lr;
            bh[n] = *(const short8*)&Bh[co * 8];
            if constexpr (NT == 3) bl[n] = *(const short8*)&Bl[co * 8];
        }
#pragma unroll
        for (int m = 0; m < WM; ++m)
#pragma unroll
            for (int n = 0; n < WN; ++n) {
                acc[m][n] = __builtin_amdgcn_mfma_f32_16x16x32_bf16(
                    ah[m], bh[n], acc[m][n], 0, 0, 0);
                if constexpr (NT == 3) {
                    acc[m][n] = __builtin_amdgcn_mfma_f32_16x16x32_bf16(
                        ah[m], bl[n], acc[m][n], 0, 0, 0);
                    acc[m][n] = __builtin_amdgcn_mfma_f32_16x16x32_bf16(
                        al[m], bh[n], acc[m][n], 0, 0, 0);
                }
            }
    }

    float bv[WN];
#pragma unroll
    for (int n = 0; n < WN; ++n) bv[n] = bias[n0 + wcol0 + n * 16 + lr];

    unsigned short* Sb = smem;
    float* Sf = (float*)smem;
    constexpr int NPASS = (OUT == 0) ? 2 : 1;

#pragma unroll
    for (int p = 0; p < NPASS; ++p) {
        __syncthreads();
#pragma unroll
        for (int m = 0; m < WM; ++m)
#pragma unroll
            for (int n = 0; n < WN; ++n)
#pragma unroll
                for (int q = 0; q < 4; ++q) {
                    int rl = wrow0 + m * 16 + g * 4 + q;
                    int cl = wcol0 + n * 16 + lr;
                    float x = acc[m][n][q] + bv[n];
                    if (ACT == 0) x = fmaxf(x, 0.f);
                    else x = tanhf(x);
                    if constexpr (OUT == 2) {
                        Sf[rl * BN + cl] = x;
                    } else {
                        unsigned short hb_ = f2bf(x);
                        Sb[rl * BN + cl] = (p == 0) ? hb_ : f2bf(x - bf2f(hb_));
                    }
                }
        __syncthreads();
        if constexpr (OUT == 2) {
            constexpr int SL = BN / 4;
#pragma unroll
            for (int it = 0; it < (128 * SL) / 256; ++it) {
                int idx = tid + it * 256;
                int row = idx / SL, sl = idx % SL;
                *(f32x4*)((float*)out0 + (size_t)(m0 + row) * NTOT + n0 + sl * 4)
                    = *(const f32x4*)&Sf[row * BN + sl * 4];
            }
        } else {
            constexpr int SL = BN / 8;
            unsigned short* dst = (unsigned short*)((p == 0) ? out0 : out1);
#pragma unroll
            for (int it = 0; it < (128 * SL) / 256; ++it) {
                int idx = tid + it * 256;
                int row = idx / SL, sl = idx % SL;
                *(short8*)&dst[(size_t)(m0 + row) * NTOT + n0 + sl * 8]
                    = *(const short8*)&Sb[row * BN + sl * 8];
            }
        }
    }
}

// ---------------------------------------------------------------------------
// BN=128 MFMA GEMM, counted-vmcnt pipeline: A 3-deep, B 2-deep, dynamic LDS.
// Proven round 11 (+4.5% over full-drain on NT3).
// ---------------------------------------------------------------------------
template <int NT, int OUT, int ACT>
__global__ __launch_bounds__(256, 2) void mfma_gemm128(
    const unsigned short* __restrict__ Ah_g, const unsigned short* __restrict__ Al_g,
    int K,
    const unsigned short* __restrict__ Wh, const unsigned short* __restrict__ Wl,
    const float* __restrict__ bias,
    void* __restrict__ out0, void* __restrict__ out1, int NTOT)
{
    constexpr int BN = 128;
    constexpr int WM = 4, WN = 4, NWC = 2;
    constexpr int ASTR = (NT == 3) ? 8192 : 4096;
    constexpr int BSTR = (NT == 3) ? 8192 : 4096;
    constexpr int BOFF = 3 * ASTR;
    extern __shared__ unsigned short smem[];

    const int tid = threadIdx.x;
    int per = gridDim.x >> 3;
    int xcd = blockIdx.x & 7;
    int lid = blockIdx.x >> 3;
    int tile = xcd * per + lid;
    const int m0 = (tile >> 3) * 128;
    const int nb = tile & 7;
    const int n0 = nb * BN;
    const int w = tid >> 6, lane = tid & 63;
    const int g = lane >> 4, lr = lane & 15;
    const int wrow0 = (w / NWC) * (WM * 16);
    const int wcol0 = (w % NWC) * (WN * 16);
    const int KS = K >> 5;

    auto stageA = [&](int i, int ks) {
        unsigned short* Ah = smem + i * ASTR;
        unsigned short* Al = Ah + 4096;
#pragma unroll
        for (int it = 0; it < 2; ++it) {
            int t0 = it * 256 + w * 64;
            int t = t0 + lane;
            int row = t & 127, kb = t >> 7;
            size_t go = (size_t)(m0 + row) * K + ks * 32 + kb * 8;
            gload16(Ah_g + go, Ah + (size_t)t0 * 8);
            if constexpr (NT == 3) gload16(Al_g + go, Al + (size_t)t0 * 8);
        }
    };
    auto stageB = [&](int j, int ks) {
        unsigned short* Bh = smem + BOFF + j * BSTR;
        unsigned short* Bl = Bh + 4096;
        size_t bo = ((size_t)nb * KS + ks) * (BN * 32);
#pragma unroll
        for (int it = 0; it < 2; ++it) {
            int t0 = it * 256 + w * 64;
            size_t go = bo + (size_t)(t0 + lane) * 8;
            gload16(Wh + go, Bh + (size_t)t0 * 8);
            if constexpr (NT == 3) gload16(Wl + go, Bl + (size_t)t0 * 8);
        }
    };

    // bias first: oldest in vmcnt queue, retired by the first counted wait.
    float bv[WN];
#pragma unroll
    for (int n = 0; n < WN; ++n) bv[n] = bias[n0 + wcol0 + n * 16 + lr];
    __builtin_amdgcn_sched_barrier(0);

    f32x4 acc[WM][WN];
#pragma unroll
    for (int m = 0; m < WM; ++m)
#pragma unroll
        for (int n = 0; n < WN; ++n) {
            acc[m][n][0] = 0.f; acc[m][n][1] = 0.f;
            acc[m][n][2] = 0.f; acc[m][n][3] = 0.f;
        }

    stageB(0, 0);
    stageA(0, 0);
    if (KS > 1) stageA(1, 1);

    for (int ks = 0; ks < KS; ++ks) {
        __builtin_amdgcn_s_barrier();
        if (ks + 1 < KS) stageB((ks + 1) & 1, ks + 1);
        if (ks + 2 < KS) stageA((ks + 2) % 3, ks + 2);
        if (ks + 2 < KS) {
            if constexpr (NT == 3) asm volatile("s_waitcnt vmcnt(12)" ::: "memory");
            else                   asm volatile("s_waitcnt vmcnt(6)" ::: "memory");
        } else if (ks + 1 < KS) {
            if constexpr (NT == 3) asm volatile("s_waitcnt vmcnt(8)" ::: "memory");
            else                   asm volatile("s_waitcnt vmcnt(4)" ::: "memory");
        } else {
            asm volatile("s_waitcnt vmcnt(0)" ::: "memory");
        }
        __builtin_amdgcn_s_barrier();
        __builtin_amdgcn_sched_barrier(0);

        unsigned short* Ah = smem + (ks % 3) * ASTR;
        unsigned short* Al = Ah + 4096;
        unsigned short* Bh = smem + BOFF + (ks & 1) * BSTR;
        unsigned short* Bl = Bh + 4096;

        short8 ah[WM], bh[WN];
        short8 al[WM], bl[WN];
#pragma unroll
        for (int m = 0; m < WM; ++m) {
            int ro = (g << 7) + wrow0 + m * 16 + lr;
            ah[m] = *(const short8*)&Ah[ro * 8];
            if constexpr (NT == 3) al[m] = *(const short8*)&Al[ro * 8];
        }
#pragma unroll
        for (int n = 0; n < WN; ++n) {
            int co = g * BN + wcol0 + n * 16 + lr;
            bh[n] = *(const short8*)&Bh[co * 8];
            if constexpr (NT == 3) bl[n] = *(const short8*)&Bl[co * 8];
        }
#pragma unroll
        for (int m = 0; m < WM; ++m)
#pragma unroll
            for (int n = 0; n < WN; ++n) {
                acc[m][n] = __builtin_amdgcn_mfma_f32_16x16x32_bf16(
                    ah[m], bh[n], acc[m][n], 0, 0, 0);
                if constexpr (NT == 3) {
                    acc[m][n] = __builtin_amdgcn_mfma_f32_16x16x32_bf16(
                        ah[m], bl[n], acc[m][n], 0, 0, 0);
                    acc[m][n] = __builtin_amdgcn_mfma_f32_16x16x32_bf16(
                        al[m], bh[n], acc[m][n], 0, 0, 0);
                }
            }
    }

    unsigned short* Sb = smem;
    float* Sf = (float*)smem;
    constexpr int NPASS = (OUT == 0) ? 2 : 1;

#pragma unroll
    for (int p = 0; p < NPASS; ++p) {
        __syncthreads();
#pragma unroll
        for (int m = 0; m < WM; ++m)
#pragma unroll
            for (int n = 0; n < WN; ++n)
#pragma unroll
                for (int q = 0; q < 4; ++q) {
                    int rl = wrow0 + m * 16 + g * 4 + q;
                    int cl = wcol0 + n * 16 + lr;
                    float x = acc[m][n][q] + bv[n];
                    if (ACT == 0) x = fmaxf(x, 0.f);
                    else x = tanhf(x);
                    if constexpr (OUT == 2) {
                        Sf[rl * BN + cl] = x;
                    } else {
                        unsigned short hb_ = f2bf(x);
                        Sb[rl * BN + cl] = (p == 0) ? hb_ : f2bf(x - bf2f(hb_));
                    }
                }
        __syncthreads();
        if constexpr (OUT == 2) {
            constexpr int SL = BN / 4;
#pragma unroll
            for (int it = 0; it < (128 * SL) / 256; ++it) {
                int idx = tid + it * 256;
                int row = idx / SL, sl = idx % SL;
                *(f32x4*)((float*)out0 + (size_t)(m0 + row) * NTOT + n0 + sl * 4)
                    = *(const f32x4*)&Sf[row * BN + sl * 4];
            }
        } else {
            constexpr int SL = BN / 8;
            unsigned short* dst = (unsigned short*)((p == 0) ? out0 : out1);
#pragma unroll
            for (int it = 0; it < (128 * SL) / 256; ++it) {
                int idx = tid + it * 256;
                int row = idx / SL, sl = idx % SL;
                *(short8*)&dst[(size_t)(m0 + row) * NTOT + n0 + sl * 8]
                    = *(const short8*)&Sb[row * BN + sl * 8];
            }
        }
    }
}

// ---------------------------------------------------------------------------
// NEW: BM=64 MFMA GEMM for small-N layers (G3: NT3/BN64, G6: NT1/BN32).
// Grid = M/64 (2x the BM=128 parallelism), small LDS (12-32 KB), fp32 out.
// ---------------------------------------------------------------------------
template <int NT, int BN, int ACT>
__global__ __launch_bounds__(256) void mfma_gemm64(
    const unsigned short* __restrict__ Ah_g, const unsigned short* __restrict__ Al_g,
    int K,
    const unsigned short* __restrict__ Wh, const unsigned short* __restrict__ Wl,
    const float* __restrict__ bias,
    float* __restrict__ out, int NTOT)
{
    constexpr int WM = (BN == 64) ? 2 : 1;
    constexpr int WN = 2;
    constexpr int ABUF = (NT == 3) ? 4096 : 2048;          // shorts
    constexpr int BBUF = BN * 32 * ((NT == 3) ? 2 : 1);
    constexpr int BUFSH = ABUF + BBUF;
    __shared__ unsigned short smem[2 * BUFSH];

    const int tid = threadIdx.x;
    const int m0 = blockIdx.x * 64;
    const int w = tid >> 6, lane = tid & 63;
    const int g = lane >> 4, lr = lane & 15;
    const int wrow0 = (BN == 64) ? ((w >> 1) * 32) : (w * 16);
    const int wcol0 = (BN == 64) ? ((w & 1) * 32) : 0;
    const int KS = K >> 5;

    auto stage = [&](unsigned short* buf, int ks) {
        unsigned short* Ah = buf;
        unsigned short* Al = buf + 2048;
        unsigned short* Bh = buf + ABUF;
        unsigned short* Bl = Bh + BN * 32;
        // A: 256 tasks t = kb*64 + row
        {
            int t0 = w * 64;
            int t = t0 + lane;
            int row = t & 63, kb = t >> 6;
            size_t go = (size_t)(m0 + row) * K + ks * 32 + kb * 8;
            gload16(Ah_g + go, Ah + (size_t)t0 * 8);
            if constexpr (NT == 3) gload16(Al_g + go, Al + (size_t)t0 * 8);
        }
        // B: linear copy of pre-transformed block (nb = 0)
        size_t bo = (size_t)ks * (BN * 32);
        constexpr int BT = BN * 4;        // 16B tasks
        if constexpr (BT == 256) {
            int t0 = w * 64;
            size_t go = bo + (size_t)(t0 + lane) * 8;
            gload16(Wh + go, Bh + (size_t)t0 * 8);
            if constexpr (NT == 3) gload16(Wl + go, Bl + (size_t)t0 * 8);
        } else {   // BT == 128
            if (tid < BT) {
                int t0 = w * 64;
                size_t go = bo + (size_t)(t0 + lane) * 8;
                gload16(Wh + go, Bh + (size_t)t0 * 8);
                if constexpr (NT == 3) gload16(Wl + go, Bl + (size_t)t0 * 8);
            }
        }
    };

    f32x4 acc[WM][WN];
#pragma unroll
    for (int m = 0; m < WM; ++m)
#pragma unroll
        for (int n = 0; n < WN; ++n) {
            acc[m][n][0] = 0.f; acc[m][n][1] = 0.f;
            acc[m][n][2] = 0.f; acc[m][n][3] = 0.f;
        }

    stage(smem, 0);

    for (int ks = 0; ks < KS; ++ks) {
        __syncthreads();
        unsigned short* buf = smem + (size_t)(ks & 1) * BUFSH;
        if (ks + 1 < KS)
            stage(smem + (size_t)((ks + 1) & 1) * BUFSH, ks + 1);

        unsigned short* Ah = buf;
        unsigned short* Al = buf + 2048;
        unsigned short* Bh = buf + ABUF;
        unsigned short* Bl = Bh + BN * 32;

        short8 ah[WM], bh[WN];
        short8 al[WM], bl[WN];
#pragma unroll
        for (int m = 0; m < WM; ++m) {
            int ro = (g << 6) + wrow0 + m * 16 + lr;
            ah[m] = *(const short8*)&Ah[ro * 8];
            if constexpr (NT == 3) al[m] = *(const short8*)&Al[ro * 8];
        }
#pragma unroll
        for (int n = 0; n < WN; ++n) {
            int co = g * BN + wcol0 + n * 16 + lr;
            bh[n] = *(const short8*)&Bh[co * 8];
            if constexpr (NT == 3) bl[n] = *(const short8*)&Bl[co * 8];
        }
#pragma unroll
        for (int m = 0; m < WM; ++m)
#pragma unroll
            for (int n = 0; n < WN; ++n) {
                acc[m][n] = __builtin_amdgcn_mfma_f32_16x16x32_bf16(
                    ah[m], bh[n], acc[m][n], 0, 0, 0);
                if constexpr (NT == 3) {
                    acc[m][n] = __builtin_amdgcn_mfma_f32_16x16x32_bf16(
                        ah[m], bl[n], acc[m][n], 0, 0, 0);
                    acc[m][n] = __builtin_amdgcn_mfma_f32_16x16x32_bf16(
                        al[m], bh[n], acc[m][n], 0, 0, 0);
                }
            }
    }

    // epilogue: fp32 out via LDS transpose
    float bv[WN];
#pragma unroll
    for (int n = 0; n < WN; ++n) bv[n] = bias[wcol0 + n * 16 + lr];

    float* Sf = (float*)smem;
    __syncthreads();
#pragma unroll
    for (int m = 0; m < WM; ++m)
#pragma unroll
        for (int n = 0; n < WN; ++n)
#pragma unroll
            for (int q = 0; q < 4; ++q) {
                int rl = wrow0 + m * 16 + g * 4 + q;
                int cl = wcol0 + n * 16 + lr;
                float x = acc[m][n][q] + bv[n];
                if (ACT == 0) x = fmaxf(x, 0.f);
                else x = tanhf(x);
                Sf[rl * BN + cl] = x;
            }
    __syncthreads();
    constexpr int SL = BN / 4;
#pragma unroll
    for (int it = 0; it < (64 * SL) / 256; ++it) {
        int idx = tid + it * 256;
        int row = idx / SL, sl = idx % SL;
        *(f32x4*)(out + (size_t)(m0 + row) * NTOT + sl * 4)
            = *(const f32x4*)&Sf[row * BN + sl * 4];
    }
}

// ---------------------------------------------------------------------------
// fp32 fixup GEMM, 32-row tiles (proven round 9).
// ---------------------------------------------------------------------------
template <int BN, int ACT>
__global__ __launch_bounds__(256) void gemm_fix(
    const int* __restrict__ mrows,
    const float* __restrict__ A, int K,
    const float* __restrict__ W, const float* __restrict__ bias,
    float* __restrict__ Co, int N)
{
    const int m0 = blockIdx.x * 32;
    if (m0 >= *mrows) return;

    constexpr int TN = BN / 16;
    __shared__ float At[16][36];
    __shared__ float Bt[16][BN + 4];

    const int tid = threadIdx.x;
    const int n0 = blockIdx.y * BN;
    const int r = tid >> 4;
    const int c = tid & 15;

    float acc[2][TN];
#pragma unroll
    for (int i = 0; i < 2; ++i)
#pragma unroll
        for (int j = 0; j < TN; ++j) acc[i][j] = 0.f;

    for (int k0 = 0; k0 < K; k0 += 16) {
        if (tid < 128) {
            int row = tid >> 2;
            int lf = tid & 3;
            float4 v = *(const float4*)(A + (size_t)(m0 + row) * K + k0 + lf * 4);
            At[lf * 4 + 0][row] = v.x;
            At[lf * 4 + 1][row] = v.y;
            At[lf * 4 + 2][row] = v.z;
            At[lf * 4 + 3][row] = v.w;
        }
        constexpr int NF4 = BN / 4;
        constexpr int NEL = 16 * NF4;
#pragma unroll
        for (int it = 0; it < NEL / 256; ++it) {
            int idx = tid + it * 256;
            int kk = idx / NF4;
            int f = idx % NF4;
            float4 v = *(const float4*)(W + (size_t)(k0 + kk) * N + n0 + f * 4);
            *(float4*)&Bt[kk][f * 4] = v;
        }
        __syncthreads();

#pragma unroll
        for (int kk = 0; kk < 16; ++kk) {
            float a0 = At[kk][r * 2];
            float a1 = At[kk][r * 2 + 1];
            float b[TN];
            if constexpr (BN == 128) {
                float4 b0 = *(const float4*)&Bt[kk][c * 4];
                float4 b1 = *(const float4*)&Bt[kk][64 + c * 4];
                b[0] = b0.x; b[1] = b0.y; b[2] = b0.z; b[3] = b0.w;
                b[4] = b1.x; b[5] = b1.y; b[6] = b1.z; b[7] = b1.w;
            } else {
                float4 b0 = *(const float4*)&Bt[kk][c * 4];
                b[0] = b0.x; b[1] = b0.y; b[2] = b0.z; b[3] = b0.w;
            }
#pragma unroll
            for (int j = 0; j < TN; ++j) {
                acc[0][j] = fmaf(a0, b[j], acc[0][j]);
                acc[1][j] = fmaf(a1, b[j], acc[1][j]);
            }
        }
        __syncthreads();
    }

#pragma unroll
    for (int i = 0; i < 2; ++i) {
        size_t row = (size_t)(m0 + r * 2 + i);
        if constexpr (BN == 128) {
            float e[8];
#pragma unroll
            for (int j = 0; j < 8; ++j) {
                int col = (j < 4) ? (c * 4 + j) : (64 + c * 4 + (j - 4));
                float v = acc[i][j] + bias[n0 + col];
                if (ACT == 0) v = fmaxf(v, 0.f);
                e[j] = v;
            }
            float4 v0, v1;
            v0.x = e[0]; v0.y = e[1]; v0.z = e[2]; v0.w = e[3];
            v1.x = e[4]; v1.y = e[5]; v1.z = e[6]; v1.w = e[7];
            *(float4*)&Co[row * N + n0 + c * 4] = v0;
            *(float4*)&Co[row * N + n0 + 64 + c * 4] = v1;
        } else {
            float e[4];
#pragma unroll
            for (int j = 0; j < 4; ++j) {
                float v = acc[i][j] + bias[n0 + c * 4 + j];
                if (ACT == 0) v = fmaxf(v, 0.f);
                e[j] = v;
            }
            float4 v0;
            v0.x = e[0]; v0.y = e[1]; v0.z = e[2]; v0.w = e[3];
            *(float4*)&Co[row * N + n0 + c * 4] = v0;
        }
    }
}

// ---------------------------------------------------------------------------
__global__ void sa_pre(const float* __restrict__ state, const float* __restrict__ action,
                       unsigned short* __restrict__ saH, unsigned short* __restrict__ saL)
{
    int idx = blockIdx.x * 256 + threadIdx.x;
    int row = idx / 12, q = idx % 12;
    const float* src = (q < 8) ? (state + (size_t)row * 64 + q * 8)
                               : (action + (size_t)row * 32 + (q - 8) * 8);
    f32x4 v0 = *(const f32x4*)src;
    f32x4 v1 = *(const f32x4*)(src + 4);
    short8 h, l;
#pragma unroll
    for (int j = 0; j < 8; ++j) {
        float x = (j < 4) ? v0[j] : v1[j - 4];
        unsigned short hb_ = f2bf(x);
        h[j] = (short)hb_;
        l[j] = (short)f2bf(x - bf2f(hb_));
    }
    *(short8*)&saH[(size_t)row * 96 + q * 8] = h;
    *(short8*)&saL[(size_t)row * 96 + q * 8] = l;
}

// ---------------------------------------------------------------------------
// VQ score kernel: 64 rows x 512 codes per block, grid (M/64, 2).
// ---------------------------------------------------------------------------
__global__ __launch_bounds__(256) void vq_score(
    const float* __restrict__ midz,
    const float* __restrict__ codebook,
    const float* __restrict__ cbn,
    float4* __restrict__ part)
{
    __shared__ float Zt[64 * 68];
    __shared__ float Ct[64 * 68];
    __shared__ float cn[64];

    const int tid = threadIdx.x;
    const int m0 = blockIdx.x * 64;
    const int eh = blockIdx.y;
    const int r = tid >> 4;
    const int c = tid & 15;

#pragma unroll
    for (int it = 0; it < 4; ++it) {
        int idx = tid + it * 256;
        int row = idx >> 4, f = idx & 15;
        float4 v = *(const float4*)(midz + (size_t)(m0 + row) * 64 + f * 4);
        Zt[(f * 4 + 0) * 68 + row] = v.x;
        Zt[(f * 4 + 1) * 68 + row] = v.y;
        Zt[(f * 4 + 2) * 68 + row] = v.z;
        Zt[(f * 4 + 3) * 68 + row] = v.w;
    }

    float best[4], sec[4];
    int bidx[4];
#pragma unroll
    for (int i = 0; i < 4; ++i) { best[i] = 3.4e38f; sec[i] = 3.4e38f; bidx[i] = 0x7fffffff; }

    for (int ch = 0; ch < 8; ++ch) {
        int e0 = eh * 512 + ch * 64;
        __syncthreads();
#pragma unroll
        for (int it = 0; it < 4; ++it) {
            int idx = tid + it * 256;
            int e = idx >> 4, f = idx & 15;
            float4 v = *(const float4*)(codebook + (size_t)(e0 + e) * 64 + f * 4);
            Ct[(f * 4 + 0) * 68 + e] = v.x;
            Ct[(f * 4 + 1) * 68 + e] = v.y;
            Ct[(f * 4 + 2) * 68 + e] = v.z;
            Ct[(f * 4 + 3) * 68 + e] = v.w;
        }
        if (tid < 64) cn[tid] = cbn[e0 + tid];
        __syncthreads();

        float acc[4][4];
#pragma unroll
        for (int i = 0; i < 4; ++i)
#pragma unroll
            for (int j = 0; j < 4; ++j) acc[i][j] = 0.f;

#pragma unroll 8
        for (int kk = 0; kk < 64; ++kk) {
            float4 a = *(const float4*)&Zt[kk * 68 + r * 4];
            float4 b = *(const float4*)&Ct[kk * 68 + c * 4];
            acc[0][0] = fmaf(a.x, b.x, acc[0][0]);
            acc[0][1] = fmaf(a.x, b.y, acc[0][1]);
            acc[0][2] = fmaf(a.x, b.z, acc[0][2]);
            acc[0][3] = fmaf(a.x, b.w, acc[0][3]);
            acc[1][0] = fmaf(a.y, b.x, acc[1][0]);
            acc[1][1] = fmaf(a.y, b.y, acc[1][1]);
            acc[1][2] = fmaf(a.y, b.z, acc[1][2]);
            acc[1][3] = fmaf(a.y, b.w, acc[1][3]);
            acc[2][0] = fmaf(a.z, b.x, acc[2][0]);
            acc[2][1] = fmaf(a.z, b.y, acc[2][1]);
            acc[2][2] = fmaf(a.z, b.z, acc[2][2]);
            acc[2][3] = fmaf(a.z, b.w, acc[2][3]);
            acc[3][0] = fmaf(a.w, b.x, acc[3][0]);
            acc[3][1] = fmaf(a.w, b.y, acc[3][1]);
            acc[3][2] = fmaf(a.w, b.z, acc[3][2]);
            acc[3][3] = fmaf(a.w, b.w, acc[3][3]);
        }
#pragma unroll
        for (int i = 0; i < 4; ++i)
#pragma unroll
            for (int j = 0; j < 4; ++j) {
                int e = c * 4 + j;
                float s = cn[e] - 2.0f * acc[i][j];
                int gi = e0 + e;
                if (s < best[i] || (s == best[i] && gi < bidx[i])) {
                    sec[i] = best[i];
                    best[i] = s;
                    bidx[i] = gi;
                } else {
                    sec[i] = fminf(sec[i], s);
                }
            }
    }

#pragma unroll
    for (int i = 0; i < 4; ++i) {
#pragma unroll
        for (int m = 1; m < 16; m <<= 1) {
            float ob = __shfl_xor(best[i], m, 64);
            int oi = __shfl_xor(bidx[i], m, 64);
            float os = __shfl_xor(sec[i], m, 64);
            if (ob < best[i] || (ob == best[i] && oi < bidx[i])) {
                sec[i] = fminf(best[i], os);
                best[i] = ob;
                bidx[i] = oi;
            } else {
                sec[i] = fminf(sec[i], ob);
            }
        }
    }
    if (c == 0) {
#pragma unroll
        for (int i = 0; i < 4; ++i) {
            float4 p;
            p.x = best[i];
            p.y = sec[i];
            p.z = __int_as_float(bidx[i]);
            p.w = 0.f;
            part[(size_t)(m0 + r * 4 + i) * 2 + eh] = p;
        }
    }
}

// ---------------------------------------------------------------------------
// VQ merge + flag + latent head + state half of xz.  128 rows/block, grid mt.
// ---------------------------------------------------------------------------
__global__ __launch_bounds__(256) void vq_merge(
    const float4* __restrict__ part,
    const float* __restrict__ state_c,
    const float* __restrict__ codebook,
    const float* __restrict__ mean_w, const float* __restrict__ mean_b,
    const float* __restrict__ logstd_w, const float* __restrict__ logstd_b,
    const float* __restrict__ eps,
    float* __restrict__ mean_out, float* __restrict__ std_out,
    unsigned short* __restrict__ xz,
    int* __restrict__ ctr, int* __restrict__ list, int rowbase)
{
    __shared__ float mw[4160];
    __shared__ float lw[4160];
    __shared__ int sidx[128];

    const int tid = threadIdx.x;
    const int m0 = blockIdx.x * 128;

    if (tid < 128) {
        size_t row = (size_t)(m0 + tid);
        float4 p0 = part[row * 2 + 0];
        float4 p1 = part[row * 2 + 1];
        int i0 = __float_as_int(p0.z), i1 = __float_as_int(p1.z);
        float b, s;
        int ix;
        if (p0.x < p1.x || (p0.x == p1.x && i0 < i1)) {
            b = p0.x; ix = i0; s = fminf(p0.y, p1.x);
        } else {
            b = p1.x; ix = i1; s = fminf(p1.y, p0.x);
        }
        sidx[tid] = ix;
        if (s - b < TAU) {
            int p = atomicAdd(ctr, 1);
            list[p] = rowbase + m0 + tid;
        }
    }
#pragma unroll
    for (int it = 0; it < 4; ++it) {
        int idx = tid + it * 256;
        int k = idx >> 4, f = idx & 15;
        float4 v = *(const float4*)(mean_w + (size_t)k * 64 + f * 4);
        mw[k * 65 + f * 4 + 0] = v.x;
        mw[k * 65 + f * 4 + 1] = v.y;
        mw[k * 65 + f * 4 + 2] = v.z;
        mw[k * 65 + f * 4 + 3] = v.w;
        float4 w2 = *(const float4*)(logstd_w + (size_t)k * 64 + f * 4);
        lw[k * 65 + f * 4 + 0] = w2.x;
        lw[k * 65 + f * 4 + 1] = w2.y;
        lw[k * 65 + f * 4 + 2] = w2.z;
        lw[k * 65 + f * 4 + 3] = w2.w;
    }

    // state half -> xz cols 0..63 (independent of merge; no sync needed)
    {
        int row = tid >> 1;
        int d0 = (tid & 1) * 32;
        size_t so = (size_t)(m0 + row) * 64 + d0;
        size_t xo = (size_t)(m0 + row) * 128 + d0;
#pragma unroll
        for (int q = 0; q < 8; ++q) {
            f32x4 v = *(const f32x4*)&state_c[so + q * 4];
            unsigned short o[4];
            o[0] = f2bf(v[0]); o[1] = f2bf(v[1]);
            o[2] = f2bf(v[2]); o[3] = f2bf(v[3]);
            *(uint2*)&xz[xo + q * 4] = *(uint2*)o;
        }
    }
    __syncthreads();

    {
        int row = tid >> 1;
        int d0 = (tid & 1) * 32;
        int e = sidx[row];
        const float* cb = codebook + (size_t)e * 64;
        float mv[32], lv[32];
#pragma unroll
        for (int d = 0; d < 32; ++d) {
            mv[d] = mean_b[d0 + d];
            lv[d] = logstd_b[d0 + d];
        }
        for (int k = 0; k < 64; ++k) {
            float zk = cb[k];
#pragma unroll
            for (int d = 0; d < 32; ++d) {
                mv[d] = fmaf(zk, mw[k * 65 + d0 + d], mv[d]);
                lv[d] = fmaf(zk, lw[k * 65 + d0 + d], lv[d]);
            }
        }
        size_t ro = (size_t)(m0 + row) * 64 + d0;
        size_t xo = (size_t)(m0 + row) * 128 + 64 + d0;
#pragma unroll
        for (int d = 0; d < 32; ++d) {
            float mean = mv[d];
            float ls = fminf(fmaxf(lv[d], -4.f), 15.f);
            float sd = expf(ls);
            float z = fmaf(sd, eps[ro + d], mean);
            mean_out[ro + d] = mean;
            std_out[ro + d] = sd;
            xz[xo + d] = f2bf(z);
        }
    }
}

// ---------------------------------------------------------------------------
__global__ void gather_fix(const int* __restrict__ ctr, int* __restrict__ meta,
                           const int* __restrict__ list,
                           const float* __restrict__ state,
                           const float* __restrict__ action,
                           float* __restrict__ sa_fix)
{
    int cnt = *ctr; if (cnt > FMAX) cnt = FMAX;
    if (blockIdx.x == 0 && threadIdx.x == 0)
        meta[0] = (cnt + 31) & ~31;
    int t = blockIdx.x * 256 + threadIdx.x;
    if (t >= cnt * 24) return;
    int f = t / 24, q = t % 24;
    size_t g = (size_t)list[f];
    f32x4 v = (q < 16) ? *(const f32x4*)&state[g * 64 + q * 4]
                       : *(const f32x4*)&action[g * 32 + (q - 16) * 4];
    *(f32x4*)&sa_fix[(size_t)f * 96 + q * 4] = v;
}

// ---------------------------------------------------------------------------
__global__ __launch_bounds__(256) void vq_fix(
    const int* __restrict__ ctr, const int* __restrict__ list,
    const float* __restrict__ mz_fix,
    const float* __restrict__ codebook, const float* __restrict__ cbn,
    const float* __restrict__ mean_w, const float* __restrict__ mean_b,
    const float* __restrict__ logstd_w, const float* __restrict__ logstd_b,
    const float* __restrict__ eps,
    float* __restrict__ mean_out, float* __restrict__ std_out,
    unsigned short* __restrict__ xz)
{
    __shared__ float mzs[8][64];
    __shared__ float zns[8];
    __shared__ float sv[2048];
    __shared__ int si[2048];
    __shared__ int am_s[8];

    int cnt = *ctr; if (cnt > FMAX) cnt = FMAX;
    const int base = blockIdx.x * 8;
    if (base >= cnt) return;
    const int nr = min(8, cnt - base);
    const int tid = threadIdx.x;

    if (tid < 128) {
        int rr = tid >> 4, q = tid & 15;
        int src = base + ((rr < nr) ? rr : 0);
        *(f32x4*)&mzs[rr][q * 4] = *(const f32x4*)&mz_fix[(size_t)src * 64 + q * 4];
    }
    __syncthreads();
    if (tid < 8) {
        float s = 0.f;
#pragma unroll
        for (int k = 0; k < 64; ++k) s = fmaf(mzs[tid][k], mzs[tid][k], s);
        zns[tid] = s;
    }
    __syncthreads();

    float bb[8];
    int bi[8];
#pragma unroll
    for (int rr = 0; rr < 8; ++rr) { bb[rr] = 3.4e38f; bi[rr] = 0x7fffffff; }
    for (int j = 0; j < 4; ++j) {
        int code = tid + j * 256;
        const f32x4* cp = (const f32x4*)(codebook + (size_t)code * 64);
        float dot[8];
#pragma unroll
        for (int rr = 0; rr < 8; ++rr) dot[rr] = 0.f;
        for (int t = 0; t < 16; ++t) {
            f32x4 cv = cp[t];
#pragma unroll
            for (int e = 0; e < 4; ++e) {
                float cvv = cv[e];
#pragma unroll
                for (int rr = 0; rr < 8; ++rr)
                    dot[rr] = fmaf(mzs[rr][t * 4 + e], cvv, dot[rr]);
            }
        }
        float cnv = cbn[code];
#pragma unroll
        for (int rr = 0; rr < 8; ++rr) {
            float s = (zns[rr] + cnv) - 2.0f * dot[rr];
            if (s < bb[rr] || (s == bb[rr] && code < bi[rr])) {
                bb[rr] = s; bi[rr] = code;
            }
        }
    }
#pragma unroll
    for (int rr = 0; rr < 8; ++rr) {
        sv[rr * 256 + tid] = bb[rr];
        si[rr * 256 + tid] = bi[rr];
    }
    __syncthreads();
    if (tid < 8) {
        float b = 3.4e38f;
        int ix = 0x7fffffff;
        for (int t = 0; t < 256; ++t) {
            float v = sv[tid * 256 + t];
            int iv = si[tid * 256 + t];
            if (v < b || (v == b && iv < ix)) { b = v; ix = iv; }
        }
        am_s[tid] = ix;
    }
    __syncthreads();

    for (int jo = 0; jo < 2; ++jo) {
        int o = tid + jo * 256;
        int rr = o >> 6, d = o & 63;
        if (rr < nr) {
            int e = am_s[rr];
            size_t g = (size_t)list[base + rr];
            float mv = mean_b[d], lv = logstd_b[d];
            const float* cb = codebook + (size_t)e * 64;
            for (int k = 0; k < 64; ++k) {
                float zk = cb[k];
                mv = fmaf(zk, mean_w[(size_t)k * 64 + d], mv);
                lv = fmaf(zk, logstd_w[(size_t)k * 64 + d], lv);
            }
            float ls = fminf(fmaxf(lv, -4.f), 15.f);
            float sd = expf(ls);
            float z = fmaf(sd, eps[g * 64 + d], mv);
            mean_out[g * 64 + d] = mv;
            std_out[g * 64 + d] = sd;
            xz[g * 128 + 64 + d] = f2bf(z);
        }
    }
}

// ---------------------------------------------------------------------------
extern "C" void kernel_launch(void* const* d_in, const int* in_sizes, int n_in,
                              void* d_out, int out_size, void* d_ws, size_t ws_size,
                              hipStream_t stream)
{
    const float* state    = (const float*)d_in[0];
    const float* action   = (const float*)d_in[1];
    const float* eps      = (const float*)d_in[2];
    const float* enc_w1   = (const float*)d_in[3];
    const float* enc_b1   = (const float*)d_in[4];
    const float* enc_w2   = (const float*)d_in[5];
    const float* enc_b2   = (const float*)d_in[6];
    const float* enc_w3   = (const float*)d_in[7];
    const float* enc_b3   = (const float*)d_in[8];
    const float* mean_w   = (const float*)d_in[9];
    const float* mean_b   = (const float*)d_in[10];
    const float* logstd_w = (const float*)d_in[11];
    const float* logstd_b = (const float*)d_in[12];
    const float* codebook = (const float*)d_in[13];
    const float* dec_w1   = (const float*)d_in[14];
    const float* dec_b1   = (const float*)d_in[15];
    const float* dec_w2   = (const float*)d_in[16];
    const float* dec_b2   = (const float*)d_in[17];
    const float* dec_w3   = (const float*)d_in[18];
    const float* dec_b3   = (const float*)d_in[19];

    float* out = (float*)d_out;
    float* u_out = out;
    float* mean_out = out + (size_t)B_TOTAL * 32;
    float* std_out = mean_out + (size_t)B_TOTAL * 64;

    // ---- fixed ws region (~9.6 MB; fix buffers alias the dyn area) ----
    char* base = (char*)d_ws;
    float* cbn = (float*)base;                                   // 4096
    unsigned short* W1h = (unsigned short*)(base + 4096);        // 196608
    unsigned short* W1l = (unsigned short*)(base + 200704);      // 196608
    unsigned short* W2h = (unsigned short*)(base + 397312);      // 2097152
    unsigned short* W2l = (unsigned short*)(base + 2494464);     // 2097152
    unsigned short* W3h = (unsigned short*)(base + 4591616);     // 131072
    unsigned short* W3l = (unsigned short*)(base + 4722688);     // 131072
    unsigned short* W4h = (unsigned short*)(base + 4853760);     // 262144
    unsigned short* W5h = (unsigned short*)(base + 5115904);     // 2097152
    unsigned short* W6h = (unsigned short*)(base + 7213056);     // 65536
    int* ctr            = (int*)(base + 7278592);                // 256
    int* flag_list      = (int*)(base + 7278848);                // 262144
    int* meta           = (int*)(base + 7540992);                // 256
    float4* part        = (float4*)(base + 7541248);             // 2097152
    const size_t FIXED  = 9638400;

    unsigned short* xz_g = (unsigned short*)(base + FIXED);      // 16 MB
    const size_t XZ_SZ = (size_t)B_TOTAL * 128 * 2;

    // dyn region: per-chunk staging; per_row = 384 + 8192 + 256 = 8832 B
    const size_t per_row = 8832;
    size_t avail = (ws_size > FIXED + XZ_SZ) ? (ws_size - FIXED - XZ_SZ) : 0;
    long maxC = (long)(avail / per_row);
    int C = (int)(maxC / 1024) * 1024;
    if (C > B_TOTAL) C = B_TOTAL;
    if (C < 6144) C = 6144;   // >= fix-alias region (54.26 MB = 6144*8832)

    char* dyn = base + FIXED + XZ_SZ;
    unsigned short* saH = (unsigned short*)dyn;                   // [C,96]
    unsigned short* saL = saH + (size_t)C * 96;
    unsigned short* h1H = saL + (size_t)C * 96;                   // [C,1024]
    unsigned short* h1L = h1H + (size_t)C * 1024;
    unsigned short* h2H = h1L + (size_t)C * 1024;
    unsigned short* h2L = h2H + (size_t)C * 1024;
    float* mz = (float*)(h2L + (size_t)C * 1024);                 // [C,64]
    unsigned short* hc = h1H;   // decoder reuse
    unsigned short* hd = h2H;

    // fixup buffers alias dyn (phase B runs after all of phase A)
    float* sa_fix = (float*)dyn;                                  // 2359296
    float* h1_fix = (float*)(dyn + 2359296);                      // 25165824
    float* h2_fix = (float*)(dyn + 27525120);                     // 25165824
    float* mz_fix = (float*)(dyn + 52690944);                     // 1572864

    // dynamic-LDS attrs for the pipelined kernels (fallback to old if denied)
    bool deep = hipFuncSetAttribute(
        reinterpret_cast<const void*>(&mfma_gemm128<3, 0, 0>),
        hipFuncAttributeMaxDynamicSharedMemorySize, 81920) == hipSuccess;
    deep = deep && hipFuncSetAttribute(
        reinterpret_cast<const void*>(&mfma_gemm128<1, 1, 0>),
        hipFuncAttributeMaxDynamicSharedMemorySize, 40960) == hipSuccess;

    // ---- once per call ----
    cb_norms<<<dim3(4), dim3(256), 0, stream>>>(codebook, cbn);
    zero_ctr<<<dim3(1), dim3(64), 0, stream>>>(ctr);
    w_xform<3, 128><<<dim3(3, 8), dim3(256), 0, stream>>>(enc_w1, 96, 1024, W1h, W1l);
    w_xform<3, 128><<<dim3(32, 8), dim3(256), 0, stream>>>(enc_w2, 1024, 1024, W2h, W2l);
    w_xform<3, 64><<<dim3(32, 1), dim3(256), 0, stream>>>(enc_w3, 1024, 64, W3h, W3l);
    w_xform<1, 128><<<dim3(4, 8), dim3(256), 0, stream>>>(dec_w1, 128, 1024, W4h, nullptr);
    w_xform<1, 128><<<dim3(32, 8), dim3(256), 0, stream>>>(dec_w2, 1024, 1024, W5h, nullptr);
    w_xform<1, 32><<<dim3(32, 1), dim3(256), 0, stream>>>(dec_w3, 1024, 32, W6h, nullptr);

    // ---- phase A: encoder + VQ for all chunks ----
    for (int r0 = 0; r0 < B_TOTAL; r0 += C) {
        int M = (r0 + C <= B_TOTAL) ? C : (B_TOTAL - r0);
        int mt = M / 128;

        sa_pre<<<dim3(M * 12 / 256), dim3(256), 0, stream>>>(
            state + (size_t)r0 * SDIM, action + (size_t)r0 * ADIM, saH, saL);

        if (deep) {
            mfma_gemm128<3, 0, 0><<<dim3(mt * 8), dim3(256), 81920, stream>>>(
                saH, saL, 96, W1h, W1l, enc_b1, h1H, h1L, 1024);
            mfma_gemm128<3, 0, 0><<<dim3(mt * 8), dim3(256), 81920, stream>>>(
                h1H, h1L, 1024, W2h, W2l, enc_b2, h2H, h2L, 1024);
        } else {
            mfma_gemm<3, 128, 0, 0><<<dim3(mt * 8), dim3(256), 0, stream>>>(
                saH, saL, 96, W1h, W1l, enc_b1, h1H, h1L, 1024);
            mfma_gemm<3, 128, 0, 0><<<dim3(mt * 8), dim3(256), 0, stream>>>(
                h1H, h1L, 1024, W2h, W2l, enc_b2, h2H, h2L, 1024);
        }
        mfma_gemm64<3, 64, 0><<<dim3(M / 64), dim3(256), 0, stream>>>(
            h2H, h2L, 1024, W3h, W3l, enc_b3, mz, 64);

        vq_score<<<dim3(M / 64, 2), dim3(256), 0, stream>>>(
            mz, codebook, cbn, part + (size_t)r0 * 2);
        vq_merge<<<dim3(mt), dim3(256), 0, stream>>>(
            part + (size_t)r0 * 2, state + (size_t)r0 * SDIM, codebook,
            mean_w, mean_b, logstd_w, logstd_b,
            eps + (size_t)r0 * LDIM,
            mean_out + (size_t)r0 * LDIM, std_out + (size_t)r0 * LDIM,
            xz_g + (size_t)r0 * 128, ctr, flag_list, r0);
    }

    // ---- phase B: exact-fp32 fixup as 32-row-tile GEMMs on gathered rows ----
    gather_fix<<<dim3(FMAX * 24 / 256), dim3(256), 0, stream>>>(
        ctr, meta, flag_list, state, action, sa_fix);
    gemm_fix<128, 0><<<dim3(FMAX / 32, 8), dim3(256), 0, stream>>>(
        meta, sa_fix, 96, enc_w1, enc_b1, h1_fix, 1024);
    gemm_fix<128, 0><<<dim3(FMAX / 32, 8), dim3(256), 0, stream>>>(
        meta, h1_fix, 1024, enc_w2, enc_b2, h2_fix, 1024);
    gemm_fix<64, 0><<<dim3(FMAX / 32, 1), dim3(256), 0, stream>>>(
        meta, h2_fix, 1024, enc_w3, enc_b3, mz_fix, 64);
    vq_fix<<<dim3(FMAX / 8), dim3(256), 0, stream>>>(
        ctr, flag_list, mz_fix, codebook, cbn,
        mean_w, mean_b, logstd_w, logstd_b, eps,
        mean_out, std_out, xz_g);

    // ---- phase C: decoder for all chunks ----
    for (int r0 = 0; r0 < B_TOTAL; r0 += C) {
        int M = (r0 + C <= B_TOTAL) ? C : (B_TOTAL - r0);
        int mt = M / 128;

        if (deep) {
            mfma_gemm128<1, 1, 0><<<dim3(mt * 8), dim3(256), 40960, stream>>>(
                xz_g + (size_t)r0 * 128, nullptr, 128, W4h, nullptr, dec_b1,
                hc, nullptr, 1024);
            mfma_gemm128<1, 1, 0><<<dim3(mt * 8), dim3(256), 40960, stream>>>(
                hc, nullptr, 1024, W5h, nullptr, dec_b2, hd, nullptr, 1024);
        } else {
            mfma_gemm<1, 128, 1, 0><<<dim3(mt * 8), dim3(256), 0, stream>>>(
                xz_g + (size_t)r0 * 128, nullptr, 128, W4h, nullptr, dec_b1,
                hc, nullptr, 1024);
            mfma_gemm<1, 128, 1, 0><<<dim3(mt * 8), dim3(256), 0, stream>>>(
                hc, nullptr, 1024, W5h, nullptr, dec_b2, hd, nullptr, 1024);
        }
        mfma_gemm64<1, 32, 1><<<dim3(M / 64), dim3(256), 0, stream>>>(
            hd, nullptr, 1024, W6h, nullptr, dec_b3,
            u_out + (size_t)r0 * ADIM, 32);
    }
}

// Round 13
// 1508.257 us; speedup vs baseline: 2.0155x; 1.0584x over previous
//
#include <hip/hip_runtime.h>
#include <cstdint>
#include <cstddef>

#define B_TOTAL 65536
#define SDIM 64
#define ADIM 32
#define LDIM 64
#define HDIM 1024
#define NEMB 1024
#define TAU 0.125f
#define FMAX 6144

typedef __attribute__((ext_vector_type(8))) short short8;
typedef __attribute__((ext_vector_type(8))) _Float16 half8;
typedef __attribute__((ext_vector_type(4))) float f32x4;

__device__ inline unsigned short f2bf(float f) {
    unsigned int u = __float_as_uint(f);
    u += 0x7fffu + ((u >> 16) & 1u);
    return (unsigned short)(u >> 16);
}
__device__ inline float bf2f(unsigned short s) {
    return __uint_as_float(((unsigned int)s) << 16);
}
__device__ inline unsigned short f2h(float f) {
    _Float16 h = (_Float16)f;
    return __builtin_bit_cast(unsigned short, h);
}
__device__ inline float h2f(unsigned short s) {
    return (float)__builtin_bit_cast(_Float16, s);
}
__device__ inline half8 H8(short8 v) { return __builtin_bit_cast(half8, v); }

// async global->LDS, 16B per lane; LDS dest = wave-uniform base + lane*16.
__device__ inline void gload16(const unsigned short* g, unsigned short* l) {
    __builtin_amdgcn_global_load_lds(
        (__attribute__((address_space(1))) void*)(g),
        (__attribute__((address_space(3))) void*)(l), 16, 0, 0);
}

// ---------------------------------------------------------------------------
__global__ void cb_norms(const float* __restrict__ codebook, float* __restrict__ cbn)
{
    int i = blockIdx.x * 256 + threadIdx.x;
    if (i < NEMB) {
        float s = 0.f;
#pragma unroll
        for (int k = 0; k < LDIM; ++k) {
            float v = codebook[(size_t)i * LDIM + k];
            s = fmaf(v, v, s);
        }
        cbn[i] = s;
    }
}

__global__ void zero_ctr(int* ctr) { if (threadIdx.x == 0) *ctr = 0; }

// ---------------------------------------------------------------------------
// Weight pre-transform: W[K][N] fp32 -> MFMA-B-ready plane(s).
// NT==1: bf16 single. NT==2: fp16 single. NT==3: bf16 hi+lo.
// ---------------------------------------------------------------------------
template <int NT, int BN>
__global__ __launch_bounds__(256) void w_xform(
    const float* __restrict__ W, int K, int N,
    unsigned short* __restrict__ Ph, unsigned short* __restrict__ Pl)
{
    __shared__ float Ws[32][BN + 4];
    const int tid = threadIdx.x;
    const int ks = blockIdx.x, nb = blockIdx.y;
    const int k0 = ks * 32, n0 = nb * BN;
    constexpr int LT = 32 * (BN / 4);
#pragma unroll
    for (int it = 0; it < (LT + 255) / 256; ++it) {
        int idx = tid + it * 256;
        if (LT % 256 == 0 || idx < LT) {
            int k = idx / (BN / 4);
            int nf = idx % (BN / 4);
            *(f32x4*)&Ws[k][nf * 4] =
                *(const f32x4*)&W[(size_t)(k0 + k) * N + n0 + nf * 4];
        }
    }
    __syncthreads();
    const int KS = K >> 5;
    size_t bo = ((size_t)nb * KS + ks) * (BN * 32);
    constexpr int WT = BN * 4;
#pragma unroll
    for (int it = 0; it < (WT + 255) / 256; ++it) {
        int idx = tid + it * 256;
        if (WT % 256 == 0 || idx < WT) {
            int kb = idx / BN;
            int n = idx % BN;
            short8 h, l;
#pragma unroll
            for (int j = 0; j < 8; ++j) {
                float x = Ws[kb * 8 + j][n];
                if (NT == 2) {
                    h[j] = (short)f2h(x);
                } else {
                    unsigned short hb_ = f2bf(x);
                    h[j] = (short)hb_;
                    if (NT == 3) l[j] = (short)f2bf(x - bf2f(hb_));
                }
            }
            *(short8*)&Ph[bo + (size_t)idx * 8] = h;
            if (NT == 3) *(short8*)&Pl[bo + (size_t)idx * 8] = l;
        }
    }
}

// ---------------------------------------------------------------------------
// OLD proven BF16/FP16 MFMA GEMM, 2-buf full-drain (fallback only).
// NT: 1=bf16 1-term, 2=fp16 A-split 2-term, 3=bf16 3-term.
// OUT: 0=bf16 hi+lo, 1=bf16, 2=fp32, 3=fp16 hi+lo.
// ---------------------------------------------------------------------------
template <int NT, int BN, int OUT, int ACT>
__global__ __launch_bounds__(256, 2) void mfma_gemm(
    const unsigned short* __restrict__ Ah_g, const unsigned short* __restrict__ Al_g,
    int K,
    const unsigned short* __restrict__ Wh, const unsigned short* __restrict__ Wl,
    const float* __restrict__ bias,
    void* __restrict__ out0, void* __restrict__ out1, int NTOT)
{
    constexpr int NWC = (BN == 128) ? 2 : 1;
    constexpr int WM = (BN == 128) ? 4 : 2;
    constexpr int WN = (BN == 32) ? 2 : 4;
    constexpr int ABUF = (NT >= 2) ? 8192 : 4096;
    constexpr int BBUF = 4 * BN * 8 * ((NT == 3) ? 2 : 1);
    constexpr int BUFSH = ABUF + BBUF;

    __shared__ unsigned short smem[2 * BUFSH];

    const int tid = threadIdx.x;
    int row_t, nb;
    if constexpr (BN == 128) {
        int per = gridDim.x >> 3;
        int xcd = blockIdx.x & 7;
        int lid = blockIdx.x >> 3;
        int tile = xcd * per + lid;
        row_t = tile >> 3;
        nb = tile & 7;
    } else {
        row_t = blockIdx.x;
        nb = 0;
    }
    const int m0 = row_t * 128;
    const int n0 = nb * BN;
    const int w = tid >> 6, lane = tid & 63;
    const int g = lane >> 4, lr = lane & 15;
    const int wrow0 = (w / NWC) * (WM * 16);
    const int wcol0 = (w % NWC) * (WN * 16);
    const int KS = K >> 5;

    auto stage = [&](unsigned short* buf, int ks) {
        unsigned short* Ah = buf;
        unsigned short* Al = buf + 4096;
        unsigned short* Bh = buf + ABUF;
        unsigned short* Bl = Bh + 4 * BN * 8;
#pragma unroll
        for (int it = 0; it < 2; ++it) {
            int t0 = it * 256 + w * 64;
            int t = t0 + lane;
            int row = t & 127, kb = t >> 7;
            size_t go = (size_t)(m0 + row) * K + ks * 32 + kb * 8;
            gload16(Ah_g + go, Ah + (size_t)t0 * 8);
            if constexpr (NT >= 2) gload16(Al_g + go, Al + (size_t)t0 * 8);
        }
        size_t bo = ((size_t)nb * KS + ks) * (BN * 32);
        constexpr int BT = 4 * BN;
        if constexpr (BT >= 256) {
#pragma unroll
            for (int it = 0; it < BT / 256; ++it) {
                int t0 = it * 256 + w * 64;
                size_t go = bo + (size_t)(t0 + lane) * 8;
                gload16(Wh + go, Bh + (size_t)t0 * 8);
                if constexpr (NT == 3) gload16(Wl + go, Bl + (size_t)t0 * 8);
            }
        } else {
            if (tid < BT) {
                int t0 = w * 64;
                size_t go = bo + (size_t)(t0 + lane) * 8;
                gload16(Wh + go, Bh + (size_t)t0 * 8);
                if constexpr (NT == 3) gload16(Wl + go, Bl + (size_t)t0 * 8);
            }
        }
    };

    f32x4 acc[WM][WN];
#pragma unroll
    for (int m = 0; m < WM; ++m)
#pragma unroll
        for (int n = 0; n < WN; ++n) {
            acc[m][n][0] = 0.f; acc[m][n][1] = 0.f;
            acc[m][n][2] = 0.f; acc[m][n][3] = 0.f;
        }

    stage(smem, 0);

    for (int ks = 0; ks < KS; ++ks) {
        __syncthreads();
        unsigned short* buf = smem + (size_t)(ks & 1) * BUFSH;
        if (ks + 1 < KS)
            stage(smem + (size_t)((ks + 1) & 1) * BUFSH, ks + 1);

        unsigned short* Ah = buf;
        unsigned short* Al = buf + 4096;
        unsigned short* Bh = buf + ABUF;
        unsigned short* Bl = Bh + 4 * BN * 8;

        short8 ah[WM], bh[WN];
        short8 al[WM], bl[WN];
#pragma unroll
        for (int m = 0; m < WM; ++m) {
            int ro = (g << 7) + wrow0 + m * 16 + lr;
            ah[m] = *(const short8*)&Ah[ro * 8];
            if constexpr (NT >= 2) al[m] = *(const short8*)&Al[ro * 8];
        }
#pragma unroll
        for (int n = 0; n < WN; ++n) {
            int co = g * BN + wcol0 + n * 16 + lr;
            bh[n] = *(const short8*)&Bh[co * 8];
            if constexpr (NT == 3) bl[n] = *(const short8*)&Bl[co * 8];
        }
#pragma unroll
        for (int m = 0; m < WM; ++m)
#pragma unroll
            for (int n = 0; n < WN; ++n) {
                if constexpr (NT == 2) {
                    acc[m][n] = __builtin_amdgcn_mfma_f32_16x16x32_f16(
                        H8(ah[m]), H8(bh[n]), acc[m][n], 0, 0, 0);
                    acc[m][n] = __builtin_amdgcn_mfma_f32_16x16x32_f16(
                        H8(al[m]), H8(bh[n]), acc[m][n], 0, 0, 0);
                } else {
                    acc[m][n] = __builtin_amdgcn_mfma_f32_16x16x32_bf16(
                        ah[m], bh[n], acc[m][n], 0, 0, 0);
                    if constexpr (NT == 3) {
                        acc[m][n] = __builtin_amdgcn_mfma_f32_16x16x32_bf16(
                            ah[m], bl[n], acc[m][n], 0, 0, 0);
                        acc[m][n] = __builtin_amdgcn_mfma_f32_16x16x32_bf16(
                            al[m], bh[n], acc[m][n], 0, 0, 0);
                    }
                }
            }
    }

    float bv[WN];
#pragma unroll
    for (int n = 0; n < WN; ++n) bv[n] = bias[n0 + wcol0 + n * 16 + lr];

    unsigned short* Sb = smem;
    float* Sf = (float*)smem;
    constexpr int NPASS = (OUT == 0 || OUT == 3) ? 2 : 1;

#pragma unroll
    for (int p = 0; p < NPASS; ++p) {
        __syncthreads();
#pragma unroll
        for (int m = 0; m < WM; ++m)
#pragma unroll
            for (int n = 0; n < WN; ++n)
#pragma unroll
                for (int q = 0; q < 4; ++q) {
                    int rl = wrow0 + m * 16 + g * 4 + q;
                    int cl = wcol0 + n * 16 + lr;
                    float x = acc[m][n][q] + bv[n];
                    if (ACT == 0) x = fmaxf(x, 0.f);
                    else x = tanhf(x);
                    if constexpr (OUT == 2) {
                        Sf[rl * BN + cl] = x;
                    } else if constexpr (OUT == 3) {
                        unsigned short hh = f2h(x);
                        Sb[rl * BN + cl] = (p == 0) ? hh : f2h(x - h2f(hh));
                    } else {
                        unsigned short hb_ = f2bf(x);
                        Sb[rl * BN + cl] = (p == 0) ? hb_ : f2bf(x - bf2f(hb_));
                    }
                }
        __syncthreads();
        if constexpr (OUT == 2) {
            constexpr int SL = BN / 4;
#pragma unroll
            for (int it = 0; it < (128 * SL) / 256; ++it) {
                int idx = tid + it * 256;
                int row = idx / SL, sl = idx % SL;
                *(f32x4*)((float*)out0 + (size_t)(m0 + row) * NTOT + sl * 4)
                    = *(const f32x4*)&Sf[row * BN + sl * 4];
            }
        } else {
            constexpr int SL = BN / 8;
            unsigned short* dst = (unsigned short*)((p == 0) ? out0 : out1);
#pragma unroll
            for (int it = 0; it < (128 * SL) / 256; ++it) {
                int idx = tid + it * 256;
                int row = idx / SL, sl = idx % SL;
                *(short8*)&dst[(size_t)(m0 + row) * NTOT + n0 + sl * 8]
                    = *(const short8*)&Sb[row * BN + sl * 8];
            }
        }
    }
}

// ---------------------------------------------------------------------------
// BN=128 MFMA GEMM, counted-vmcnt pipeline: A 3-deep, B 2-deep, dynamic LDS.
// NT: 1=bf16 1-term (6/4/0), 2=fp16 2-term (10/6/0), 3=bf16 3-term (12/8/0).
// ---------------------------------------------------------------------------
template <int NT, int OUT, int ACT>
__global__ __launch_bounds__(256, 2) void mfma_gemm128(
    const unsigned short* __restrict__ Ah_g, const unsigned short* __restrict__ Al_g,
    int K,
    const unsigned short* __restrict__ Wh, const unsigned short* __restrict__ Wl,
    const float* __restrict__ bias,
    void* __restrict__ out0, void* __restrict__ out1, int NTOT)
{
    constexpr int BN = 128;
    constexpr int WM = 4, WN = 4, NWC = 2;
    constexpr int ASTR = (NT >= 2) ? 8192 : 4096;
    constexpr int BSTR = (NT == 3) ? 8192 : 4096;
    constexpr int BOFF = 3 * ASTR;
    extern __shared__ unsigned short smem[];

    const int tid = threadIdx.x;
    int per = gridDim.x >> 3;
    int xcd = blockIdx.x & 7;
    int lid = blockIdx.x >> 3;
    int tile = xcd * per + lid;
    const int m0 = (tile >> 3) * 128;
    const int nb = tile & 7;
    const int n0 = nb * BN;
    const int w = tid >> 6, lane = tid & 63;
    const int g = lane >> 4, lr = lane & 15;
    const int wrow0 = (w / NWC) * (WM * 16);
    const int wcol0 = (w % NWC) * (WN * 16);
    const int KS = K >> 5;

    auto stageA = [&](int i, int ks) {
        unsigned short* Ah = smem + i * ASTR;
        unsigned short* Al = Ah + 4096;
#pragma unroll
        for (int it = 0; it < 2; ++it) {
            int t0 = it * 256 + w * 64;
            int t = t0 + lane;
            int row = t & 127, kb = t >> 7;
            size_t go = (size_t)(m0 + row) * K + ks * 32 + kb * 8;
            gload16(Ah_g + go, Ah + (size_t)t0 * 8);
            if constexpr (NT >= 2) gload16(Al_g + go, Al + (size_t)t0 * 8);
        }
    };
    auto stageB = [&](int j, int ks) {
        unsigned short* Bh = smem + BOFF + j * BSTR;
        unsigned short* Bl = Bh + 4096;
        size_t bo = ((size_t)nb * KS + ks) * (BN * 32);
#pragma unroll
        for (int it = 0; it < 2; ++it) {
            int t0 = it * 256 + w * 64;
            size_t go = bo + (size_t)(t0 + lane) * 8;
            gload16(Wh + go, Bh + (size_t)t0 * 8);
            if constexpr (NT == 3) gload16(Wl + go, Bl + (size_t)t0 * 8);
        }
    };

    // bias first: oldest in vmcnt queue, retired by the first counted wait.
    float bv[WN];
#pragma unroll
    for (int n = 0; n < WN; ++n) bv[n] = bias[n0 + wcol0 + n * 16 + lr];
    __builtin_amdgcn_sched_barrier(0);

    f32x4 acc[WM][WN];
#pragma unroll
    for (int m = 0; m < WM; ++m)
#pragma unroll
        for (int n = 0; n < WN; ++n) {
            acc[m][n][0] = 0.f; acc[m][n][1] = 0.f;
            acc[m][n][2] = 0.f; acc[m][n][3] = 0.f;
        }

    stageB(0, 0);
    stageA(0, 0);
    if (KS > 1) stageA(1, 1);

    for (int ks = 0; ks < KS; ++ks) {
        __builtin_amdgcn_s_barrier();
        if (ks + 1 < KS) stageB((ks + 1) & 1, ks + 1);
        if (ks + 2 < KS) stageA((ks + 2) % 3, ks + 2);
        if (ks + 2 < KS) {
            if constexpr (NT == 3)      asm volatile("s_waitcnt vmcnt(12)" ::: "memory");
            else if constexpr (NT == 2) asm volatile("s_waitcnt vmcnt(10)" ::: "memory");
            else                        asm volatile("s_waitcnt vmcnt(6)" ::: "memory");
        } else if (ks + 1 < KS) {
            if constexpr (NT == 3)      asm volatile("s_waitcnt vmcnt(8)" ::: "memory");
            else if constexpr (NT == 2) asm volatile("s_waitcnt vmcnt(6)" ::: "memory");
            else                        asm volatile("s_waitcnt vmcnt(4)" ::: "memory");
        } else {
            asm volatile("s_waitcnt vmcnt(0)" ::: "memory");
        }
        __builtin_amdgcn_s_barrier();
        __builtin_amdgcn_sched_barrier(0);

        unsigned short* Ah = smem + (ks % 3) * ASTR;
        unsigned short* Al = Ah + 4096;
        unsigned short* Bh = smem + BOFF + (ks & 1) * BSTR;
        unsigned short* Bl = Bh + 4096;

        short8 ah[WM], bh[WN];
        short8 al[WM], bl[WN];
#pragma unroll
        for (int m = 0; m < WM; ++m) {
            int ro = (g << 7) + wrow0 + m * 16 + lr;
            ah[m] = *(const short8*)&Ah[ro * 8];
            if constexpr (NT >= 2) al[m] = *(const short8*)&Al[ro * 8];
        }
#pragma unroll
        for (int n = 0; n < WN; ++n) {
            int co = g * BN + wcol0 + n * 16 + lr;
            bh[n] = *(const short8*)&Bh[co * 8];
            if constexpr (NT == 3) bl[n] = *(const short8*)&Bl[co * 8];
        }
#pragma unroll
        for (int m = 0; m < WM; ++m)
#pragma unroll
            for (int n = 0; n < WN; ++n) {
                if constexpr (NT == 2) {
                    acc[m][n] = __builtin_amdgcn_mfma_f32_16x16x32_f16(
                        H8(ah[m]), H8(bh[n]), acc[m][n], 0, 0, 0);
                    acc[m][n] = __builtin_amdgcn_mfma_f32_16x16x32_f16(
                        H8(al[m]), H8(bh[n]), acc[m][n], 0, 0, 0);
                } else {
                    acc[m][n] = __builtin_amdgcn_mfma_f32_16x16x32_bf16(
                        ah[m], bh[n], acc[m][n], 0, 0, 0);
                    if constexpr (NT == 3) {
                        acc[m][n] = __builtin_amdgcn_mfma_f32_16x16x32_bf16(
                            ah[m], bl[n], acc[m][n], 0, 0, 0);
                        acc[m][n] = __builtin_amdgcn_mfma_f32_16x16x32_bf16(
                            al[m], bh[n], acc[m][n], 0, 0, 0);
                    }
                }
            }
    }

    unsigned short* Sb = smem;
    float* Sf = (float*)smem;
    constexpr int NPASS = (OUT == 0 || OUT == 3) ? 2 : 1;

#pragma unroll
    for (int p = 0; p < NPASS; ++p) {
        __syncthreads();
#pragma unroll
        for (int m = 0; m < WM; ++m)
#pragma unroll
            for (int n = 0; n < WN; ++n)
#pragma unroll
                for (int q = 0; q < 4; ++q) {
                    int rl = wrow0 + m * 16 + g * 4 + q;
                    int cl = wcol0 + n * 16 + lr;
                    float x = acc[m][n][q] + bv[n];
                    if (ACT == 0) x = fmaxf(x, 0.f);
                    else x = tanhf(x);
                    if constexpr (OUT == 2) {
                        Sf[rl * BN + cl] = x;
                    } else if constexpr (OUT == 3) {
                        unsigned short hh = f2h(x);
                        Sb[rl * BN + cl] = (p == 0) ? hh : f2h(x - h2f(hh));
                    } else {
                        unsigned short hb_ = f2bf(x);
                        Sb[rl * BN + cl] = (p == 0) ? hb_ : f2bf(x - bf2f(hb_));
                    }
                }
        __syncthreads();
        if constexpr (OUT == 2) {
            constexpr int SL = BN / 4;
#pragma unroll
            for (int it = 0; it < (128 * SL) / 256; ++it) {
                int idx = tid + it * 256;
                int row = idx / SL, sl = idx % SL;
                *(f32x4*)((float*)out0 + (size_t)(m0 + row) * NTOT + sl * 4)
                    = *(const f32x4*)&Sf[row * BN + sl * 4];
            }
        } else {
            constexpr int SL = BN / 8;
            unsigned short* dst = (unsigned short*)((p == 0) ? out0 : out1);
#pragma unroll
            for (int it = 0; it < (128 * SL) / 256; ++it) {
                int idx = tid + it * 256;
                int row = idx / SL, sl = idx % SL;
                *(short8*)&dst[(size_t)(m0 + row) * NTOT + n0 + sl * 8]
                    = *(const short8*)&Sb[row * BN + sl * 8];
            }
        }
    }
}

// ---------------------------------------------------------------------------
// BM=64 MFMA GEMM for small-N layers (G3: NT2/BN64 fp16, G6: NT1/BN32 bf16).
// ---------------------------------------------------------------------------
template <int NT, int BN, int ACT>
__global__ __launch_bounds__(256) void mfma_gemm64(
    const unsigned short* __restrict__ Ah_g, const unsigned short* __restrict__ Al_g,
    int K,
    const unsigned short* __restrict__ Wh, const unsigned short* __restrict__ Wl,
    const float* __restrict__ bias,
    float* __restrict__ out, int NTOT)
{
    constexpr int WM = (BN == 64) ? 2 : 1;
    constexpr int WN = 2;
    constexpr int ABUF = (NT >= 2) ? 4096 : 2048;          // shorts
    constexpr int BBUF = BN * 32 * ((NT == 3) ? 2 : 1);
    constexpr int BUFSH = ABUF + BBUF;
    __shared__ unsigned short smem[2 * BUFSH];

    const int tid = threadIdx.x;
    const int m0 = blockIdx.x * 64;
    const int w = tid >> 6, lane = tid & 63;
    const int g = lane >> 4, lr = lane & 15;
    const int wrow0 = (BN == 64) ? ((w >> 1) * 32) : (w * 16);
    const int wcol0 = (BN == 64) ? ((w & 1) * 32) : 0;
    const int KS = K >> 5;

    auto stage = [&](unsigned short* buf, int ks) {
        unsigned short* Ah = buf;
        unsigned short* Al = buf + 2048;
        unsigned short* Bh = buf + ABUF;
        unsigned short* Bl = Bh + BN * 32;
        {
            int t0 = w * 64;
            int t = t0 + lane;
            int row = t & 63, kb = t >> 6;
            size_t go = (size_t)(m0 + row) * K + ks * 32 + kb * 8;
            gload16(Ah_g + go, Ah + (size_t)t0 * 8);
            if constexpr (NT >= 2) gload16(Al_g + go, Al + (size_t)t0 * 8);
        }
        size_t bo = (size_t)ks * (BN * 32);
        constexpr int BT = BN * 4;
        if constexpr (BT == 256) {
            int t0 = w * 64;
            size_t go = bo + (size_t)(t0 + lane) * 8;
            gload16(Wh + go, Bh + (size_t)t0 * 8);
            if constexpr (NT == 3) gload16(Wl + go, Bl + (size_t)t0 * 8);
        } else {
            if (tid < BT) {
                int t0 = w * 64;
                size_t go = bo + (size_t)(t0 + lane) * 8;
                gload16(Wh + go, Bh + (size_t)t0 * 8);
                if constexpr (NT == 3) gload16(Wl + go, Bl + (size_t)t0 * 8);
            }
        }
    };

    f32x4 acc[WM][WN];
#pragma unroll
    for (int m = 0; m < WM; ++m)
#pragma unroll
        for (int n = 0; n < WN; ++n) {
            acc[m][n][0] = 0.f; acc[m][n][1] = 0.f;
            acc[m][n][2] = 0.f; acc[m][n][3] = 0.f;
        }

    stage(smem, 0);

    for (int ks = 0; ks < KS; ++ks) {
        __syncthreads();
        unsigned short* buf = smem + (size_t)(ks & 1) * BUFSH;
        if (ks + 1 < KS)
            stage(smem + (size_t)((ks + 1) & 1) * BUFSH, ks + 1);

        unsigned short* Ah = buf;
        unsigned short* Al = buf + 2048;
        unsigned short* Bh = buf + ABUF;
        unsigned short* Bl = Bh + BN * 32;

        short8 ah[WM], bh[WN];
        short8 al[WM], bl[WN];
#pragma unroll
        for (int m = 0; m < WM; ++m) {
            int ro = (g << 6) + wrow0 + m * 16 + lr;
            ah[m] = *(const short8*)&Ah[ro * 8];
            if constexpr (NT >= 2) al[m] = *(const short8*)&Al[ro * 8];
        }
#pragma unroll
        for (int n = 0; n < WN; ++n) {
            int co = g * BN + wcol0 + n * 16 + lr;
            bh[n] = *(const short8*)&Bh[co * 8];
            if constexpr (NT == 3) bl[n] = *(const short8*)&Bl[co * 8];
        }
#pragma unroll
        for (int m = 0; m < WM; ++m)
#pragma unroll
            for (int n = 0; n < WN; ++n) {
                if constexpr (NT == 2) {
                    acc[m][n] = __builtin_amdgcn_mfma_f32_16x16x32_f16(
                        H8(ah[m]), H8(bh[n]), acc[m][n], 0, 0, 0);
                    acc[m][n] = __builtin_amdgcn_mfma_f32_16x16x32_f16(
                        H8(al[m]), H8(bh[n]), acc[m][n], 0, 0, 0);
                } else {
                    acc[m][n] = __builtin_amdgcn_mfma_f32_16x16x32_bf16(
                        ah[m], bh[n], acc[m][n], 0, 0, 0);
                    if constexpr (NT == 3) {
                        acc[m][n] = __builtin_amdgcn_mfma_f32_16x16x32_bf16(
                            ah[m], bl[n], acc[m][n], 0, 0, 0);
                        acc[m][n] = __builtin_amdgcn_mfma_f32_16x16x32_bf16(
                            al[m], bh[n], acc[m][n], 0, 0, 0);
                    }
                }
            }
    }

    float bv[WN];
#pragma unroll
    for (int n = 0; n < WN; ++n) bv[n] = bias[wcol0 + n * 16 + lr];

    float* Sf = (float*)smem;
    __syncthreads();
#pragma unroll
    for (int m = 0; m < WM; ++m)
#pragma unroll
        for (int n = 0; n < WN; ++n)
#pragma unroll
            for (int q = 0; q < 4; ++q) {
                int rl = wrow0 + m * 16 + g * 4 + q;
                int cl = wcol0 + n * 16 + lr;
                float x = acc[m][n][q] + bv[n];
                if (ACT == 0) x = fmaxf(x, 0.f);
                else x = tanhf(x);
                Sf[rl * BN + cl] = x;
            }
    __syncthreads();
    constexpr int SL = BN / 4;
#pragma unroll
    for (int it = 0; it < (64 * SL) / 256; ++it) {
        int idx = tid + it * 256;
        int row = idx / SL, sl = idx % SL;
        *(f32x4*)(out + (size_t)(m0 + row) * NTOT + sl * 4)
            = *(const f32x4*)&Sf[row * BN + sl * 4];
    }
}

// ---------------------------------------------------------------------------
// fp32 fixup GEMM, 32-row tiles (proven round 9).
// ---------------------------------------------------------------------------
template <int BN, int ACT>
__global__ __launch_bounds__(256) void gemm_fix(
    const int* __restrict__ mrows,
    const float* __restrict__ A, int K,
    const float* __restrict__ W, const float* __restrict__ bias,
    float* __restrict__ Co, int N)
{
    const int m0 = blockIdx.x * 32;
    if (m0 >= *mrows) return;

    constexpr int TN = BN / 16;
    __shared__ float At[16][36];
    __shared__ float Bt[16][BN + 4];

    const int tid = threadIdx.x;
    const int n0 = blockIdx.y * BN;
    const int r = tid >> 4;
    const int c = tid & 15;

    float acc[2][TN];
#pragma unroll
    for (int i = 0; i < 2; ++i)
#pragma unroll
        for (int j = 0; j < TN; ++j) acc[i][j] = 0.f;

    for (int k0 = 0; k0 < K; k0 += 16) {
        if (tid < 128) {
            int row = tid >> 2;
            int lf = tid & 3;
            float4 v = *(const float4*)(A + (size_t)(m0 + row) * K + k0 + lf * 4);
            At[lf * 4 + 0][row] = v.x;
            At[lf * 4 + 1][row] = v.y;
            At[lf * 4 + 2][row] = v.z;
            At[lf * 4 + 3][row] = v.w;
        }
        constexpr int NF4 = BN / 4;
        constexpr int NEL = 16 * NF4;
#pragma unroll
        for (int it = 0; it < NEL / 256; ++it) {
            int idx = tid + it * 256;
            int kk = idx / NF4;
            int f = idx % NF4;
            float4 v = *(const float4*)(W + (size_t)(k0 + kk) * N + n0 + f * 4);
            *(float4*)&Bt[kk][f * 4] = v;
        }
        __syncthreads();

#pragma unroll
        for (int kk = 0; kk < 16; ++kk) {
            float a0 = At[kk][r * 2];
            float a1 = At[kk][r * 2 + 1];
            float b[TN];
            if constexpr (BN == 128) {
                float4 b0 = *(const float4*)&Bt[kk][c * 4];
                float4 b1 = *(const float4*)&Bt[kk][64 + c * 4];
                b[0] = b0.x; b[1] = b0.y; b[2] = b0.z; b[3] = b0.w;
                b[4] = b1.x; b[5] = b1.y; b[6] = b1.z; b[7] = b1.w;
            } else {
                float4 b0 = *(const float4*)&Bt[kk][c * 4];
                b[0] = b0.x; b[1] = b0.y; b[2] = b0.z; b[3] = b0.w;
            }
#pragma unroll
            for (int j = 0; j < TN; ++j) {
                acc[0][j] = fmaf(a0, b[j], acc[0][j]);
                acc[1][j] = fmaf(a1, b[j], acc[1][j]);
            }
        }
        __syncthreads();
    }

#pragma unroll
    for (int i = 0; i < 2; ++i) {
        size_t row = (size_t)(m0 + r * 2 + i);
        if constexpr (BN == 128) {
            float e[8];
#pragma unroll
            for (int j = 0; j < 8; ++j) {
                int col = (j < 4) ? (c * 4 + j) : (64 + c * 4 + (j - 4));
                float v = acc[i][j] + bias[n0 + col];
                if (ACT == 0) v = fmaxf(v, 0.f);
                e[j] = v;
            }
            float4 v0, v1;
            v0.x = e[0]; v0.y = e[1]; v0.z = e[2]; v0.w = e[3];
            v1.x = e[4]; v1.y = e[5]; v1.z = e[6]; v1.w = e[7];
            *(float4*)&Co[row * N + n0 + c * 4] = v0;
            *(float4*)&Co[row * N + n0 + 64 + c * 4] = v1;
        } else {
            float e[4];
#pragma unroll
            for (int j = 0; j < 4; ++j) {
                float v = acc[i][j] + bias[n0 + c * 4 + j];
                if (ACT == 0) v = fmaxf(v, 0.f);
                e[j] = v;
            }
            float4 v0;
            v0.x = e[0]; v0.y = e[1]; v0.z = e[2]; v0.w = e[3];
            *(float4*)&Co[row * N + n0 + c * 4] = v0;
        }
    }
}

// ---------------------------------------------------------------------------
// sa planes now fp16 hi + lo.
// ---------------------------------------------------------------------------
__global__ void sa_pre(const float* __restrict__ state, const float* __restrict__ action,
                       unsigned short* __restrict__ saH, unsigned short* __restrict__ saL)
{
    int idx = blockIdx.x * 256 + threadIdx.x;
    int row = idx / 12, q = idx % 12;
    const float* src = (q < 8) ? (state + (size_t)row * 64 + q * 8)
                               : (action + (size_t)row * 32 + (q - 8) * 8);
    f32x4 v0 = *(const f32x4*)src;
    f32x4 v1 = *(const f32x4*)(src + 4);
    short8 h, l;
#pragma unroll
    for (int j = 0; j < 8; ++j) {
        float x = (j < 4) ? v0[j] : v1[j - 4];
        unsigned short hh = f2h(x);
        h[j] = (short)hh;
        l[j] = (short)f2h(x - h2f(hh));
    }
    *(short8*)&saH[(size_t)row * 96 + q * 8] = h;
    *(short8*)&saL[(size_t)row * 96 + q * 8] = l;
}

// ---------------------------------------------------------------------------
// VQ score kernel: 64 rows x 512 codes per block, grid (M/64, 2).
// ---------------------------------------------------------------------------
__global__ __launch_bounds__(256) void vq_score(
    const float* __restrict__ midz,
    const float* __restrict__ codebook,
    const float* __restrict__ cbn,
    float4* __restrict__ part)
{
    __shared__ float Zt[64 * 68];
    __shared__ float Ct[64 * 68];
    __shared__ float cn[64];

    const int tid = threadIdx.x;
    const int m0 = blockIdx.x * 64;
    const int eh = blockIdx.y;
    const int r = tid >> 4;
    const int c = tid & 15;

#pragma unroll
    for (int it = 0; it < 4; ++it) {
        int idx = tid + it * 256;
        int row = idx >> 4, f = idx & 15;
        float4 v = *(const float4*)(midz + (size_t)(m0 + row) * 64 + f * 4);
        Zt[(f * 4 + 0) * 68 + row] = v.x;
        Zt[(f * 4 + 1) * 68 + row] = v.y;
        Zt[(f * 4 + 2) * 68 + row] = v.z;
        Zt[(f * 4 + 3) * 68 + row] = v.w;
    }

    float best[4], sec[4];
    int bidx[4];
#pragma unroll
    for (int i = 0; i < 4; ++i) { best[i] = 3.4e38f; sec[i] = 3.4e38f; bidx[i] = 0x7fffffff; }

    for (int ch = 0; ch < 8; ++ch) {
        int e0 = eh * 512 + ch * 64;
        __syncthreads();
#pragma unroll
        for (int it = 0; it < 4; ++it) {
            int idx = tid + it * 256;
            int e = idx >> 4, f = idx & 15;
            float4 v = *(const float4*)(codebook + (size_t)(e0 + e) * 64 + f * 4);
            Ct[(f * 4 + 0) * 68 + e] = v.x;
            Ct[(f * 4 + 1) * 68 + e] = v.y;
            Ct[(f * 4 + 2) * 68 + e] = v.z;
            Ct[(f * 4 + 3) * 68 + e] = v.w;
        }
        if (tid < 64) cn[tid] = cbn[e0 + tid];
        __syncthreads();

        float acc[4][4];
#pragma unroll
        for (int i = 0; i < 4; ++i)
#pragma unroll
            for (int j = 0; j < 4; ++j) acc[i][j] = 0.f;

#pragma unroll 8
        for (int kk = 0; kk < 64; ++kk) {
            float4 a = *(const float4*)&Zt[kk * 68 + r * 4];
            float4 b = *(const float4*)&Ct[kk * 68 + c * 4];
            acc[0][0] = fmaf(a.x, b.x, acc[0][0]);
            acc[0][1] = fmaf(a.x, b.y, acc[0][1]);
            acc[0][2] = fmaf(a.x, b.z, acc[0][2]);
            acc[0][3] = fmaf(a.x, b.w, acc[0][3]);
            acc[1][0] = fmaf(a.y, b.x, acc[1][0]);
            acc[1][1] = fmaf(a.y, b.y, acc[1][1]);
            acc[1][2] = fmaf(a.y, b.z, acc[1][2]);
            acc[1][3] = fmaf(a.y, b.w, acc[1][3]);
            acc[2][0] = fmaf(a.z, b.x, acc[2][0]);
            acc[2][1] = fmaf(a.z, b.y, acc[2][1]);
            acc[2][2] = fmaf(a.z, b.z, acc[2][2]);
            acc[2][3] = fmaf(a.z, b.w, acc[2][3]);
            acc[3][0] = fmaf(a.w, b.x, acc[3][0]);
            acc[3][1] = fmaf(a.w, b.y, acc[3][1]);
            acc[3][2] = fmaf(a.w, b.z, acc[3][2]);
            acc[3][3] = fmaf(a.w, b.w, acc[3][3]);
        }
#pragma unroll
        for (int i = 0; i < 4; ++i)
#pragma unroll
            for (int j = 0; j < 4; ++j) {
                int e = c * 4 + j;
                float s = cn[e] - 2.0f * acc[i][j];
                int gi = e0 + e;
                if (s < best[i] || (s == best[i] && gi < bidx[i])) {
                    sec[i] = best[i];
                    best[i] = s;
                    bidx[i] = gi;
                } else {
                    sec[i] = fminf(sec[i], s);
                }
            }
    }

#pragma unroll
    for (int i = 0; i < 4; ++i) {
#pragma unroll
        for (int m = 1; m < 16; m <<= 1) {
            float ob = __shfl_xor(best[i], m, 64);
            int oi = __shfl_xor(bidx[i], m, 64);
            float os = __shfl_xor(sec[i], m, 64);
            if (ob < best[i] || (ob == best[i] && oi < bidx[i])) {
                sec[i] = fminf(best[i], os);
                best[i] = ob;
                bidx[i] = oi;
            } else {
                sec[i] = fminf(sec[i], ob);
            }
        }
    }
    if (c == 0) {
#pragma unroll
        for (int i = 0; i < 4; ++i) {
            float4 p;
            p.x = best[i];
            p.y = sec[i];
            p.z = __int_as_float(bidx[i]);
            p.w = 0.f;
            part[(size_t)(m0 + r * 4 + i) * 2 + eh] = p;
        }
    }
}

// ---------------------------------------------------------------------------
// VQ merge + flag + latent head + state half of xz.  128 rows/block, grid mt.
// ---------------------------------------------------------------------------
__global__ __launch_bounds__(256) void vq_merge(
    const float4* __restrict__ part,
    const float* __restrict__ state_c,
    const float* __restrict__ codebook,
    const float* __restrict__ mean_w, const float* __restrict__ mean_b,
    const float* __restrict__ logstd_w, const float* __restrict__ logstd_b,
    const float* __restrict__ eps,
    float* __restrict__ mean_out, float* __restrict__ std_out,
    unsigned short* __restrict__ xz,
    int* __restrict__ ctr, int* __restrict__ list, int rowbase)
{
    __shared__ float mw[4160];
    __shared__ float lw[4160];
    __shared__ int sidx[128];

    const int tid = threadIdx.x;
    const int m0 = blockIdx.x * 128;

    if (tid < 128) {
        size_t row = (size_t)(m0 + tid);
        float4 p0 = part[row * 2 + 0];
        float4 p1 = part[row * 2 + 1];
        int i0 = __float_as_int(p0.z), i1 = __float_as_int(p1.z);
        float b, s;
        int ix;
        if (p0.x < p1.x || (p0.x == p1.x && i0 < i1)) {
            b = p0.x; ix = i0; s = fminf(p0.y, p1.x);
        } else {
            b = p1.x; ix = i1; s = fminf(p1.y, p0.x);
        }
        sidx[tid] = ix;
        if (s - b < TAU) {
            int p = atomicAdd(ctr, 1);
            list[p] = rowbase + m0 + tid;
        }
    }
#pragma unroll
    for (int it = 0; it < 4; ++it) {
        int idx = tid + it * 256;
        int k = idx >> 4, f = idx & 15;
        float4 v = *(const float4*)(mean_w + (size_t)k * 64 + f * 4);
        mw[k * 65 + f * 4 + 0] = v.x;
        mw[k * 65 + f * 4 + 1] = v.y;
        mw[k * 65 + f * 4 + 2] = v.z;
        mw[k * 65 + f * 4 + 3] = v.w;
        float4 w2 = *(const float4*)(logstd_w + (size_t)k * 64 + f * 4);
        lw[k * 65 + f * 4 + 0] = w2.x;
        lw[k * 65 + f * 4 + 1] = w2.y;
        lw[k * 65 + f * 4 + 2] = w2.z;
        lw[k * 65 + f * 4 + 3] = w2.w;
    }

    // state half -> xz cols 0..63 (independent of merge; no sync needed)
    {
        int row = tid >> 1;
        int d0 = (tid & 1) * 32;
        size_t so = (size_t)(m0 + row) * 64 + d0;
        size_t xo = (size_t)(m0 + row) * 128 + d0;
#pragma unroll
        for (int q = 0; q < 8; ++q) {
            f32x4 v = *(const f32x4*)&state_c[so + q * 4];
            unsigned short o[4];
            o[0] = f2bf(v[0]); o[1] = f2bf(v[1]);
            o[2] = f2bf(v[2]); o[3] = f2bf(v[3]);
            *(uint2*)&xz[xo + q * 4] = *(uint2*)o;
        }
    }
    __syncthreads();

    {
        int row = tid >> 1;
        int d0 = (tid & 1) * 32;
        int e = sidx[row];
        const float* cb = codebook + (size_t)e * 64;
        float mv[32], lv[32];
#pragma unroll
        for (int d = 0; d < 32; ++d) {
            mv[d] = mean_b[d0 + d];
            lv[d] = logstd_b[d0 + d];
        }
        for (int k = 0; k < 64; ++k) {
            float zk = cb[k];
#pragma unroll
            for (int d = 0; d < 32; ++d) {
                mv[d] = fmaf(zk, mw[k * 65 + d0 + d], mv[d]);
                lv[d] = fmaf(zk, lw[k * 65 + d0 + d], lv[d]);
            }
        }
        size_t ro = (size_t)(m0 + row) * 64 + d0;
        size_t xo = (size_t)(m0 + row) * 128 + 64 + d0;
#pragma unroll
        for (int d = 0; d < 32; ++d) {
            float mean = mv[d];
            float ls = fminf(fmaxf(lv[d], -4.f), 15.f);
            float sd = expf(ls);
            float z = fmaf(sd, eps[ro + d], mean);
            mean_out[ro + d] = mean;
            std_out[ro + d] = sd;
            xz[xo + d] = f2bf(z);
        }
    }
}

// ---------------------------------------------------------------------------
__global__ void gather_fix(const int* __restrict__ ctr, int* __restrict__ meta,
                           const int* __restrict__ list,
                           const float* __restrict__ state,
                           const float* __restrict__ action,
                           float* __restrict__ sa_fix)
{
    int cnt = *ctr; if (cnt > FMAX) cnt = FMAX;
    if (blockIdx.x == 0 && threadIdx.x == 0)
        meta[0] = (cnt + 31) & ~31;
    int t = blockIdx.x * 256 + threadIdx.x;
    if (t >= cnt * 24) return;
    int f = t / 24, q = t % 24;
    size_t g = (size_t)list[f];
    f32x4 v = (q < 16) ? *(const f32x4*)&state[g * 64 + q * 4]
                       : *(const f32x4*)&action[g * 32 + (q - 16) * 4];
    *(f32x4*)&sa_fix[(size_t)f * 96 + q * 4] = v;
}

// ---------------------------------------------------------------------------
__global__ __launch_bounds__(256) void vq_fix(
    const int* __restrict__ ctr, const int* __restrict__ list,
    const float* __restrict__ mz_fix,
    const float* __restrict__ codebook, const float* __restrict__ cbn,
    const float* __restrict__ mean_w, const float* __restrict__ mean_b,
    const float* __restrict__ logstd_w, const float* __restrict__ logstd_b,
    const float* __restrict__ eps,
    float* __restrict__ mean_out, float* __restrict__ std_out,
    unsigned short* __restrict__ xz)
{
    __shared__ float mzs[8][64];
    __shared__ float zns[8];
    __shared__ float sv[2048];
    __shared__ int si[2048];
    __shared__ int am_s[8];

    int cnt = *ctr; if (cnt > FMAX) cnt = FMAX;
    const int base = blockIdx.x * 8;
    if (base >= cnt) return;
    const int nr = min(8, cnt - base);
    const int tid = threadIdx.x;

    if (tid < 128) {
        int rr = tid >> 4, q = tid & 15;
        int src = base + ((rr < nr) ? rr : 0);
        *(f32x4*)&mzs[rr][q * 4] = *(const f32x4*)&mz_fix[(size_t)src * 64 + q * 4];
    }
    __syncthreads();
    if (tid < 8) {
        float s = 0.f;
#pragma unroll
        for (int k = 0; k < 64; ++k) s = fmaf(mzs[tid][k], mzs[tid][k], s);
        zns[tid] = s;
    }
    __syncthreads();

    float bb[8];
    int bi[8];
#pragma unroll
    for (int rr = 0; rr < 8; ++rr) { bb[rr] = 3.4e38f; bi[rr] = 0x7fffffff; }
    for (int j = 0; j < 4; ++j) {
        int code = tid + j * 256;
        const f32x4* cp = (const f32x4*)(codebook + (size_t)code * 64);
        float dot[8];
#pragma unroll
        for (int rr = 0; rr < 8; ++rr) dot[rr] = 0.f;
        for (int t = 0; t < 16; ++t) {
            f32x4 cv = cp[t];
#pragma unroll
            for (int e = 0; e < 4; ++e) {
                float cvv = cv[e];
#pragma unroll
                for (int rr = 0; rr < 8; ++rr)
                    dot[rr] = fmaf(mzs[rr][t * 4 + e], cvv, dot[rr]);
            }
        }
        float cnv = cbn[code];
#pragma unroll
        for (int rr = 0; rr < 8; ++rr) {
            float s = (zns[rr] + cnv) - 2.0f * dot[rr];
            if (s < bb[rr] || (s == bb[rr] && code < bi[rr])) {
                bb[rr] = s; bi[rr] = code;
            }
        }
    }
#pragma unroll
    for (int rr = 0; rr < 8; ++rr) {
        sv[rr * 256 + tid] = bb[rr];
        si[rr * 256 + tid] = bi[rr];
    }
    __syncthreads();
    if (tid < 8) {
        float b = 3.4e38f;
        int ix = 0x7fffffff;
        for (int t = 0; t < 256; ++t) {
            float v = sv[tid * 256 + t];
            int iv = si[tid * 256 + t];
            if (v < b || (v == b && iv < ix)) { b = v; ix = iv; }
        }
        am_s[tid] = ix;
    }
    __syncthreads();

    for (int jo = 0; jo < 2; ++jo) {
        int o = tid + jo * 256;
        int rr = o >> 6, d = o & 63;
        if (rr < nr) {
            int e = am_s[rr];
            size_t g = (size_t)list[base + rr];
            float mv = mean_b[d], lv = logstd_b[d];
            const float* cb = codebook + (size_t)e * 64;
            for (int k = 0; k < 64; ++k) {
                float zk = cb[k];
                mv = fmaf(zk, mean_w[(size_t)k * 64 + d], mv);
                lv = fmaf(zk, logstd_w[(size_t)k * 64 + d], lv);
            }
            float ls = fminf(fmaxf(lv, -4.f), 15.f);
            float sd = expf(ls);
            float z = fmaf(sd, eps[g * 64 + d], mv);
            mean_out[g * 64 + d] = mv;
            std_out[g * 64 + d] = sd;
            xz[g * 128 + 64 + d] = f2bf(z);
        }
    }
}

// ---------------------------------------------------------------------------
extern "C" void kernel_launch(void* const* d_in, const int* in_sizes, int n_in,
                              void* d_out, int out_size, void* d_ws, size_t ws_size,
                              hipStream_t stream)
{
    const float* state    = (const float*)d_in[0];
    const float* action   = (const float*)d_in[1];
    const float* eps      = (const float*)d_in[2];
    const float* enc_w1   = (const float*)d_in[3];
    const float* enc_b1   = (const float*)d_in[4];
    const float* enc_w2   = (const float*)d_in[5];
    const float* enc_b2   = (const float*)d_in[6];
    const float* enc_w3   = (const float*)d_in[7];
    const float* enc_b3   = (const float*)d_in[8];
    const float* mean_w   = (const float*)d_in[9];
    const float* mean_b   = (const float*)d_in[10];
    const float* logstd_w = (const float*)d_in[11];
    const float* logstd_b = (const float*)d_in[12];
    const float* codebook = (const float*)d_in[13];
    const float* dec_w1   = (const float*)d_in[14];
    const float* dec_b1   = (const float*)d_in[15];
    const float* dec_w2   = (const float*)d_in[16];
    const float* dec_b2   = (const float*)d_in[17];
    const float* dec_w3   = (const float*)d_in[18];
    const float* dec_b3   = (const float*)d_in[19];

    float* out = (float*)d_out;
    float* u_out = out;
    float* mean_out = out + (size_t)B_TOTAL * 32;
    float* std_out = mean_out + (size_t)B_TOTAL * 64;

    // ---- fixed ws region (~9.6 MB; fix buffers alias the dyn area) ----
    char* base = (char*)d_ws;
    float* cbn = (float*)base;                                   // 4096
    unsigned short* W1h = (unsigned short*)(base + 4096);        // 196608 (fp16)
    unsigned short* W1l = (unsigned short*)(base + 200704);      // unused
    unsigned short* W2h = (unsigned short*)(base + 397312);      // 2097152 (fp16)
    unsigned short* W2l = (unsigned short*)(base + 2494464);     // unused
    unsigned short* W3h = (unsigned short*)(base + 4591616);     // 131072 (fp16)
    unsigned short* W3l = (unsigned short*)(base + 4722688);     // unused
    unsigned short* W4h = (unsigned short*)(base + 4853760);     // 262144 (bf16)
    unsigned short* W5h = (unsigned short*)(base + 5115904);     // 2097152 (bf16)
    unsigned short* W6h = (unsigned short*)(base + 7213056);     // 65536 (bf16)
    int* ctr            = (int*)(base + 7278592);                // 256
    int* flag_list      = (int*)(base + 7278848);                // 262144
    int* meta           = (int*)(base + 7540992);                // 256
    float4* part        = (float4*)(base + 7541248);             // 2097152
    const size_t FIXED  = 9638400;

    unsigned short* xz_g = (unsigned short*)(base + FIXED);      // 16 MB
    const size_t XZ_SZ = (size_t)B_TOTAL * 128 * 2;

    // dyn region: per-chunk staging; per_row = 384 + 8192 + 256 = 8832 B
    const size_t per_row = 8832;
    size_t avail = (ws_size > FIXED + XZ_SZ) ? (ws_size - FIXED - XZ_SZ) : 0;
    long maxC = (long)(avail / per_row);
    int C = (int)(maxC / 1024) * 1024;
    if (C > B_TOTAL) C = B_TOTAL;
    if (C < 6144) C = 6144;   // >= fix-alias region (54.26 MB = 6144*8832)

    char* dyn = base + FIXED + XZ_SZ;
    unsigned short* saH = (unsigned short*)dyn;                   // [C,96] fp16
    unsigned short* saL = saH + (size_t)C * 96;
    unsigned short* h1H = saL + (size_t)C * 96;                   // [C,1024] fp16
    unsigned short* h1L = h1H + (size_t)C * 1024;
    unsigned short* h2H = h1L + (size_t)C * 1024;
    unsigned short* h2L = h2H + (size_t)C * 1024;
    float* mz = (float*)(h2L + (size_t)C * 1024);                 // [C,64]
    unsigned short* hc = h1H;   // decoder reuse (bf16)
    unsigned short* hd = h2H;

    // fixup buffers alias dyn (phase B runs after all of phase A)
    float* sa_fix = (float*)dyn;                                  // 2359296
    float* h1_fix = (float*)(dyn + 2359296);                      // 25165824
    float* h2_fix = (float*)(dyn + 27525120);                     // 25165824
    float* mz_fix = (float*)(dyn + 52690944);                     // 1572864

    // dynamic-LDS attrs for the pipelined kernels (fallback to old if denied)
    bool deep = hipFuncSetAttribute(
        reinterpret_cast<const void*>(&mfma_gemm128<2, 3, 0>),
        hipFuncAttributeMaxDynamicSharedMemorySize, 65536) == hipSuccess;
    deep = deep && hipFuncSetAttribute(
        reinterpret_cast<const void*>(&mfma_gemm128<1, 1, 0>),
        hipFuncAttributeMaxDynamicSharedMemorySize, 40960) == hipSuccess;

    // ---- once per call ----
    cb_norms<<<dim3(4), dim3(256), 0, stream>>>(codebook, cbn);
    zero_ctr<<<dim3(1), dim3(64), 0, stream>>>(ctr);
    w_xform<2, 128><<<dim3(3, 8), dim3(256), 0, stream>>>(enc_w1, 96, 1024, W1h, nullptr);
    w_xform<2, 128><<<dim3(32, 8), dim3(256), 0, stream>>>(enc_w2, 1024, 1024, W2h, nullptr);
    w_xform<2, 64><<<dim3(32, 1), dim3(256), 0, stream>>>(enc_w3, 1024, 64, W3h, nullptr);
    w_xform<1, 128><<<dim3(4, 8), dim3(256), 0, stream>>>(dec_w1, 128, 1024, W4h, nullptr);
    w_xform<1, 128><<<dim3(32, 8), dim3(256), 0, stream>>>(dec_w2, 1024, 1024, W5h, nullptr);
    w_xform<1, 32><<<dim3(32, 1), dim3(256), 0, stream>>>(dec_w3, 1024, 32, W6h, nullptr);

    // ---- phase A: encoder (fp16 2-term) + VQ for all chunks ----
    for (int r0 = 0; r0 < B_TOTAL; r0 += C) {
        int M = (r0 + C <= B_TOTAL) ? C : (B_TOTAL - r0);
        int mt = M / 128;

        sa_pre<<<dim3(M * 12 / 256), dim3(256), 0, stream>>>(
            state + (size_t)r0 * SDIM, action + (size_t)r0 * ADIM, saH, saL);

        if (deep) {
            mfma_gemm128<2, 3, 0><<<dim3(mt * 8), dim3(256), 65536, stream>>>(
                saH, saL, 96, W1h, nullptr, enc_b1, h1H, h1L, 1024);
            mfma_gemm128<2, 3, 0><<<dim3(mt * 8), dim3(256), 65536, stream>>>(
                h1H, h1L, 1024, W2h, nullptr, enc_b2, h2H, h2L, 1024);
        } else {
            mfma_gemm<2, 128, 3, 0><<<dim3(mt * 8), dim3(256), 0, stream>>>(
                saH, saL, 96, W1h, nullptr, enc_b1, h1H, h1L, 1024);
            mfma_gemm<2, 128, 3, 0><<<dim3(mt * 8), dim3(256), 0, stream>>>(
                h1H, h1L, 1024, W2h, nullptr, enc_b2, h2H, h2L, 1024);
        }
        mfma_gemm64<2, 64, 0><<<dim3(M / 64), dim3(256), 0, stream>>>(
            h2H, h2L, 1024, W3h, nullptr, enc_b3, mz, 64);

        vq_score<<<dim3(M / 64, 2), dim3(256), 0, stream>>>(
            mz, codebook, cbn, part + (size_t)r0 * 2);
        vq_merge<<<dim3(mt), dim3(256), 0, stream>>>(
            part + (size_t)r0 * 2, state + (size_t)r0 * SDIM, codebook,
            mean_w, mean_b, logstd_w, logstd_b,
            eps + (size_t)r0 * LDIM,
            mean_out + (size_t)r0 * LDIM, std_out + (size_t)r0 * LDIM,
            xz_g + (size_t)r0 * 128, ctr, flag_list, r0);
    }

    // ---- phase B: exact-fp32 fixup as 32-row-tile GEMMs on gathered rows ----
    gather_fix<<<dim3(FMAX * 24 / 256), dim3(256), 0, stream>>>(
        ctr, meta, flag_list, state, action, sa_fix);
    gemm_fix<128, 0><<<dim3(FMAX / 32, 8), dim3(256), 0, stream>>>(
        meta, sa_fix, 96, enc_w1, enc_b1, h1_fix, 1024);
    gemm_fix<128, 0><<<dim3(FMAX / 32, 8), dim3(256), 0, stream>>>(
        meta, h1_fix, 1024, enc_w2, enc_b2, h2_fix, 1024);
    gemm_fix<64, 0><<<dim3(FMAX / 32, 1), dim3(256), 0, stream>>>(
        meta, h2_fix, 1024, enc_w3, enc_b3, mz_fix, 64);
    vq_fix<<<dim3(FMAX / 8), dim3(256), 0, stream>>>(
        ctr, flag_list, mz_fix, codebook, cbn,
        mean_w, mean_b, logstd_w, logstd_b, eps,
        mean_out, std_out, xz_g);

    // ---- phase C: decoder (bf16 1-term) for all chunks ----
    for (int r0 = 0; r0 < B_TOTAL; r0 += C) {
        int M = (r0 + C <= B_TOTAL) ? C : (B_TOTAL - r0);
        int mt = M / 128;

        if (deep) {
            mfma_gemm128<1, 1, 0><<<dim3(mt * 8), dim3(256), 40960, stream>>>(
                xz_g + (size_t)r0 * 128, nullptr, 128, W4h, nullptr, dec_b1,
                hc, nullptr, 1024);
            mfma_gemm128<1, 1, 0><<<dim3(mt * 8), dim3(256), 40960, stream>>>(
                hc, nullptr, 1024, W5h, nullptr, dec_b2, hd, nullptr, 1024);
        } else {
            mfma_gemm<1, 128, 1, 0><<<dim3(mt * 8), dim3(256), 0, stream>>>(
                xz_g + (size_t)r0 * 128, nullptr, 128, W4h, nullptr, dec_b1,
                hc, nullptr, 1024);
            mfma_gemm<1, 128, 1, 0><<<dim3(mt * 8), dim3(256), 0, stream>>>(
                hc, nullptr, 1024, W5h, nullptr, dec_b2, hd, nullptr, 1024);
        }
        mfma_gemm64<1, 32, 1><<<dim3(M / 64), dim3(256), 0, stream>>>(
            hd, nullptr, 1024, W6h, nullptr, dec_b3,
            u_out + (size_t)r0 * ADIM, 32);
    }
}